// Round 1
// baseline (3752.079 us; speedup 1.0000x reference)
//
#include <hip/hip_runtime.h>

#define NCLS 26
#define HID 128

// ---------------- preprocessing kernels ----------------

__global__ void edge_pass1(const int* __restrict__ ei, const float* __restrict__ ew,
                           float* __restrict__ deg, int* __restrict__ cnt, int E) {
  int e = blockIdx.x * 256 + threadIdx.x;
  if (e >= E) return;
  int c = ei[E + e];
  atomicAdd(&deg[c], ew[e]);
  atomicAdd(&cnt[c], 1);
}

__global__ void dinv_kernel(float* __restrict__ deg, int n) {
  int i = blockIdx.x * 256 + threadIdx.x;
  if (i >= n) return;
  float d = deg[i];
  deg[i] = d > 0.f ? rsqrtf(fmaxf(d, 1e-12f)) : 0.f;
}

__global__ void scan_block(const int* __restrict__ cnt, int* __restrict__ excl,
                           int* __restrict__ blksum, int n) {
  __shared__ int s[256];
  int g = blockIdx.x * 256 + threadIdx.x;
  int v = (g < n) ? cnt[g] : 0;
  s[threadIdx.x] = v;
  __syncthreads();
  for (int off = 1; off < 256; off <<= 1) {
    int t = (threadIdx.x >= (unsigned)off) ? s[threadIdx.x - off] : 0;
    __syncthreads();
    s[threadIdx.x] += t;
    __syncthreads();
  }
  if (g < n) excl[g] = s[threadIdx.x] - v;
  if (threadIdx.x == 255) blksum[blockIdx.x] = s[255];
}

__global__ void scan_partials(int* __restrict__ blksum, int nb) {
  __shared__ int s[512];
  int t = threadIdx.x;
  int v = (t < nb) ? blksum[t] : 0;
  s[t] = v;
  __syncthreads();
  for (int off = 1; off < 512; off <<= 1) {
    int u = (t >= off) ? s[t - off] : 0;
    __syncthreads();
    s[t] += u;
    __syncthreads();
  }
  if (t < nb) blksum[t] = s[t] - v;
}

__global__ void add_offsets(int* __restrict__ excl, const int* __restrict__ blksum, int n) {
  int g = blockIdx.x * 256 + threadIdx.x;
  if (g < n) excl[g] += blksum[blockIdx.x];
}

__global__ void edge_pass2(const int* __restrict__ ei, const float* __restrict__ ew,
                           const float* __restrict__ dinv, const int* __restrict__ start,
                           int* __restrict__ cur, int* __restrict__ srow,
                           float* __restrict__ snorm, int E) {
  int e = blockIdx.x * 256 + threadIdx.x;
  if (e >= E) return;
  int r = ei[e], c = ei[E + e];
  float nrm = dinv[r] * ew[e] * dinv[c];
  int p = start[c] + atomicAdd(&cur[c], 1);
  srow[p] = r;
  snorm[p] = nrm;
}

// ---------------- SpMM (pull, CSR by destination) ----------------

// width 128: 256 threads = 2 nodes x 128 lanes
__global__ void spmm_w128(const int* __restrict__ srow, const float* __restrict__ snorm,
                          const int* __restrict__ start, const int* __restrict__ cnt,
                          const float* __restrict__ in, float* __restrict__ out, int n) {
  int node = blockIdx.x * 2 + (threadIdx.x >> 7);
  int f = threadIdx.x & 127;
  if (node >= n) return;
  int s = start[node], m = cnt[node];
  float a = 0.f;
  for (int e = s; e < s + m; ++e) {
    a += snorm[e] * in[srow[e] * HID + f];
  }
  out[node * HID + f] = a;
}

// width 26: 256 threads = 8 nodes x 32 lanes (26 active)
__global__ void spmm_w26(const int* __restrict__ srow, const float* __restrict__ snorm,
                         const int* __restrict__ start, const int* __restrict__ cnt,
                         const float* __restrict__ in, float* __restrict__ out, int n) {
  int node = blockIdx.x * 8 + (threadIdx.x >> 5);
  int f = threadIdx.x & 31;
  if (node >= n || f >= NCLS) return;
  int s = start[node], m = cnt[node];
  float a = 0.f;
  for (int e = s; e < s + m; ++e) {
    a += snorm[e] * in[srow[e] * NCLS + f];
  }
  out[node * NCLS + f] = a;
}

// ---------------- GEMM accumulate: C (+)= A(MxK) @ B(KxN) [+bias] [ELU] ----------------

template <int BM, int BN, int BK, int TM, int TN>
__global__ __launch_bounds__(256) void gemm_acc(
    const float* __restrict__ A, int lda, const float* __restrict__ B, int ldb,
    float* __restrict__ C, int ldc, int M, int N, int K,
    const float* __restrict__ bias, int init, int elu) {
  __shared__ float As[BK][BM + 1];
  __shared__ float Bs[BK][BN + 1];
  const int tid = threadIdx.x;
  const int tcols = BN / TN;  // threads along N
  const int tx = tid % tcols;
  const int ty = tid / tcols;
  const int row0 = blockIdx.x * BM;
  const int col0 = blockIdx.y * BN;

  float acc[TM][TN];
#pragma unroll
  for (int i = 0; i < TM; ++i)
#pragma unroll
    for (int j = 0; j < TN; ++j) acc[i][j] = 0.f;

  for (int k0 = 0; k0 < K; k0 += BK) {
    for (int idx = tid; idx < BM * BK; idx += 256) {
      int m = idx / BK, kk = idx % BK;
      int gm = row0 + m, gk = k0 + kk;
      As[kk][m] = (gm < M && gk < K) ? A[gm * lda + gk] : 0.f;
    }
    for (int idx = tid; idx < BK * BN; idx += 256) {
      int kk = idx / BN, nn = idx % BN;
      int gk = k0 + kk, gn = col0 + nn;
      Bs[kk][nn] = (gk < K && gn < N) ? B[gk * ldb + gn] : 0.f;
    }
    __syncthreads();
#pragma unroll
    for (int kk = 0; kk < BK; ++kk) {
      float a[TM], b[TN];
#pragma unroll
      for (int i = 0; i < TM; ++i) a[i] = As[kk][ty * TM + i];
#pragma unroll
      for (int j = 0; j < TN; ++j) b[j] = Bs[kk][tx * TN + j];
#pragma unroll
      for (int i = 0; i < TM; ++i)
#pragma unroll
        for (int j = 0; j < TN; ++j) acc[i][j] += a[i] * b[j];
    }
    __syncthreads();
  }

#pragma unroll
  for (int i = 0; i < TM; ++i) {
    int gm = row0 + ty * TM + i;
    if (gm >= M) continue;
#pragma unroll
    for (int j = 0; j < TN; ++j) {
      int gn = col0 + tx * TN + j;
      if (gn >= N) continue;
      float v = init ? (bias ? bias[gn] : 0.f) : C[gm * ldc + gn];
      v += acc[i][j];
      if (elu) v = v > 0.f ? v : (expf(v) - 1.f);
      C[gm * ldc + gn] = v;
    }
  }
}

// gemm variant for N=128 tiles
static void launch_gemm_n128(const float* A, int lda, const float* B,
                             float* C, int M, int K, const float* bias, int init, int elu,
                             hipStream_t stream) {
  dim3 grid((M + 63) / 64, 1);
  gemm_acc<64, 128, 32, 4, 8><<<grid, 256, 0, stream>>>(A, lda, B, HID, C, HID, M, HID, K,
                                                        bias, init, elu);
}

// gemm variant for N=26
static void launch_gemm_n26(const float* A, int lda, const float* B,
                            float* C, int M, int K, const float* bias, int init, int elu,
                            hipStream_t stream) {
  dim3 grid((M + 127) / 128, 1);
  gemm_acc<128, 32, 32, 8, 2><<<grid, 256, 0, stream>>>(A, lda, B, NCLS, C, NCLS, M, NCLS, K,
                                                        bias, init, elu);
}

// ---------------- launcher ----------------

extern "C" void kernel_launch(void* const* d_in, const int* in_sizes, int n_in,
                              void* d_out, int out_size, void* d_ws, size_t ws_size,
                              hipStream_t stream) {
  const float* x  = (const float*)d_in[0];
  const int*   ei = (const int*)d_in[1];
  const float* ew = (const float*)d_in[2];
  const float* W1 = (const float*)d_in[3];
  const float* b1 = (const float*)d_in[4];
  const float* W2 = (const float*)d_in[5];
  const float* b2 = (const float*)d_in[6];
  const float* W3 = (const float*)d_in[7];
  const float* b3 = (const float*)d_in[8];
  float* out = (float*)d_out;

  const int n = in_sizes[0] / NCLS;  // 100000
  const int E = in_sizes[2];         // 1600000

  char* w = (char*)d_ws;
  auto alloc = [&](size_t bytes) {
    char* p = w;
    w += (bytes + 255) / 256 * 256;
    return p;
  };
  float* B0    = (float*)alloc((size_t)n * HID * 4);
  float* B1    = (float*)alloc((size_t)n * HID * 4);
  float* B2    = (float*)alloc((size_t)n * HID * 4);
  float* p26a  = (float*)alloc((size_t)n * NCLS * 4);
  float* p26b  = (float*)alloc((size_t)n * NCLS * 4);
  int*   srow  = (int*)alloc((size_t)E * 4);
  float* snorm = (float*)alloc((size_t)E * 4);
  int*   start = (int*)alloc((size_t)n * 4);
  int*   cnt   = (int*)alloc((size_t)n * 4);
  int*   cur   = (int*)alloc((size_t)n * 4);
  float* deg   = (float*)alloc((size_t)n * 4);
  int*   blks  = (int*)alloc(4096 * 4);

  const int eb = (E + 255) / 256;
  const int nb = (n + 255) / 256;  // 391 — also #scan blocks (fits in 512-thread partials scan)

  hipMemsetAsync(deg, 0, (size_t)n * 4, stream);
  hipMemsetAsync(cnt, 0, (size_t)n * 4, stream);
  hipMemsetAsync(cur, 0, (size_t)n * 4, stream);

  edge_pass1<<<eb, 256, 0, stream>>>(ei, ew, deg, cnt, E);
  dinv_kernel<<<nb, 256, 0, stream>>>(deg, n);
  scan_block<<<nb, 256, 0, stream>>>(cnt, start, blks, n);
  scan_partials<<<1, 512, 0, stream>>>(blks, nb);
  add_offsets<<<nb, 256, 0, stream>>>(start, blks, n);
  edge_pass2<<<eb, 256, 0, stream>>>(ei, ew, deg, start, cur, srow, snorm, E);

  const int gs128 = (n + 1) / 2;  // spmm_w128 grid
  const int gs26 = (n + 7) / 8;   // spmm_w26 grid

  // ---- Layer 1: x (n x 26) -> B0 (n x 128), ELU ----
  launch_gemm_n128(x, NCLS, W1 + 0 * NCLS * HID, B0, n, NCLS, b1, 1, 0, stream);
  spmm_w26<<<gs26, 256, 0, stream>>>(srow, snorm, start, cnt, x, p26a, n);
  launch_gemm_n128(p26a, NCLS, W1 + 1 * NCLS * HID, B0, n, NCLS, nullptr, 0, 0, stream);
  spmm_w26<<<gs26, 256, 0, stream>>>(srow, snorm, start, cnt, p26a, p26b, n);
  launch_gemm_n128(p26b, NCLS, W1 + 2 * NCLS * HID, B0, n, NCLS, nullptr, 0, 0, stream);
  spmm_w26<<<gs26, 256, 0, stream>>>(srow, snorm, start, cnt, p26b, p26a, n);
  launch_gemm_n128(p26a, NCLS, W1 + 3 * NCLS * HID, B0, n, NCLS, nullptr, 0, 1, stream);

  // ---- Layer 2: B0 (n x 128) -> B1 (n x 128), ELU ----
  launch_gemm_n128(B0, HID, W2 + 0 * HID * HID, B1, n, HID, b2, 1, 0, stream);
  spmm_w128<<<gs128, 256, 0, stream>>>(srow, snorm, start, cnt, B0, B2, n);
  launch_gemm_n128(B2, HID, W2 + 1 * HID * HID, B1, n, HID, nullptr, 0, 0, stream);
  spmm_w128<<<gs128, 256, 0, stream>>>(srow, snorm, start, cnt, B2, B0, n);  // B0 (old h) dead
  launch_gemm_n128(B0, HID, W2 + 2 * HID * HID, B1, n, HID, nullptr, 0, 0, stream);
  spmm_w128<<<gs128, 256, 0, stream>>>(srow, snorm, start, cnt, B0, B2, n);
  launch_gemm_n128(B2, HID, W2 + 3 * HID * HID, B1, n, HID, nullptr, 0, 1, stream);

  // ---- Layer 3: B1 (n x 128) -> out (n x 26) ----
  launch_gemm_n26(B1, HID, W3 + 0 * HID * NCLS, out, n, HID, b3, 1, 0, stream);
  spmm_w128<<<gs128, 256, 0, stream>>>(srow, snorm, start, cnt, B1, B0, n);
  launch_gemm_n26(B0, HID, W3 + 1 * HID * NCLS, out, n, HID, nullptr, 0, 0, stream);
  spmm_w128<<<gs128, 256, 0, stream>>>(srow, snorm, start, cnt, B0, B2, n);
  launch_gemm_n26(B2, HID, W3 + 2 * HID * NCLS, out, n, HID, nullptr, 0, 0, stream);
  spmm_w128<<<gs128, 256, 0, stream>>>(srow, snorm, start, cnt, B2, B0, n);
  launch_gemm_n26(B0, HID, W3 + 3 * HID * NCLS, out, n, HID, nullptr, 0, 0, stream);
}

// Round 2
// 2317.739 us; speedup vs baseline: 1.6189x; 1.6189x over previous
//
#include <hip/hip_runtime.h>

#define NCLS 26
#define HID 128
typedef unsigned short ushort_t;
typedef unsigned int uint_t;

// ---------------- bf16 helpers (ushort storage) ----------------
static __device__ __forceinline__ float b2f(ushort_t h) {
  return __uint_as_float(((uint_t)h) << 16);
}
static __device__ __forceinline__ ushort_t f2b(float f) {
  uint_t u = __float_as_uint(f);
  uint_t r = (u + 0x7fffu + ((u >> 16) & 1u)) >> 16;
  return (ushort_t)r;
}
static __device__ __forceinline__ uint_t pack2(float f0, float f1) {
  return (uint_t)f2b(f0) | ((uint_t)f2b(f1) << 16);
}

// ---------------- preprocessing kernels ----------------

__global__ void edge_pass1(const int* __restrict__ ei, const float* __restrict__ ew,
                           float* __restrict__ deg, int* __restrict__ cnt, int E) {
  int e = blockIdx.x * 256 + threadIdx.x;
  if (e >= E) return;
  int c = ei[E + e];
  atomicAdd(&deg[c], ew[e]);
  atomicAdd(&cnt[c], 1);
}

__global__ void dinv_kernel(float* __restrict__ deg, int n) {
  int i = blockIdx.x * 256 + threadIdx.x;
  if (i >= n) return;
  float d = deg[i];
  deg[i] = d > 0.f ? rsqrtf(fmaxf(d, 1e-12f)) : 0.f;
}

__global__ void scan_block(const int* __restrict__ cnt, int* __restrict__ excl,
                           int* __restrict__ blksum, int n) {
  __shared__ int s[256];
  int g = blockIdx.x * 256 + threadIdx.x;
  int v = (g < n) ? cnt[g] : 0;
  s[threadIdx.x] = v;
  __syncthreads();
  for (int off = 1; off < 256; off <<= 1) {
    int t = (threadIdx.x >= (unsigned)off) ? s[threadIdx.x - off] : 0;
    __syncthreads();
    s[threadIdx.x] += t;
    __syncthreads();
  }
  if (g < n) excl[g] = s[threadIdx.x] - v;
  if (threadIdx.x == 255) blksum[blockIdx.x] = s[255];
}

__global__ void scan_partials(int* __restrict__ blksum, int nb) {
  __shared__ int s[512];
  int t = threadIdx.x;
  int v = (t < nb) ? blksum[t] : 0;
  s[t] = v;
  __syncthreads();
  for (int off = 1; off < 512; off <<= 1) {
    int u = (t >= off) ? s[t - off] : 0;
    __syncthreads();
    s[t] += u;
    __syncthreads();
  }
  if (t < nb) blksum[t] = s[t] - v;
}

__global__ void add_offsets(int* __restrict__ excl, const int* __restrict__ blksum, int n) {
  int g = blockIdx.x * 256 + threadIdx.x;
  if (g < n) excl[g] += blksum[blockIdx.x];
}

__global__ void edge_pass2(const int* __restrict__ ei, const float* __restrict__ ew,
                           const float* __restrict__ dinv, const int* __restrict__ start,
                           int* __restrict__ cur, int* __restrict__ srow,
                           float* __restrict__ snorm, int E) {
  int e = blockIdx.x * 256 + threadIdx.x;
  if (e >= E) return;
  int r = ei[e], c = ei[E + e];
  float nrm = dinv[r] * ew[e] * dinv[c];
  int p = start[c] + atomicAdd(&cur[c], 1);
  srow[p] = r;
  snorm[p] = nrm;
}

__global__ void convert_f2b(const float* __restrict__ in, uint_t* __restrict__ out, int ndw) {
  int i = blockIdx.x * 256 + threadIdx.x;
  if (i >= ndw) return;
  out[i] = pack2(in[2 * i], in[2 * i + 1]);
}

// ---------------- SpMM (pull, CSR by destination, bf16 in/out) ----------------

// width 128 bf16: 256 threads = 4 nodes x 64 lanes; lane handles 2 features (1 dword)
__global__ void spmm128_bf(const int* __restrict__ srow, const float* __restrict__ snorm,
                           const int* __restrict__ start, const int* __restrict__ cnt,
                           const uint_t* __restrict__ in, uint_t* __restrict__ out, int n) {
  int node = blockIdx.x * 4 + (threadIdx.x >> 6);
  int lane = threadIdx.x & 63;
  if (node >= n) return;
  int s = start[node], m = cnt[node];
  float a0 = 0.f, a1 = 0.f;
  for (int e = s; e < s + m; ++e) {
    float w = snorm[e];
    uint_t v = in[srow[e] * 64 + lane];
    a0 += w * b2f((ushort_t)(v & 0xffffu));
    a1 += w * b2f((ushort_t)(v >> 16));
  }
  out[node * 64 + lane] = pack2(a0, a1);
}

// width 26 bf16: 256 threads = 16 nodes x 16 lanes; lanes 0..12 each handle 1 dword (2 feats)
// optional bf16 "add" term (Horner): out = add + A*in
__global__ void spmm26_bf(const int* __restrict__ srow, const float* __restrict__ snorm,
                          const int* __restrict__ start, const int* __restrict__ cnt,
                          const uint_t* __restrict__ in, const uint_t* __restrict__ add,
                          uint_t* __restrict__ out, int n) {
  int node = blockIdx.x * 16 + (threadIdx.x >> 4);
  int lane = threadIdx.x & 15;
  if (node >= n || lane >= 13) return;
  int s = start[node], m = cnt[node];
  float a0 = 0.f, a1 = 0.f;
  for (int e = s; e < s + m; ++e) {
    float w = snorm[e];
    uint_t v = in[srow[e] * 13 + lane];
    a0 += w * b2f((ushort_t)(v & 0xffffu));
    a1 += w * b2f((ushort_t)(v >> 16));
  }
  if (add) {
    uint_t v = add[node * 13 + lane];
    a0 += b2f((ushort_t)(v & 0xffffu));
    a1 += b2f((ushort_t)(v >> 16));
  }
  out[node * 13 + lane] = pack2(a0, a1);
}

// final Horner step: out_f32 += A*in  (out holds z0 fp32, becomes the model output)
__global__ void spmm26_addf(const int* __restrict__ srow, const float* __restrict__ snorm,
                            const int* __restrict__ start, const int* __restrict__ cnt,
                            const uint_t* __restrict__ in, float* __restrict__ out, int n) {
  int node = blockIdx.x * 16 + (threadIdx.x >> 4);
  int lane = threadIdx.x & 15;
  if (node >= n || lane >= 13) return;
  int s = start[node], m = cnt[node];
  float a0 = 0.f, a1 = 0.f;
  for (int e = s; e < s + m; ++e) {
    float w = snorm[e];
    uint_t v = in[srow[e] * 13 + lane];
    a0 += w * b2f((ushort_t)(v & 0xffffu));
    a1 += w * b2f((ushort_t)(v >> 16));
  }
  out[node * 26 + 2 * lane] += a0;
  out[node * 26 + 2 * lane + 1] += a1;
}

// ---------------- GEMM: bf16 A (n x K) @ fp32 W (K x N), fp32 C state ----------------
// mode bits: 1 = init (bias or 0 instead of reading Cf), 2 = ELU, 4 = write bf16 to Cb

template <int BM, int BN, int BK, int TM, int TN>
__global__ __launch_bounds__(256) void gemm_bf(
    const ushort_t* __restrict__ A, int lda, const float* __restrict__ B, int ldb,
    float* __restrict__ Cf, uint_t* __restrict__ Cb, int ldc, int M, int N, int K,
    const float* __restrict__ bias, int mode) {
  __shared__ float As[BK][BM + 1];
  __shared__ float Bs[BK][BN + 1];
  const int tid = threadIdx.x;
  const int tcols = BN / TN;
  const int tx = tid % tcols;
  const int ty = tid / tcols;
  const int row0 = blockIdx.x * BM;
  const int col0 = blockIdx.y * BN;

  float acc[TM][TN];
#pragma unroll
  for (int i = 0; i < TM; ++i)
#pragma unroll
    for (int j = 0; j < TN; ++j) acc[i][j] = 0.f;

  for (int k0 = 0; k0 < K; k0 += BK) {
    for (int idx = tid; idx < BM * BK; idx += 256) {
      int m = idx / BK, kk = idx % BK;
      int gm = row0 + m, gk = k0 + kk;
      As[kk][m] = (gm < M && gk < K) ? b2f(A[(size_t)gm * lda + gk]) : 0.f;
    }
    for (int idx = tid; idx < BK * BN; idx += 256) {
      int kk = idx / BN, nn = idx % BN;
      int gk = k0 + kk, gn = col0 + nn;
      Bs[kk][nn] = (gk < K && gn < N) ? B[gk * ldb + gn] : 0.f;
    }
    __syncthreads();
#pragma unroll
    for (int kk = 0; kk < BK; ++kk) {
      float a[TM], b[TN];
#pragma unroll
      for (int i = 0; i < TM; ++i) a[i] = As[kk][ty * TM + i];
#pragma unroll
      for (int j = 0; j < TN; ++j) b[j] = Bs[kk][tx * TN + j];
#pragma unroll
      for (int i = 0; i < TM; ++i)
#pragma unroll
        for (int j = 0; j < TN; ++j) acc[i][j] += a[i] * b[j];
    }
    __syncthreads();
  }

#pragma unroll
  for (int i = 0; i < TM; ++i) {
    int gm = row0 + ty * TM + i;
    if (gm >= M) continue;
#pragma unroll
    for (int j = 0; j < TN; ++j) {
      int gn = col0 + tx * TN + j;
      if (gn >= N) continue;
      float v = (mode & 1) ? (bias ? bias[gn] : 0.f) : Cf[(size_t)gm * ldc + gn];
      v += acc[i][j];
      if (mode & 2) v = v > 0.f ? v : (expf(v) - 1.f);
      if (mode & 4) {
        // bf16 output: pack pairwise. TN even and tx*TN even => gn even pairs align.
        // write each half via 16-bit store to avoid cross-thread pairing complexity
        ((ushort_t*)Cb)[(size_t)gm * ldc + gn] = f2b(v);
      } else {
        Cf[(size_t)gm * ldc + gn] = v;
      }
    }
  }
}

static void gemm_n128(const ushort_t* A, int lda, const float* W, float* Cf, uint_t* Cb,
                      int M, int K, const float* bias, int mode, hipStream_t stream) {
  dim3 grid((M + 63) / 64, 1);
  gemm_bf<64, 128, 32, 4, 8><<<grid, 256, 0, stream>>>(A, lda, W, HID, Cf, Cb, HID, M, HID, K,
                                                       bias, mode);
}

static void gemm_n26(const ushort_t* A, int lda, const float* W, float* Cf, uint_t* Cb,
                     int M, int K, const float* bias, int mode, hipStream_t stream) {
  dim3 grid((M + 127) / 128, 1);
  gemm_bf<128, 32, 32, 8, 2><<<grid, 256, 0, stream>>>(A, lda, W, NCLS, Cf, Cb, NCLS, M, NCLS, K,
                                                       bias, mode);
}

// ---------------- launcher ----------------

extern "C" void kernel_launch(void* const* d_in, const int* in_sizes, int n_in,
                              void* d_out, int out_size, void* d_ws, size_t ws_size,
                              hipStream_t stream) {
  const float* x  = (const float*)d_in[0];
  const int*   ei = (const int*)d_in[1];
  const float* ew = (const float*)d_in[2];
  const float* W1 = (const float*)d_in[3];
  const float* b1 = (const float*)d_in[4];
  const float* W2 = (const float*)d_in[5];
  const float* b2 = (const float*)d_in[6];
  const float* W3 = (const float*)d_in[7];
  const float* b3 = (const float*)d_in[8];
  float* out = (float*)d_out;

  const int n = in_sizes[0] / NCLS;  // 100000
  const int E = in_sizes[2];         // 1600000

  char* w = (char*)d_ws;
  auto alloc = [&](size_t bytes) {
    char* p = w;
    w += (bytes + 255) / 256 * 256;
    return p;
  };
  // fp32 GEMM accumulator state (n x 128)
  float* Cf    = (float*)alloc((size_t)n * HID * 4);
  // bf16 node features (n x 128), stored as dwords (64 per node)
  uint_t* H0   = (uint_t*)alloc((size_t)n * 64 * 4);
  uint_t* P1   = (uint_t*)alloc((size_t)n * 64 * 4);
  uint_t* P2   = (uint_t*)alloc((size_t)n * 64 * 4);
  // bf16 width-26 buffers (13 dwords per node)
  uint_t* xb   = (uint_t*)alloc((size_t)n * 13 * 4);
  uint_t* qa   = (uint_t*)alloc((size_t)n * 13 * 4);
  uint_t* qb   = (uint_t*)alloc((size_t)n * 13 * 4);
  uint_t* z1b  = (uint_t*)alloc((size_t)n * 13 * 4);
  uint_t* z2b  = (uint_t*)alloc((size_t)n * 13 * 4);
  uint_t* z3b  = (uint_t*)alloc((size_t)n * 13 * 4);
  // graph CSR
  int*   srow  = (int*)alloc((size_t)E * 4);
  float* snorm = (float*)alloc((size_t)E * 4);
  int*   start = (int*)alloc((size_t)n * 4);
  int*   cnt   = (int*)alloc((size_t)n * 4);
  int*   cur   = (int*)alloc((size_t)n * 4);
  float* deg   = (float*)alloc((size_t)n * 4);
  int*   blks  = (int*)alloc(4096 * 4);

  const int eb = (E + 255) / 256;
  const int nb = (n + 255) / 256;  // 391 blocks (fits 512-thread partials scan)

  hipMemsetAsync(deg, 0, (size_t)n * 4, stream);
  hipMemsetAsync(cnt, 0, (size_t)n * 4, stream);
  hipMemsetAsync(cur, 0, (size_t)n * 4, stream);

  edge_pass1<<<eb, 256, 0, stream>>>(ei, ew, deg, cnt, E);
  dinv_kernel<<<nb, 256, 0, stream>>>(deg, n);
  scan_block<<<nb, 256, 0, stream>>>(cnt, start, blks, n);
  scan_partials<<<1, 512, 0, stream>>>(blks, nb);
  add_offsets<<<nb, 256, 0, stream>>>(start, blks, n);
  edge_pass2<<<eb, 256, 0, stream>>>(ei, ew, deg, start, cur, srow, snorm, E);

  convert_f2b<<<(n * 13 + 255) / 256, 256, 0, stream>>>(x, xb, n * 13);

  const int g128 = (n + 3) / 4;    // spmm128_bf grid
  const int g26  = (n + 15) / 16;  // spmm26 grid

  // ---- Layer 1: xb (n x 26 bf16) -> H0 (n x 128 bf16), ELU ----
  gemm_n128((const ushort_t*)xb, NCLS, W1 + 0 * NCLS * HID, Cf, nullptr, n, NCLS, b1, 1, stream);
  spmm26_bf<<<g26, 256, 0, stream>>>(srow, snorm, start, cnt, xb, nullptr, qa, n);
  gemm_n128((const ushort_t*)qa, NCLS, W1 + 1 * NCLS * HID, Cf, nullptr, n, NCLS, nullptr, 0, stream);
  spmm26_bf<<<g26, 256, 0, stream>>>(srow, snorm, start, cnt, qa, nullptr, qb, n);
  gemm_n128((const ushort_t*)qb, NCLS, W1 + 2 * NCLS * HID, Cf, nullptr, n, NCLS, nullptr, 0, stream);
  spmm26_bf<<<g26, 256, 0, stream>>>(srow, snorm, start, cnt, qb, nullptr, qa, n);
  gemm_n128((const ushort_t*)qa, NCLS, W1 + 3 * NCLS * HID, Cf, H0, n, NCLS, nullptr, 0 | 2 | 4, stream);

  // ---- Layer 2: H0 (n x 128 bf16) -> H0 (overwritten, n x 128 bf16), ELU ----
  gemm_n128((const ushort_t*)H0, HID, W2 + 0 * HID * HID, Cf, nullptr, n, HID, b2, 1, stream);
  spmm128_bf<<<g128, 256, 0, stream>>>(srow, snorm, start, cnt, H0, P1, n);
  gemm_n128((const ushort_t*)P1, HID, W2 + 1 * HID * HID, Cf, nullptr, n, HID, nullptr, 0, stream);
  spmm128_bf<<<g128, 256, 0, stream>>>(srow, snorm, start, cnt, P1, P2, n);
  gemm_n128((const ushort_t*)P2, HID, W2 + 2 * HID * HID, Cf, nullptr, n, HID, nullptr, 0, stream);
  spmm128_bf<<<g128, 256, 0, stream>>>(srow, snorm, start, cnt, P2, P1, n);
  gemm_n128((const ushort_t*)P1, HID, W2 + 3 * HID * HID, Cf, H0, n, HID, nullptr, 0 | 2 | 4, stream);

  // ---- Layer 3 (Horner in width-26 space): out = z0 + A(z1 + A(z2 + A z3)) ----
  gemm_n26((const ushort_t*)H0, HID, W3 + 0 * HID * NCLS, out, nullptr, n, HID, b3, 1, stream);          // z0 -> out (fp32)
  gemm_n26((const ushort_t*)H0, HID, W3 + 1 * HID * NCLS, nullptr, z1b, n, HID, nullptr, 1 | 4, stream); // z1 bf16
  gemm_n26((const ushort_t*)H0, HID, W3 + 2 * HID * NCLS, nullptr, z2b, n, HID, nullptr, 1 | 4, stream); // z2 bf16
  gemm_n26((const ushort_t*)H0, HID, W3 + 3 * HID * NCLS, nullptr, z3b, n, HID, nullptr, 1 | 4, stream); // z3 bf16

  spmm26_bf<<<g26, 256, 0, stream>>>(srow, snorm, start, cnt, z3b, z2b, qa, n);  // qa = z2 + A z3
  spmm26_bf<<<g26, 256, 0, stream>>>(srow, snorm, start, cnt, qa, z1b, qb, n);   // qb = z1 + A qa
  spmm26_addf<<<g26, 256, 0, stream>>>(srow, snorm, start, cnt, qb, out, n);     // out += A qb
}

// Round 3
// 1146.090 us; speedup vs baseline: 3.2738x; 2.0223x over previous
//
#include <hip/hip_runtime.h>

#define NCLS 26
#define HID 128
typedef unsigned short ushort_t;
typedef unsigned int uint_t;

typedef __bf16 bf16x8 __attribute__((ext_vector_type(8)));
typedef float f32x4 __attribute__((ext_vector_type(4)));
typedef unsigned int u32x4 __attribute__((ext_vector_type(4)));

// ---------------- bf16 helpers (ushort storage) ----------------
static __device__ __forceinline__ float b2f(ushort_t h) {
  return __uint_as_float(((uint_t)h) << 16);
}
static __device__ __forceinline__ ushort_t f2b(float f) {
  uint_t u = __float_as_uint(f);
  uint_t r = (u + 0x7fffu + ((u >> 16) & 1u)) >> 16;
  return (ushort_t)r;
}
static __device__ __forceinline__ uint_t pack2(float f0, float f1) {
  return (uint_t)f2b(f0) | ((uint_t)f2b(f1) << 16);
}
static __device__ __forceinline__ bf16x8 ld_frag(const ushort_t* p) {
  u32x4 v = *reinterpret_cast<const u32x4*>(p);
  return __builtin_bit_cast(bf16x8, v);
}

// ---------------- preprocessing kernels ----------------

__global__ void edge_pass1(const int* __restrict__ ei, const float* __restrict__ ew,
                           float* __restrict__ deg, int* __restrict__ cnt, int E) {
  int e = blockIdx.x * 256 + threadIdx.x;
  if (e >= E) return;
  int c = ei[E + e];
  atomicAdd(&deg[c], ew[e]);
  atomicAdd(&cnt[c], 1);
}

__global__ void dinv_kernel(float* __restrict__ deg, int n) {
  int i = blockIdx.x * 256 + threadIdx.x;
  if (i >= n) return;
  float d = deg[i];
  deg[i] = d > 0.f ? rsqrtf(fmaxf(d, 1e-12f)) : 0.f;
}

__global__ void scan_block(const int* __restrict__ cnt, int* __restrict__ excl,
                           int* __restrict__ blksum, int n) {
  __shared__ int s[256];
  int g = blockIdx.x * 256 + threadIdx.x;
  int v = (g < n) ? cnt[g] : 0;
  s[threadIdx.x] = v;
  __syncthreads();
  for (int off = 1; off < 256; off <<= 1) {
    int t = (threadIdx.x >= (unsigned)off) ? s[threadIdx.x - off] : 0;
    __syncthreads();
    s[threadIdx.x] += t;
    __syncthreads();
  }
  if (g < n) excl[g] = s[threadIdx.x] - v;
  if (threadIdx.x == 255) blksum[blockIdx.x] = s[255];
}

__global__ void scan_partials(int* __restrict__ blksum, int nb) {
  __shared__ int s[512];
  int t = threadIdx.x;
  int v = (t < nb) ? blksum[t] : 0;
  s[t] = v;
  __syncthreads();
  for (int off = 1; off < 512; off <<= 1) {
    int u = (t >= off) ? s[t - off] : 0;
    __syncthreads();
    s[t] += u;
    __syncthreads();
  }
  if (t < nb) blksum[t] = s[t] - v;
}

__global__ void add_offsets(int* __restrict__ excl, const int* __restrict__ blksum, int n) {
  int g = blockIdx.x * 256 + threadIdx.x;
  if (g < n) excl[g] += blksum[blockIdx.x];
}

__global__ void edge_pass2(const int* __restrict__ ei, const float* __restrict__ ew,
                           const float* __restrict__ dinv, const int* __restrict__ start,
                           int* __restrict__ cur, int* __restrict__ srow,
                           float* __restrict__ snorm, int E) {
  int e = blockIdx.x * 256 + threadIdx.x;
  if (e >= E) return;
  int r = ei[e], c = ei[E + e];
  float nrm = dinv[r] * ew[e] * dinv[c];
  int p = start[c] + atomicAdd(&cur[c], 1);
  srow[p] = r;
  snorm[p] = nrm;
}

// x (n x 26 fp32) -> padded bf16 (n x 32), zeros in cols 26..31
__global__ void convert_x(const float* __restrict__ in, uint_t* __restrict__ out, int n) {
  int idx = blockIdx.x * 256 + threadIdx.x;
  if (idx >= n * 16) return;
  int node = idx >> 4, lane = idx & 15;
  float f0 = 0.f, f1 = 0.f;
  if (lane < 13) {
    f0 = in[node * 26 + 2 * lane];
    f1 = in[node * 26 + 2 * lane + 1];
  }
  out[idx] = pack2(f0, f1);
}

// ---------------- W swizzle into MFMA B-fragment order ----------------
// out layout: [t (global kstep)][j 0..7][lane 0..63][i 0..7] bf16
// fragment element = B[k][col], k = 32*t_in_src + 8*(lane>>4) + i, col = 16*j + (lane&15)

// K-concat: W fp32 [nsrc][kwv][128] ; ksteps_per_src = ceil-pad, k >= kwv -> 0
__global__ void swizzleW_kcat(const float* __restrict__ W, ushort_t* __restrict__ out,
                              int ksps, int kwv, int nsrc) {
  int idx = blockIdx.x * 256 + threadIdx.x;
  int total = nsrc * ksps * 4096;
  if (idx >= total) return;
  int i = idx & 7, l = (idx >> 3) & 63, j = (idx >> 9) & 7, t = idx >> 12;
  int s = t / ksps, tt = t - s * ksps;
  int k = tt * 32 + 8 * (l >> 4) + i;
  int col = 16 * j + (l & 15);
  float v = (k < kwv) ? W[((size_t)s * kwv + k) * 128 + col] : 0.f;
  out[idx] = f2b(v);
}

// N-slot (layer 3): W3 fp32 [4][128][26] -> K=128, N=128 (4 slots of 32, cols>=26 zero)
__global__ void swizzleW_nslot(const float* __restrict__ W, ushort_t* __restrict__ out) {
  int idx = blockIdx.x * 256 + threadIdx.x;
  if (idx >= 4 * 4096) return;
  int i = idx & 7, l = (idx >> 3) & 63, j = (idx >> 9) & 7, t = idx >> 12;
  int k = t * 32 + 8 * (l >> 4) + i;
  int col = 16 * j + (l & 15);
  int s = col >> 5, c = col & 31;
  float v = (c < 26) ? W[((size_t)s * 128 + k) * 26 + c] : 0.f;
  out[idx] = f2b(v);
}

// ---------------- SpMM (pull, CSR by destination, bf16) ----------------

// width 128: 256 threads = 4 nodes x 64 lanes; lane handles 1 dword (2 feats)
__global__ void spmm128_bf(const int* __restrict__ srow, const float* __restrict__ snorm,
                           const int* __restrict__ start, const int* __restrict__ cnt,
                           const uint_t* __restrict__ in, uint_t* __restrict__ out, int n) {
  int node = blockIdx.x * 4 + (threadIdx.x >> 6);
  int lane = threadIdx.x & 63;
  if (node >= n) return;
  int s = start[node], m = cnt[node];
  float a0 = 0.f, a1 = 0.f;
  for (int e = s; e < s + m; ++e) {
    float w = snorm[e];
    uint_t v = in[srow[e] * 64 + lane];
    a0 += w * b2f((ushort_t)(v & 0xffffu));
    a1 += w * b2f((ushort_t)(v >> 16));
  }
  out[node * 64 + lane] = pack2(a0, a1);
}

// width 26 padded to 32: 256 threads = 16 nodes x 16 lanes (13 gather, 3 write zeros)
// optional bf16 "add" term: out = add + A*in   (all buffers stride 16 dwords)
__global__ void spmm26_bf(const int* __restrict__ srow, const float* __restrict__ snorm,
                          const int* __restrict__ start, const int* __restrict__ cnt,
                          const uint_t* __restrict__ in, const uint_t* __restrict__ add,
                          uint_t* __restrict__ out, int n) {
  int node = blockIdx.x * 16 + (threadIdx.x >> 4);
  int lane = threadIdx.x & 15;
  if (node >= n) return;
  float a0 = 0.f, a1 = 0.f;
  if (lane < 13) {
    int s = start[node], m = cnt[node];
    for (int e = s; e < s + m; ++e) {
      float w = snorm[e];
      uint_t v = in[srow[e] * 16 + lane];
      a0 += w * b2f((ushort_t)(v & 0xffffu));
      a1 += w * b2f((ushort_t)(v >> 16));
    }
    if (add) {
      uint_t v = add[node * 16 + lane];
      a0 += b2f((ushort_t)(v & 0xffffu));
      a1 += b2f((ushort_t)(v >> 16));
    }
  }
  out[node * 16 + lane] = pack2(a0, a1);
}

// final Horner step: out_f32 (n x 26) += A*in
__global__ void spmm26_addf(const int* __restrict__ srow, const float* __restrict__ snorm,
                            const int* __restrict__ start, const int* __restrict__ cnt,
                            const uint_t* __restrict__ in, float* __restrict__ out, int n) {
  int node = blockIdx.x * 16 + (threadIdx.x >> 4);
  int lane = threadIdx.x & 15;
  if (node >= n || lane >= 13) return;
  int s = start[node], m = cnt[node];
  float a0 = 0.f, a1 = 0.f;
  for (int e = s; e < s + m; ++e) {
    float w = snorm[e];
    uint_t v = in[srow[e] * 16 + lane];
    a0 += w * b2f((ushort_t)(v & 0xffffu));
    a1 += w * b2f((ushort_t)(v >> 16));
  }
  out[node * 26 + 2 * lane] += a0;
  out[node * 26 + 2 * lane + 1] += a1;
}

// ---------------- fused MFMA GEMM ----------------
// C(n x 128) = [A0|A1|A2|A3] (each n x KW bf16) @ Wswz (+bias)
// EPI 0: ELU, write bf16 n x 128 to outb
// EPI 1: layer-3 slots: slot0 -> outf (n x 26 fp32, +bias); slots 1..3 -> outb (3 x n x 32 bf16)
// block: 256 threads = 4 waves; wave w owns rows [blk*64 + w*16, +16), all 128 cols.
template <int KW, int NSRC, int EPI>
__global__ __launch_bounds__(256) void mfma_gemm(
    const ushort_t* __restrict__ A0, const ushort_t* __restrict__ A1,
    const ushort_t* __restrict__ A2, const ushort_t* __restrict__ A3,
    const ushort_t* __restrict__ Wswz, const float* __restrict__ bias,
    ushort_t* __restrict__ outb, float* __restrict__ outf, int n) {
  constexpr int KSPS = KW / 32;
  constexpr int KSTEPS = NSRC * KSPS;
  const int w = threadIdx.x >> 6;
  const int l = threadIdx.x & 63;
  const int row0 = blockIdx.x * 64 + w * 16;
  const int arow = row0 + (l & 15);
  const int arow_c = arow < n ? arow : (n - 1);
  const int koff = 8 * (l >> 4);  // elements

  f32x4 acc[8];
#pragma unroll
  for (int j = 0; j < 8; ++j) acc[j] = (f32x4){0.f, 0.f, 0.f, 0.f};

  const ushort_t* const srcs[4] = {A0, A1, A2, A3};

#pragma unroll
  for (int t = 0; t < KSTEPS; ++t) {
    const int s = t / KSPS;
    const int tt = t - s * KSPS;
    bf16x8 af = ld_frag(srcs[s] + (size_t)arow_c * KW + tt * 32 + koff);
    const ushort_t* wp = Wswz + ((size_t)t * 8 * 64 + l) * 8;
#pragma unroll
    for (int j = 0; j < 8; ++j) {
      bf16x8 bfr = ld_frag(wp + (size_t)j * 64 * 8);
      acc[j] = __builtin_amdgcn_mfma_f32_16x16x32_bf16(af, bfr, acc[j], 0, 0, 0);
    }
  }

  const int crow0 = row0 + 4 * (l >> 4);  // rows crow0..crow0+3 (reg r)
  const int ccol = l & 15;
#pragma unroll
  for (int j = 0; j < 8; ++j) {
    if (EPI == 0) {
      int col = 16 * j + ccol;
      float bi = bias[col];
#pragma unroll
      for (int r = 0; r < 4; ++r) {
        int row = crow0 + r;
        if (row >= n) continue;
        float v = acc[j][r] + bi;
        v = v > 0.f ? v : (__expf(v) - 1.f);
        outb[(size_t)row * 128 + col] = f2b(v);
      }
    } else {
      int slot = j >> 1;
      int c = 16 * (j & 1) + ccol;
#pragma unroll
      for (int r = 0; r < 4; ++r) {
        int row = crow0 + r;
        if (row >= n) continue;
        float v = acc[j][r];
        if (slot == 0) {
          if (c < 26) outf[(size_t)row * 26 + c] = v + bias[c];
        } else {
          outb[((size_t)(slot - 1) * n + row) * 32 + c] = f2b(v);
        }
      }
    }
  }
}

// ---------------- launcher ----------------

extern "C" void kernel_launch(void* const* d_in, const int* in_sizes, int n_in,
                              void* d_out, int out_size, void* d_ws, size_t ws_size,
                              hipStream_t stream) {
  const float* x  = (const float*)d_in[0];
  const int*   ei = (const int*)d_in[1];
  const float* ew = (const float*)d_in[2];
  const float* W1 = (const float*)d_in[3];
  const float* b1 = (const float*)d_in[4];
  const float* W2 = (const float*)d_in[5];
  const float* b2 = (const float*)d_in[6];
  const float* W3 = (const float*)d_in[7];
  const float* b3 = (const float*)d_in[8];
  float* out = (float*)d_out;

  const int n = in_sizes[0] / NCLS;  // 100000
  const int E = in_sizes[2];         // 1600000

  char* w = (char*)d_ws;
  auto alloc = [&](size_t bytes) {
    char* p = w;
    w += (bytes + 255) / 256 * 256;
    return p;
  };
  // width-128 bf16 feature buffers (64 dwords per node)
  uint_t* H0 = (uint_t*)alloc((size_t)n * 64 * 4);
  uint_t* P1 = (uint_t*)alloc((size_t)n * 64 * 4);
  uint_t* P2 = (uint_t*)alloc((size_t)n * 64 * 4);
  uint_t* P3 = (uint_t*)alloc((size_t)n * 64 * 4);
  uint_t* H1 = (uint_t*)alloc((size_t)n * 64 * 4);
  // width-32-padded bf16 buffers (16 dwords per node)
  uint_t* x32 = (uint_t*)alloc((size_t)n * 16 * 4);
  uint_t* q1  = (uint_t*)alloc((size_t)n * 16 * 4);
  uint_t* q2  = (uint_t*)alloc((size_t)n * 16 * 4);
  uint_t* q3  = (uint_t*)alloc((size_t)n * 16 * 4);
  uint_t* zb  = (uint_t*)alloc((size_t)n * 48 * 4);  // z1,z2,z3 each n x 32 bf16
  // swizzled weights
  ushort_t* Wz1 = (ushort_t*)alloc(4 * 4096 * 2);
  ushort_t* Wz2 = (ushort_t*)alloc(16 * 4096 * 2);
  ushort_t* Wz3 = (ushort_t*)alloc(4 * 4096 * 2);
  // graph CSR
  int*   srow  = (int*)alloc((size_t)E * 4);
  float* snorm = (float*)alloc((size_t)E * 4);
  int*   start = (int*)alloc((size_t)n * 4);
  int*   cnt   = (int*)alloc((size_t)n * 4);
  int*   cur   = (int*)alloc((size_t)n * 4);
  float* deg   = (float*)alloc((size_t)n * 4);
  int*   blks  = (int*)alloc(4096 * 4);

  const int eb = (E + 255) / 256;
  const int nb = (n + 255) / 256;  // 391 blocks (fits 512-thread partials scan)

  hipMemsetAsync(deg, 0, (size_t)n * 4, stream);
  hipMemsetAsync(cnt, 0, (size_t)n * 4, stream);
  hipMemsetAsync(cur, 0, (size_t)n * 4, stream);

  edge_pass1<<<eb, 256, 0, stream>>>(ei, ew, deg, cnt, E);
  dinv_kernel<<<nb, 256, 0, stream>>>(deg, n);
  scan_block<<<nb, 256, 0, stream>>>(cnt, start, blks, n);
  scan_partials<<<1, 512, 0, stream>>>(blks, nb);
  add_offsets<<<nb, 256, 0, stream>>>(start, blks, n);
  edge_pass2<<<eb, 256, 0, stream>>>(ei, ew, deg, start, cur, srow, snorm, E);

  convert_x<<<(n * 16 + 255) / 256, 256, 0, stream>>>(x, x32, n);
  swizzleW_kcat<<<(4 * 4096 + 255) / 256, 256, 0, stream>>>(W1, Wz1, 1, NCLS, 4);
  swizzleW_kcat<<<(16 * 4096 + 255) / 256, 256, 0, stream>>>(W2, Wz2, 4, HID, 4);
  swizzleW_nslot<<<(4 * 4096 + 255) / 256, 256, 0, stream>>>(W3, Wz3);

  const int g128 = (n + 3) / 4;
  const int g26  = (n + 15) / 16;
  const int gg   = (n + 63) / 64;  // mfma_gemm grid

  // ---- Layer 1: q_k = A^k x (width 32-padded), H0 = ELU([x|q1|q2|q3] @ W1cat + b1) ----
  spmm26_bf<<<g26, 256, 0, stream>>>(srow, snorm, start, cnt, x32, nullptr, q1, n);
  spmm26_bf<<<g26, 256, 0, stream>>>(srow, snorm, start, cnt, q1, nullptr, q2, n);
  spmm26_bf<<<g26, 256, 0, stream>>>(srow, snorm, start, cnt, q2, nullptr, q3, n);
  mfma_gemm<32, 4, 0><<<gg, 256, 0, stream>>>(
      (const ushort_t*)x32, (const ushort_t*)q1, (const ushort_t*)q2, (const ushort_t*)q3,
      Wz1, b1, (ushort_t*)H0, nullptr, n);

  // ---- Layer 2: P_k = A^k H0, H1 = ELU([H0|P1|P2|P3] @ W2cat + b2) ----
  spmm128_bf<<<g128, 256, 0, stream>>>(srow, snorm, start, cnt, H0, P1, n);
  spmm128_bf<<<g128, 256, 0, stream>>>(srow, snorm, start, cnt, P1, P2, n);
  spmm128_bf<<<g128, 256, 0, stream>>>(srow, snorm, start, cnt, P2, P3, n);
  mfma_gemm<128, 4, 0><<<gg, 256, 0, stream>>>(
      (const ushort_t*)H0, (const ushort_t*)P1, (const ushort_t*)P2, (const ushort_t*)P3,
      Wz2, b2, (ushort_t*)H1, nullptr, n);

  // ---- Layer 3: Z = H1 @ [W3_0|W3_1|W3_2|W3_3]; Horner out = z0+b3 + A(z1 + A(z2 + A z3)) ----
  mfma_gemm<128, 1, 1><<<gg, 256, 0, stream>>>(
      (const ushort_t*)H1, (const ushort_t*)H1, (const ushort_t*)H1, (const ushort_t*)H1,
      Wz3, b3, (ushort_t*)zb, out, n);

  uint_t* z1 = zb;
  uint_t* z2 = zb + (size_t)n * 16;
  uint_t* z3 = zb + (size_t)n * 32;
  spmm26_bf<<<g26, 256, 0, stream>>>(srow, snorm, start, cnt, z3, z2, q1, n);  // q1 = z2 + A z3
  spmm26_bf<<<g26, 256, 0, stream>>>(srow, snorm, start, cnt, q1, z1, q2, n);  // q2 = z1 + A q1
  spmm26_addf<<<g26, 256, 0, stream>>>(srow, snorm, start, cnt, q2, out, n);   // out += A q2
}

// Round 4
// 692.832 us; speedup vs baseline: 5.4156x; 1.6542x over previous
//
#include <hip/hip_runtime.h>

#define NCLS 26
#define HID 128
typedef unsigned short ushort_t;
typedef unsigned int uint_t;

typedef __bf16 bf16x8 __attribute__((ext_vector_type(8)));
typedef float f32x4 __attribute__((ext_vector_type(4)));
typedef unsigned int u32x4 __attribute__((ext_vector_type(4)));
typedef unsigned int u32x2 __attribute__((ext_vector_type(2)));

// ---------------- bf16 helpers (ushort storage) ----------------
static __device__ __forceinline__ float b2f(ushort_t h) {
  return __uint_as_float(((uint_t)h) << 16);
}
static __device__ __forceinline__ ushort_t f2b(float f) {
  uint_t u = __float_as_uint(f);
  uint_t r = (u + 0x7fffu + ((u >> 16) & 1u)) >> 16;
  return (ushort_t)r;
}
static __device__ __forceinline__ uint_t pack2(float f0, float f1) {
  return (uint_t)f2b(f0) | ((uint_t)f2b(f1) << 16);
}
static __device__ __forceinline__ bf16x8 ld_frag(const ushort_t* p) {
  u32x4 v = *reinterpret_cast<const u32x4*>(p);
  return __builtin_bit_cast(bf16x8, v);
}

// ---------------- preprocessing kernels ----------------

__global__ void edge_pass1(const int* __restrict__ ei, const float* __restrict__ ew,
                           float* __restrict__ deg, int* __restrict__ cnt, int E) {
  int e = blockIdx.x * 256 + threadIdx.x;
  if (e >= E) return;
  int c = ei[E + e];
  atomicAdd(&deg[c], ew[e]);
  atomicAdd(&cnt[c], 1);
}

__global__ void dinv_kernel(float* __restrict__ deg, int n) {
  int i = blockIdx.x * 256 + threadIdx.x;
  if (i >= n) return;
  float d = deg[i];
  deg[i] = d > 0.f ? rsqrtf(fmaxf(d, 1e-12f)) : 0.f;
}

__global__ void scan_block(const int* __restrict__ cnt, int* __restrict__ excl,
                           int* __restrict__ blksum, int n) {
  __shared__ int s[256];
  int g = blockIdx.x * 256 + threadIdx.x;
  int v = (g < n) ? cnt[g] : 0;
  s[threadIdx.x] = v;
  __syncthreads();
  for (int off = 1; off < 256; off <<= 1) {
    int t = (threadIdx.x >= (unsigned)off) ? s[threadIdx.x - off] : 0;
    __syncthreads();
    s[threadIdx.x] += t;
    __syncthreads();
  }
  if (g < n) excl[g] = s[threadIdx.x] - v;
  if (threadIdx.x == 255) blksum[blockIdx.x] = s[255];
}

__global__ void scan_partials(int* __restrict__ blksum, int nb) {
  __shared__ int s[512];
  int t = threadIdx.x;
  int v = (t < nb) ? blksum[t] : 0;
  s[t] = v;
  __syncthreads();
  for (int off = 1; off < 512; off <<= 1) {
    int u = (t >= off) ? s[t - off] : 0;
    __syncthreads();
    s[t] += u;
    __syncthreads();
  }
  if (t < nb) blksum[t] = s[t] - v;
}

__global__ void add_offsets(int* __restrict__ excl, const int* __restrict__ blksum, int n) {
  int g = blockIdx.x * 256 + threadIdx.x;
  if (g < n) excl[g] += blksum[blockIdx.x];
}

__global__ void edge_pass2(const int* __restrict__ ei, const float* __restrict__ ew,
                           const float* __restrict__ dinv, const int* __restrict__ start,
                           int* __restrict__ cur, int* __restrict__ srow,
                           float* __restrict__ snorm, int E) {
  int e = blockIdx.x * 256 + threadIdx.x;
  if (e >= E) return;
  int r = ei[e], c = ei[E + e];
  float nrm = dinv[r] * ew[e] * dinv[c];
  int p = start[c] + atomicAdd(&cur[c], 1);
  srow[p] = r;
  snorm[p] = nrm;
}

// x (n x 26 fp32) -> padded bf16 (n x 32), zeros in cols 26..31
__global__ void convert_x(const float* __restrict__ in, uint_t* __restrict__ out, int n) {
  int idx = blockIdx.x * 256 + threadIdx.x;
  if (idx >= n * 16) return;
  int node = idx >> 4, lane = idx & 15;
  float f0 = 0.f, f1 = 0.f;
  if (lane < 13) {
    f0 = in[node * 26 + 2 * lane];
    f1 = in[node * 26 + 2 * lane + 1];
  }
  out[idx] = pack2(f0, f1);
}

// ---------------- W swizzle into MFMA B-fragment order ----------------
// out layout: [t (global kstep)][j 0..7][lane 0..63][i 0..7] bf16
// fragment element = B[k][col], k = 32*t_in_src + 8*(lane>>4) + i, col = 16*j + (lane&15)

__global__ void swizzleW_kcat(const float* __restrict__ W, ushort_t* __restrict__ out,
                              int ksps, int kwv, int nsrc) {
  int idx = blockIdx.x * 256 + threadIdx.x;
  int total = nsrc * ksps * 4096;
  if (idx >= total) return;
  int i = idx & 7, l = (idx >> 3) & 63, j = (idx >> 9) & 7, t = idx >> 12;
  int s = t / ksps, tt = t - s * ksps;
  int k = tt * 32 + 8 * (l >> 4) + i;
  int col = 16 * j + (l & 15);
  float v = (k < kwv) ? W[((size_t)s * kwv + k) * 128 + col] : 0.f;
  out[idx] = f2b(v);
}

__global__ void swizzleW_nslot(const float* __restrict__ W, ushort_t* __restrict__ out) {
  int idx = blockIdx.x * 256 + threadIdx.x;
  if (idx >= 4 * 4096) return;
  int i = idx & 7, l = (idx >> 3) & 63, j = (idx >> 9) & 7, t = idx >> 12;
  int k = t * 32 + 8 * (l >> 4) + i;
  int col = 16 * j + (l & 15);
  int s = col >> 5, c = col & 31;
  float v = (c < 26) ? W[((size_t)s * 128 + k) * 26 + c] : 0.f;
  out[idx] = f2b(v);
}

// ---------------- SpMM (pull, CSR by destination, bf16) ----------------
// chunked: 8 edges' metadata loaded cooperatively, broadcast via shfl,
// gathers issued back-to-back for memory-level parallelism.

// width 128: one node per wave; 2 edges per inner iter (half-wave each, dwordx2/lane)
__global__ __launch_bounds__(256) void spmm128_bf(
    const int* __restrict__ srow, const float* __restrict__ snorm,
    const int* __restrict__ start, const int* __restrict__ cnt,
    const uint_t* __restrict__ in, uint_t* __restrict__ out, int n) {
  int node = blockIdx.x * 4 + (threadIdx.x >> 6);
  int lane = threadIdx.x & 63;
  if (node >= n) return;
  int s = start[node], m = cnt[node];
  int h = lane >> 5;   // which edge of the pair this half-wave handles
  int q = lane & 31;   // dword-pair index within the 64-dword row
  float a0 = 0.f, a1 = 0.f, a2 = 0.f, a3 = 0.f;
  for (int base = 0; base < m; base += 8) {
    int li = lane & 7;
    bool valid = base + li < m;
    int r = valid ? srow[s + base + li] : 0;
    float wv = valid ? snorm[s + base + li] : 0.f;
#pragma unroll
    for (int j = 0; j < 4; ++j) {
      int rj = __shfl(r, 2 * j + h);
      float wj = __shfl(wv, 2 * j + h);
      u32x2 v = *reinterpret_cast<const u32x2*>(in + (size_t)rj * 64 + 2 * q);
      a0 += wj * b2f((ushort_t)(v.x & 0xffffu));
      a1 += wj * b2f((ushort_t)(v.x >> 16));
      a2 += wj * b2f((ushort_t)(v.y & 0xffffu));
      a3 += wj * b2f((ushort_t)(v.y >> 16));
    }
  }
  a0 += __shfl_xor(a0, 32);
  a1 += __shfl_xor(a1, 32);
  a2 += __shfl_xor(a2, 32);
  a3 += __shfl_xor(a3, 32);
  if (h == 0) {
    u32x2 o;
    o.x = pack2(a0, a1);
    o.y = pack2(a2, a3);
    *reinterpret_cast<u32x2*>(out + (size_t)node * 64 + 2 * q) = o;
  }
}

// width 32-padded: 16 lanes per node (pad cols are zeros -> unconditional gathers exact)
__global__ __launch_bounds__(256) void spmm26_bf(
    const int* __restrict__ srow, const float* __restrict__ snorm,
    const int* __restrict__ start, const int* __restrict__ cnt,
    const uint_t* __restrict__ in, const uint_t* __restrict__ add,
    uint_t* __restrict__ out, int n) {
  int node = blockIdx.x * 16 + (threadIdx.x >> 4);
  int lane = threadIdx.x & 15;
  if (node >= n) return;
  int s = start[node], m = cnt[node];
  float a0 = 0.f, a1 = 0.f;
  for (int base = 0; base < m; base += 8) {
    int li = lane & 7;
    bool valid = base + li < m;
    int r = valid ? srow[s + base + li] : 0;
    float wv = valid ? snorm[s + base + li] : 0.f;
#pragma unroll
    for (int j = 0; j < 8; ++j) {
      int rj = __shfl(r, j, 16);
      float wj = __shfl(wv, j, 16);
      uint_t v = in[(size_t)rj * 16 + lane];
      a0 += wj * b2f((ushort_t)(v & 0xffffu));
      a1 += wj * b2f((ushort_t)(v >> 16));
    }
  }
  if (add) {
    uint_t v = add[(size_t)node * 16 + lane];
    a0 += b2f((ushort_t)(v & 0xffffu));
    a1 += b2f((ushort_t)(v >> 16));
  }
  out[(size_t)node * 16 + lane] = pack2(a0, a1);
}

// final Horner step: out_f32 (n x 26) += A*in
__global__ __launch_bounds__(256) void spmm26_addf(
    const int* __restrict__ srow, const float* __restrict__ snorm,
    const int* __restrict__ start, const int* __restrict__ cnt,
    const uint_t* __restrict__ in, float* __restrict__ out, int n) {
  int node = blockIdx.x * 16 + (threadIdx.x >> 4);
  int lane = threadIdx.x & 15;
  if (node >= n) return;
  int s = start[node], m = cnt[node];
  float a0 = 0.f, a1 = 0.f;
  for (int base = 0; base < m; base += 8) {
    int li = lane & 7;
    bool valid = base + li < m;
    int r = valid ? srow[s + base + li] : 0;
    float wv = valid ? snorm[s + base + li] : 0.f;
#pragma unroll
    for (int j = 0; j < 8; ++j) {
      int rj = __shfl(r, j, 16);
      float wj = __shfl(wv, j, 16);
      uint_t v = in[(size_t)rj * 16 + lane];
      a0 += wj * b2f((ushort_t)(v & 0xffffu));
      a1 += wj * b2f((ushort_t)(v >> 16));
    }
  }
  if (lane < 13) {
    out[(size_t)node * 26 + 2 * lane] += a0;
    out[(size_t)node * 26 + 2 * lane + 1] += a1;
  }
}

// ---------------- fused MFMA GEMM ----------------
// C(n x 128) = [A0|A1|A2|A3] (each n x KW bf16) @ Wswz (+bias)
// EPI 0: ELU, write bf16 n x 128 to outb
// EPI 1: layer-3 slots: slot0 -> outf (n x 26 fp32, +bias); slots 1..3 -> outb (3 x n x 32 bf16)
// block: 256 threads = 4 waves; wave owns 16*MR rows x 128 cols.
template <int KW, int NSRC, int EPI, int MR>
__global__ __launch_bounds__(256) void mfma_gemm(
    const ushort_t* __restrict__ A0, const ushort_t* __restrict__ A1,
    const ushort_t* __restrict__ A2, const ushort_t* __restrict__ A3,
    const ushort_t* __restrict__ Wswz, const float* __restrict__ bias,
    ushort_t* __restrict__ outb, float* __restrict__ outf, int n) {
  constexpr int KSPS = KW / 32;
  constexpr int KSTEPS = NSRC * KSPS;
  const int w = threadIdx.x >> 6;
  const int l = threadIdx.x & 63;
  const int row0 = blockIdx.x * (64 * MR) + w * (16 * MR);
  const int koff = 8 * (l >> 4);  // elements

  f32x4 acc[MR][8];
#pragma unroll
  for (int f = 0; f < MR; ++f)
#pragma unroll
    for (int j = 0; j < 8; ++j) acc[f][j] = (f32x4){0.f, 0.f, 0.f, 0.f};

  const ushort_t* const srcs[4] = {A0, A1, A2, A3};

#pragma unroll
  for (int t = 0; t < KSTEPS; ++t) {
    const int s = t / KSPS;
    const int tt = t - s * KSPS;
    bf16x8 af[MR];
#pragma unroll
    for (int f = 0; f < MR; ++f) {
      int arow = row0 + f * 16 + (l & 15);
      int arow_c = arow < n ? arow : (n - 1);
      af[f] = ld_frag(srcs[s] + (size_t)arow_c * KW + tt * 32 + koff);
    }
    const ushort_t* wp = Wswz + ((size_t)t * 8 * 64 + l) * 8;
#pragma unroll
    for (int j = 0; j < 8; ++j) {
      bf16x8 bfr = ld_frag(wp + (size_t)j * 64 * 8);
#pragma unroll
      for (int f = 0; f < MR; ++f)
        acc[f][j] = __builtin_amdgcn_mfma_f32_16x16x32_bf16(af[f], bfr, acc[f][j], 0, 0, 0);
    }
  }

  const int ccol = l & 15;
#pragma unroll
  for (int f = 0; f < MR; ++f) {
    const int crow0 = row0 + f * 16 + 4 * (l >> 4);
#pragma unroll
    for (int j = 0; j < 8; ++j) {
      if (EPI == 0) {
        int col = 16 * j + ccol;
        float bi = bias[col];
#pragma unroll
        for (int r = 0; r < 4; ++r) {
          int row = crow0 + r;
          if (row >= n) continue;
          float v = acc[f][j][r] + bi;
          v = v > 0.f ? v : (__expf(v) - 1.f);
          outb[(size_t)row * 128 + col] = f2b(v);
        }
      } else {
        int slot = j >> 1;
        int c = 16 * (j & 1) + ccol;
#pragma unroll
        for (int r = 0; r < 4; ++r) {
          int row = crow0 + r;
          if (row >= n) continue;
          float v = acc[f][j][r];
          if (slot == 0) {
            if (c < 26) outf[(size_t)row * 26 + c] = v + bias[c];
          } else {
            outb[((size_t)(slot - 1) * n + row) * 32 + c] = f2b(v);
          }
        }
      }
    }
  }
}

// ---------------- launcher ----------------

extern "C" void kernel_launch(void* const* d_in, const int* in_sizes, int n_in,
                              void* d_out, int out_size, void* d_ws, size_t ws_size,
                              hipStream_t stream) {
  const float* x  = (const float*)d_in[0];
  const int*   ei = (const int*)d_in[1];
  const float* ew = (const float*)d_in[2];
  const float* W1 = (const float*)d_in[3];
  const float* b1 = (const float*)d_in[4];
  const float* W2 = (const float*)d_in[5];
  const float* b2 = (const float*)d_in[6];
  const float* W3 = (const float*)d_in[7];
  const float* b3 = (const float*)d_in[8];
  float* out = (float*)d_out;

  const int n = in_sizes[0] / NCLS;  // 100000
  const int E = in_sizes[2];         // 1600000

  char* w = (char*)d_ws;
  auto alloc = [&](size_t bytes) {
    char* p = w;
    w += (bytes + 255) / 256 * 256;
    return p;
  };
  // width-128 bf16 feature buffers (64 dwords per node)
  uint_t* H0 = (uint_t*)alloc((size_t)n * 64 * 4);
  uint_t* P1 = (uint_t*)alloc((size_t)n * 64 * 4);
  uint_t* P2 = (uint_t*)alloc((size_t)n * 64 * 4);
  uint_t* P3 = (uint_t*)alloc((size_t)n * 64 * 4);
  uint_t* H1 = (uint_t*)alloc((size_t)n * 64 * 4);
  // width-32-padded bf16 buffers (16 dwords per node)
  uint_t* x32 = (uint_t*)alloc((size_t)n * 16 * 4);
  uint_t* q1  = (uint_t*)alloc((size_t)n * 16 * 4);
  uint_t* q2  = (uint_t*)alloc((size_t)n * 16 * 4);
  uint_t* q3  = (uint_t*)alloc((size_t)n * 16 * 4);
  uint_t* zb  = (uint_t*)alloc((size_t)n * 48 * 4);  // z1,z2,z3 each n x 32 bf16
  // swizzled weights
  ushort_t* Wz1 = (ushort_t*)alloc(4 * 4096 * 2);
  ushort_t* Wz2 = (ushort_t*)alloc(16 * 4096 * 2);
  ushort_t* Wz3 = (ushort_t*)alloc(4 * 4096 * 2);
  // graph CSR
  int*   srow  = (int*)alloc((size_t)E * 4);
  float* snorm = (float*)alloc((size_t)E * 4);
  int*   start = (int*)alloc((size_t)n * 4);
  int*   cnt   = (int*)alloc((size_t)n * 4);
  int*   cur   = (int*)alloc((size_t)n * 4);
  float* deg   = (float*)alloc((size_t)n * 4);
  int*   blks  = (int*)alloc(4096 * 4);

  const int eb = (E + 255) / 256;
  const int nb = (n + 255) / 256;  // 391 blocks (fits 512-thread partials scan)

  hipMemsetAsync(deg, 0, (size_t)n * 4, stream);
  hipMemsetAsync(cnt, 0, (size_t)n * 4, stream);
  hipMemsetAsync(cur, 0, (size_t)n * 4, stream);

  edge_pass1<<<eb, 256, 0, stream>>>(ei, ew, deg, cnt, E);
  dinv_kernel<<<nb, 256, 0, stream>>>(deg, n);
  scan_block<<<nb, 256, 0, stream>>>(cnt, start, blks, n);
  scan_partials<<<1, 512, 0, stream>>>(blks, nb);
  add_offsets<<<nb, 256, 0, stream>>>(start, blks, n);
  edge_pass2<<<eb, 256, 0, stream>>>(ei, ew, deg, start, cur, srow, snorm, E);

  convert_x<<<(n * 16 + 255) / 256, 256, 0, stream>>>(x, x32, n);
  swizzleW_kcat<<<(4 * 4096 + 255) / 256, 256, 0, stream>>>(W1, Wz1, 1, NCLS, 4);
  swizzleW_kcat<<<(16 * 4096 + 255) / 256, 256, 0, stream>>>(W2, Wz2, 4, HID, 4);
  swizzleW_nslot<<<(4 * 4096 + 255) / 256, 256, 0, stream>>>(W3, Wz3);

  const int g128 = (n + 3) / 4;
  const int g26  = (n + 15) / 16;
  const int gg   = (n + 127) / 128;  // mfma_gemm grid (MR=2: 128 rows/block)

  // ---- Layer 1: q_k = A^k x (width 32-padded), H0 = ELU([x|q1|q2|q3] @ W1cat + b1) ----
  spmm26_bf<<<g26, 256, 0, stream>>>(srow, snorm, start, cnt, x32, nullptr, q1, n);
  spmm26_bf<<<g26, 256, 0, stream>>>(srow, snorm, start, cnt, q1, nullptr, q2, n);
  spmm26_bf<<<g26, 256, 0, stream>>>(srow, snorm, start, cnt, q2, nullptr, q3, n);
  mfma_gemm<32, 4, 0, 2><<<gg, 256, 0, stream>>>(
      (const ushort_t*)x32, (const ushort_t*)q1, (const ushort_t*)q2, (const ushort_t*)q3,
      Wz1, b1, (ushort_t*)H0, nullptr, n);

  // ---- Layer 2: P_k = A^k H0, H1 = ELU([H0|P1|P2|P3] @ W2cat + b2) ----
  spmm128_bf<<<g128, 256, 0, stream>>>(srow, snorm, start, cnt, H0, P1, n);
  spmm128_bf<<<g128, 256, 0, stream>>>(srow, snorm, start, cnt, P1, P2, n);
  spmm128_bf<<<g128, 256, 0, stream>>>(srow, snorm, start, cnt, P2, P3, n);
  mfma_gemm<128, 4, 0, 2><<<gg, 256, 0, stream>>>(
      (const ushort_t*)H0, (const ushort_t*)P1, (const ushort_t*)P2, (const ushort_t*)P3,
      Wz2, b2, (ushort_t*)H1, nullptr, n);

  // ---- Layer 3: Z = H1 @ [W3_0|W3_1|W3_2|W3_3]; Horner out = z0+b3 + A(z1 + A(z2 + A z3)) ----
  mfma_gemm<128, 1, 1, 2><<<gg, 256, 0, stream>>>(
      (const ushort_t*)H1, (const ushort_t*)H1, (const ushort_t*)H1, (const ushort_t*)H1,
      Wz3, b3, (ushort_t*)zb, out, n);

  uint_t* z1 = zb;
  uint_t* z2 = zb + (size_t)n * 16;
  uint_t* z3 = zb + (size_t)n * 32;
  spmm26_bf<<<g26, 256, 0, stream>>>(srow, snorm, start, cnt, z3, z2, q1, n);  // q1 = z2 + A z3
  spmm26_bf<<<g26, 256, 0, stream>>>(srow, snorm, start, cnt, q1, z1, q2, n);  // q2 = z1 + A q1
  spmm26_addf<<<g26, 256, 0, stream>>>(srow, snorm, start, cnt, q2, out, n);   // out += A q2
}

// Round 5
// 656.783 us; speedup vs baseline: 5.7128x; 1.0549x over previous
//
#include <hip/hip_runtime.h>

#define NCLS 26
#define HID 128
typedef unsigned short ushort_t;
typedef unsigned int uint_t;
typedef unsigned long long u64;

typedef __bf16 bf16x8 __attribute__((ext_vector_type(8)));
typedef float f32x4 __attribute__((ext_vector_type(4)));
typedef unsigned int u32x4 __attribute__((ext_vector_type(4)));
typedef unsigned int u32x2 __attribute__((ext_vector_type(2)));

#define FIXSCALE 16777216.0f  // 2^24

// ---------------- bf16 helpers (ushort storage) ----------------
static __device__ __forceinline__ float b2f(ushort_t h) {
  return __uint_as_float(((uint_t)h) << 16);
}
static __device__ __forceinline__ ushort_t f2b(float f) {
  uint_t u = __float_as_uint(f);
  uint_t r = (u + 0x7fffu + ((u >> 16) & 1u)) >> 16;
  return (ushort_t)r;
}
static __device__ __forceinline__ uint_t pack2(float f0, float f1) {
  return (uint_t)f2b(f0) | ((uint_t)f2b(f1) << 16);
}
static __device__ __forceinline__ float lo16(uint_t v) { return b2f((ushort_t)(v & 0xffffu)); }
static __device__ __forceinline__ float hi16(uint_t v) { return b2f((ushort_t)(v >> 16)); }
static __device__ __forceinline__ bf16x8 ld_frag(const ushort_t* p) {
  u32x4 v = *reinterpret_cast<const u32x4*>(p);
  return __builtin_bit_cast(bf16x8, v);
}

// ---------------- preprocessing ----------------

// packed[c]: hi32 = edge count, lo32 = fixed-point weighted degree
__global__ void edge_pass1(const int* __restrict__ ei, const float* __restrict__ ew,
                           u64* __restrict__ packed, int E) {
  int e = blockIdx.x * 256 + threadIdx.x;
  if (e >= E) return;
  int c = ei[E + e];
  uint_t wfix = (uint_t)(ew[e] * FIXSCALE + 0.5f);
  atomicAdd(&packed[c], (1ULL << 32) | (u64)wfix);
}

__global__ void dinv_kernel(const u64* __restrict__ packed, float* __restrict__ dinv, int n) {
  int i = blockIdx.x * 256 + threadIdx.x;
  if (i >= n) return;
  uint_t lo = (uint_t)(packed[i] & 0xffffffffULL);
  float d = (float)lo * (1.0f / FIXSCALE);
  dinv[i] = lo > 0 ? rsqrtf(fmaxf(d, 1e-12f)) : 0.f;
}

__global__ void scan_block(const u64* __restrict__ packed, int* __restrict__ excl,
                           int* __restrict__ blksum, int n) {
  __shared__ int s[256];
  int g = blockIdx.x * 256 + threadIdx.x;
  int v = (g < n) ? (int)(packed[g] >> 32) : 0;
  s[threadIdx.x] = v;
  __syncthreads();
  for (int off = 1; off < 256; off <<= 1) {
    int t = (threadIdx.x >= (unsigned)off) ? s[threadIdx.x - off] : 0;
    __syncthreads();
    s[threadIdx.x] += t;
    __syncthreads();
  }
  if (g < n) excl[g] = s[threadIdx.x] - v;
  if (threadIdx.x == 255) blksum[blockIdx.x] = s[255];
}

__global__ void scan_partials(int* __restrict__ blksum, int nb) {
  __shared__ int s[512];
  int t = threadIdx.x;
  int v = (t < nb) ? blksum[t] : 0;
  s[t] = v;
  __syncthreads();
  for (int off = 1; off < 512; off <<= 1) {
    int u = (t >= off) ? s[t - off] : 0;
    __syncthreads();
    s[t] += u;
    __syncthreads();
  }
  if (t < nb) blksum[t] = s[t] - v;
}

__global__ void add_offsets(int* __restrict__ excl, const int* __restrict__ blksum, int n, int E) {
  int g = blockIdx.x * 256 + threadIdx.x;
  if (g < n) excl[g] += blksum[blockIdx.x];
  if (g == 0) excl[n] = E;
}

// meta[p] = {row, norm}; slot via atomic decrement of packed hi32 (count field)
__global__ void edge_pass2(const int* __restrict__ ei, const float* __restrict__ ew,
                           const float* __restrict__ dinv, const int* __restrict__ start,
                           u64* __restrict__ packed, u32x2* __restrict__ meta, int E) {
  int e = blockIdx.x * 256 + threadIdx.x;
  if (e >= E) return;
  int r = ei[e], c = ei[E + e];
  float nrm = dinv[r] * ew[e] * dinv[c];
  u64 old = atomicAdd(&packed[c], 0xFFFFFFFF00000000ULL);
  int p = start[c] + (int)(old >> 32) - 1;
  u32x2 m;
  m.x = (uint_t)r;
  m.y = __float_as_uint(nrm);
  meta[p] = m;
}

// x (n x 26 fp32) -> padded bf16 (n x 32), zeros in cols 26..31
__global__ void convert_x(const float* __restrict__ in, uint_t* __restrict__ out, int n) {
  int idx = blockIdx.x * 256 + threadIdx.x;
  if (idx >= n * 16) return;
  int node = idx >> 4, lane = idx & 15;
  float f0 = 0.f, f1 = 0.f;
  if (lane < 13) {
    f0 = in[node * 26 + 2 * lane];
    f1 = in[node * 26 + 2 * lane + 1];
  }
  out[idx] = pack2(f0, f1);
}

// ---------------- W swizzle into MFMA B-fragment order ----------------
// out layout: [t (global kstep)][j 0..7][lane 0..63][i 0..7] bf16
// fragment element = B[k][col], k = 32*t_in_src + 8*(lane>>4) + i, col = 16*j + (lane&15)

__global__ void swizzleW_kcat(const float* __restrict__ W, ushort_t* __restrict__ out,
                              int ksps, int kwv, int nsrc) {
  int idx = blockIdx.x * 256 + threadIdx.x;
  int total = nsrc * ksps * 4096;
  if (idx >= total) return;
  int i = idx & 7, l = (idx >> 3) & 63, j = (idx >> 9) & 7, t = idx >> 12;
  int s = t / ksps, tt = t - s * ksps;
  int k = tt * 32 + 8 * (l >> 4) + i;
  int col = 16 * j + (l & 15);
  float v = (k < kwv) ? W[((size_t)s * kwv + k) * 128 + col] : 0.f;
  out[idx] = f2b(v);
}

__global__ void swizzleW_nslot(const float* __restrict__ W, ushort_t* __restrict__ out) {
  int idx = blockIdx.x * 256 + threadIdx.x;
  if (idx >= 4 * 4096) return;
  int i = idx & 7, l = (idx >> 3) & 63, j = (idx >> 9) & 7, t = idx >> 12;
  int k = t * 32 + 8 * (l >> 4) + i;
  int col = 16 * j + (l & 15);
  int s = col >> 5, c = col & 31;
  float v = (c < 26) ? W[((size_t)s * 128 + k) * 26 + c] : 0.f;
  out[idx] = f2b(v);
}

// ---------------- SpMM (pull, CSR by destination, bf16, interleaved meta) ----------------

// width 128: wave per node; 16 lanes per edge-slot (eq=lane>>4), dwordx4 gathers;
// 4 independent edge chains in flight. Final reduce via shfl_xor 16/32.
__global__ __launch_bounds__(256) void spmm128_bf(
    const u32x2* __restrict__ meta, const int* __restrict__ start,
    const uint_t* __restrict__ in, uint_t* __restrict__ out, int n) {
  int node = blockIdx.x * 4 + (threadIdx.x >> 6);
  int lane = threadIdx.x & 63;
  if (node >= n) return;
  int s = start[node], m = start[node + 1] - s;
  int eq = lane >> 4;   // which edge of the quad
  int f16 = lane & 15;  // 16B chunk within 256B row
  float a0 = 0.f, a1 = 0.f, a2 = 0.f, a3 = 0.f, a4 = 0.f, a5 = 0.f, a6 = 0.f, a7 = 0.f;
  for (int base = 0; base < m; base += 4) {
    int eidx = base + eq;
    u32x2 mt = (eidx < m) ? meta[s + eidx] : (u32x2){0u, 0u};
    int r = (int)mt.x;
    float wv = __uint_as_float(mt.y);
    u32x4 v = *reinterpret_cast<const u32x4*>(in + (size_t)r * 64 + f16 * 4);
    a0 += wv * lo16(v.x); a1 += wv * hi16(v.x);
    a2 += wv * lo16(v.y); a3 += wv * hi16(v.y);
    a4 += wv * lo16(v.z); a5 += wv * hi16(v.z);
    a6 += wv * lo16(v.w); a7 += wv * hi16(v.w);
  }
  a0 += __shfl_xor(a0, 16); a1 += __shfl_xor(a1, 16);
  a2 += __shfl_xor(a2, 16); a3 += __shfl_xor(a3, 16);
  a4 += __shfl_xor(a4, 16); a5 += __shfl_xor(a5, 16);
  a6 += __shfl_xor(a6, 16); a7 += __shfl_xor(a7, 16);
  a0 += __shfl_xor(a0, 32); a1 += __shfl_xor(a1, 32);
  a2 += __shfl_xor(a2, 32); a3 += __shfl_xor(a3, 32);
  a4 += __shfl_xor(a4, 32); a5 += __shfl_xor(a5, 32);
  a6 += __shfl_xor(a6, 32); a7 += __shfl_xor(a7, 32);
  if (eq == 0) {
    u32x4 o;
    o.x = pack2(a0, a1);
    o.y = pack2(a2, a3);
    o.z = pack2(a4, a5);
    o.w = pack2(a6, a7);
    *reinterpret_cast<u32x4*>(out + (size_t)node * 64 + f16 * 4) = o;
  }
}

// width 32-padded: 8 lanes per node (dwordx2 each), 8 edges per chunk, same-addr meta broadcast
__global__ __launch_bounds__(256) void spmm26_bf(
    const u32x2* __restrict__ meta, const int* __restrict__ start,
    const uint_t* __restrict__ in, const uint_t* __restrict__ add,
    uint_t* __restrict__ out, int n) {
  int node = blockIdx.x * 32 + (threadIdx.x >> 3);
  int d2 = threadIdx.x & 7;  // dword-pair index (cols 4*d2..4*d2+3)
  if (node >= n) return;
  int s = start[node], m = start[node + 1] - s;
  float a0 = 0.f, a1 = 0.f, a2 = 0.f, a3 = 0.f;
  for (int base = 0; base < m; base += 8) {
#pragma unroll
    for (int j = 0; j < 8; ++j) {
      int eidx = base + j;
      u32x2 mt = (eidx < m) ? meta[s + eidx] : (u32x2){0u, 0u};
      int r = (int)mt.x;
      float wv = __uint_as_float(mt.y);
      u32x2 v = *reinterpret_cast<const u32x2*>(in + (size_t)r * 16 + 2 * d2);
      a0 += wv * lo16(v.x); a1 += wv * hi16(v.x);
      a2 += wv * lo16(v.y); a3 += wv * hi16(v.y);
    }
  }
  if (add) {
    u32x2 v = *reinterpret_cast<const u32x2*>(add + (size_t)node * 16 + 2 * d2);
    a0 += lo16(v.x); a1 += hi16(v.x);
    a2 += lo16(v.y); a3 += hi16(v.y);
  }
  u32x2 o;
  o.x = pack2(a0, a1);
  o.y = pack2(a2, a3);
  *reinterpret_cast<u32x2*>(out + (size_t)node * 16 + 2 * d2) = o;
}

// final Horner step: out_f32 (n x 26) += A*in
__global__ __launch_bounds__(256) void spmm26_addf(
    const u32x2* __restrict__ meta, const int* __restrict__ start,
    const uint_t* __restrict__ in, float* __restrict__ out, int n) {
  int node = blockIdx.x * 32 + (threadIdx.x >> 3);
  int d2 = threadIdx.x & 7;
  if (node >= n) return;
  int s = start[node], m = start[node + 1] - s;
  float a0 = 0.f, a1 = 0.f, a2 = 0.f, a3 = 0.f;
  for (int base = 0; base < m; base += 8) {
#pragma unroll
    for (int j = 0; j < 8; ++j) {
      int eidx = base + j;
      u32x2 mt = (eidx < m) ? meta[s + eidx] : (u32x2){0u, 0u};
      int r = (int)mt.x;
      float wv = __uint_as_float(mt.y);
      u32x2 v = *reinterpret_cast<const u32x2*>(in + (size_t)r * 16 + 2 * d2);
      a0 += wv * lo16(v.x); a1 += wv * hi16(v.x);
      a2 += wv * lo16(v.y); a3 += wv * hi16(v.y);
    }
  }
  int c0 = 4 * d2;
  if (c0 + 0 < 26) out[(size_t)node * 26 + c0 + 0] += a0;
  if (c0 + 1 < 26) out[(size_t)node * 26 + c0 + 1] += a1;
  if (c0 + 2 < 26) out[(size_t)node * 26 + c0 + 2] += a2;
  if (c0 + 3 < 26) out[(size_t)node * 26 + c0 + 3] += a3;
}

// ---------------- fused MFMA GEMM ----------------
// C(n x 128) = [A0|A1|A2|A3] (each n x KW bf16) @ Wswz (+bias)
// EPI 0: ELU, write bf16 n x 128 to outb
// EPI 1: layer-3 slots: slot0 -> outf (n x 26 fp32, +bias); slots 1..3 -> outb (3 x n x 32 bf16)
template <int KW, int NSRC, int EPI, int MR>
__global__ __launch_bounds__(256) void mfma_gemm(
    const ushort_t* __restrict__ A0, const ushort_t* __restrict__ A1,
    const ushort_t* __restrict__ A2, const ushort_t* __restrict__ A3,
    const ushort_t* __restrict__ Wswz, const float* __restrict__ bias,
    ushort_t* __restrict__ outb, float* __restrict__ outf, int n) {
  constexpr int KSPS = KW / 32;
  constexpr int KSTEPS = NSRC * KSPS;
  const int w = threadIdx.x >> 6;
  const int l = threadIdx.x & 63;
  const int row0 = blockIdx.x * (64 * MR) + w * (16 * MR);
  const int koff = 8 * (l >> 4);  // elements

  f32x4 acc[MR][8];
#pragma unroll
  for (int f = 0; f < MR; ++f)
#pragma unroll
    for (int j = 0; j < 8; ++j) acc[f][j] = (f32x4){0.f, 0.f, 0.f, 0.f};

  const ushort_t* const srcs[4] = {A0, A1, A2, A3};

#pragma unroll
  for (int t = 0; t < KSTEPS; ++t) {
    const int s = t / KSPS;
    const int tt = t - s * KSPS;
    bf16x8 af[MR];
#pragma unroll
    for (int f = 0; f < MR; ++f) {
      int arow = row0 + f * 16 + (l & 15);
      int arow_c = arow < n ? arow : (n - 1);
      af[f] = ld_frag(srcs[s] + (size_t)arow_c * KW + tt * 32 + koff);
    }
    const ushort_t* wp = Wswz + ((size_t)t * 8 * 64 + l) * 8;
#pragma unroll
    for (int j = 0; j < 8; ++j) {
      bf16x8 bfr = ld_frag(wp + (size_t)j * 64 * 8);
#pragma unroll
      for (int f = 0; f < MR; ++f)
        acc[f][j] = __builtin_amdgcn_mfma_f32_16x16x32_bf16(af[f], bfr, acc[f][j], 0, 0, 0);
    }
  }

  const int ccol = l & 15;
#pragma unroll
  for (int f = 0; f < MR; ++f) {
    const int crow0 = row0 + f * 16 + 4 * (l >> 4);
#pragma unroll
    for (int j = 0; j < 8; ++j) {
      if (EPI == 0) {
        int col = 16 * j + ccol;
        float bi = bias[col];
#pragma unroll
        for (int r = 0; r < 4; ++r) {
          int row = crow0 + r;
          if (row >= n) continue;
          float v = acc[f][j][r] + bi;
          v = v > 0.f ? v : (__expf(v) - 1.f);
          outb[(size_t)row * 128 + col] = f2b(v);
        }
      } else {
        int slot = j >> 1;
        int c = 16 * (j & 1) + ccol;
#pragma unroll
        for (int r = 0; r < 4; ++r) {
          int row = crow0 + r;
          if (row >= n) continue;
          float v = acc[f][j][r];
          if (slot == 0) {
            if (c < 26) outf[(size_t)row * 26 + c] = v + bias[c];
          } else {
            outb[((size_t)(slot - 1) * n + row) * 32 + c] = f2b(v);
          }
        }
      }
    }
  }
}

// ---------------- launcher ----------------

extern "C" void kernel_launch(void* const* d_in, const int* in_sizes, int n_in,
                              void* d_out, int out_size, void* d_ws, size_t ws_size,
                              hipStream_t stream) {
  const float* x  = (const float*)d_in[0];
  const int*   ei = (const int*)d_in[1];
  const float* ew = (const float*)d_in[2];
  const float* W1 = (const float*)d_in[3];
  const float* b1 = (const float*)d_in[4];
  const float* W2 = (const float*)d_in[5];
  const float* b2 = (const float*)d_in[6];
  const float* W3 = (const float*)d_in[7];
  const float* b3 = (const float*)d_in[8];
  float* out = (float*)d_out;

  const int n = in_sizes[0] / NCLS;  // 100000
  const int E = in_sizes[2];         // 1600000

  char* w = (char*)d_ws;
  auto alloc = [&](size_t bytes) {
    char* p = w;
    w += (bytes + 255) / 256 * 256;
    return p;
  };
  // width-128 bf16 feature buffers (64 dwords per node)
  uint_t* H0 = (uint_t*)alloc((size_t)n * 64 * 4);
  uint_t* P1 = (uint_t*)alloc((size_t)n * 64 * 4);
  uint_t* P2 = (uint_t*)alloc((size_t)n * 64 * 4);
  uint_t* P3 = (uint_t*)alloc((size_t)n * 64 * 4);
  uint_t* H1 = (uint_t*)alloc((size_t)n * 64 * 4);
  // width-32-padded bf16 buffers (16 dwords per node)
  uint_t* x32 = (uint_t*)alloc((size_t)n * 16 * 4);
  uint_t* q1  = (uint_t*)alloc((size_t)n * 16 * 4);
  uint_t* q2  = (uint_t*)alloc((size_t)n * 16 * 4);
  uint_t* q3  = (uint_t*)alloc((size_t)n * 16 * 4);
  uint_t* zb  = (uint_t*)alloc((size_t)n * 48 * 4);  // z1,z2,z3 each n x 32 bf16
  // swizzled weights
  ushort_t* Wz1 = (ushort_t*)alloc(4 * 4096 * 2);
  ushort_t* Wz2 = (ushort_t*)alloc(16 * 4096 * 2);
  ushort_t* Wz3 = (ushort_t*)alloc(4 * 4096 * 2);
  // graph CSR
  u64*   packed = (u64*)alloc((size_t)n * 8);
  u32x2* meta   = (u32x2*)alloc((size_t)E * 8);
  int*   start  = (int*)alloc((size_t)(n + 1) * 4);
  float* dinv   = (float*)alloc((size_t)n * 4);
  int*   blks   = (int*)alloc(4096 * 4);

  const int eb = (E + 255) / 256;
  const int nb = (n + 255) / 256;  // 391 blocks (fits 512-thread partials scan)

  hipMemsetAsync(packed, 0, (size_t)n * 8, stream);

  edge_pass1<<<eb, 256, 0, stream>>>(ei, ew, packed, E);
  dinv_kernel<<<nb, 256, 0, stream>>>(packed, dinv, n);
  scan_block<<<nb, 256, 0, stream>>>(packed, start, blks, n);
  scan_partials<<<1, 512, 0, stream>>>(blks, nb);
  add_offsets<<<nb, 256, 0, stream>>>(start, blks, n, E);
  edge_pass2<<<eb, 256, 0, stream>>>(ei, ew, dinv, start, packed, meta, E);

  convert_x<<<(n * 16 + 255) / 256, 256, 0, stream>>>(x, x32, n);
  swizzleW_kcat<<<(4 * 4096 + 255) / 256, 256, 0, stream>>>(W1, Wz1, 1, NCLS, 4);
  swizzleW_kcat<<<(16 * 4096 + 255) / 256, 256, 0, stream>>>(W2, Wz2, 4, HID, 4);
  swizzleW_nslot<<<(4 * 4096 + 255) / 256, 256, 0, stream>>>(W3, Wz3);

  const int g128 = (n + 3) / 4;
  const int g26  = (n + 31) / 32;
  const int gg   = (n + 127) / 128;  // mfma_gemm grid (MR=2: 128 rows/block)

  // ---- Layer 1: q_k = A^k x (width 32-padded), H0 = ELU([x|q1|q2|q3] @ W1cat + b1) ----
  spmm26_bf<<<g26, 256, 0, stream>>>(meta, start, x32, nullptr, q1, n);
  spmm26_bf<<<g26, 256, 0, stream>>>(meta, start, q1, nullptr, q2, n);
  spmm26_bf<<<g26, 256, 0, stream>>>(meta, start, q2, nullptr, q3, n);
  mfma_gemm<32, 4, 0, 2><<<gg, 256, 0, stream>>>(
      (const ushort_t*)x32, (const ushort_t*)q1, (const ushort_t*)q2, (const ushort_t*)q3,
      Wz1, b1, (ushort_t*)H0, nullptr, n);

  // ---- Layer 2: P_k = A^k H0, H1 = ELU([H0|P1|P2|P3] @ W2cat + b2) ----
  spmm128_bf<<<g128, 256, 0, stream>>>(meta, start, H0, P1, n);
  spmm128_bf<<<g128, 256, 0, stream>>>(meta, start, P1, P2, n);
  spmm128_bf<<<g128, 256, 0, stream>>>(meta, start, P2, P3, n);
  mfma_gemm<128, 4, 0, 2><<<gg, 256, 0, stream>>>(
      (const ushort_t*)H0, (const ushort_t*)P1, (const ushort_t*)P2, (const ushort_t*)P3,
      Wz2, b2, (ushort_t*)H1, nullptr, n);

  // ---- Layer 3: Z = H1 @ [W3_0|W3_1|W3_2|W3_3]; Horner out = z0+b3 + A(z1 + A(z2 + A z3)) ----
  mfma_gemm<128, 1, 1, 2><<<gg, 256, 0, stream>>>(
      (const ushort_t*)H1, (const ushort_t*)H1, (const ushort_t*)H1, (const ushort_t*)H1,
      Wz3, b3, (ushort_t*)zb, out, n);

  uint_t* z1 = zb;
  uint_t* z2 = zb + (size_t)n * 16;
  uint_t* z3 = zb + (size_t)n * 32;
  spmm26_bf<<<g26, 256, 0, stream>>>(meta, start, z3, z2, q1, n);  // q1 = z2 + A z3
  spmm26_bf<<<g26, 256, 0, stream>>>(meta, start, q1, z1, q2, n);  // q2 = z1 + A q1
  spmm26_addf<<<g26, 256, 0, stream>>>(meta, start, q2, out, n);   // out += A q2
}

// Round 6
// 552.478 us; speedup vs baseline: 6.7914x; 1.1888x over previous
//
#include <hip/hip_runtime.h>

#define NCLS 26
#define HID 128
#define EPB 8192   // edges per bucketing block
#define MAXBK 512  // max buckets (supports n <= 131072)
typedef unsigned short ushort_t;
typedef unsigned int uint_t;
typedef unsigned long long u64;

typedef __bf16 bf16x8 __attribute__((ext_vector_type(8)));
typedef float f32x4 __attribute__((ext_vector_type(4)));
typedef unsigned int u32x4 __attribute__((ext_vector_type(4)));
typedef unsigned int u32x2 __attribute__((ext_vector_type(2)));

// ---------------- bf16 helpers (ushort storage) ----------------
static __device__ __forceinline__ float b2f(ushort_t h) {
  return __uint_as_float(((uint_t)h) << 16);
}
static __device__ __forceinline__ ushort_t f2b(float f) {
  uint_t u = __float_as_uint(f);
  uint_t r = (u + 0x7fffu + ((u >> 16) & 1u)) >> 16;
  return (ushort_t)r;
}
static __device__ __forceinline__ uint_t pack2(float f0, float f1) {
  return (uint_t)f2b(f0) | ((uint_t)f2b(f1) << 16);
}
static __device__ __forceinline__ float lo16(uint_t v) { return b2f((ushort_t)(v & 0xffffu)); }
static __device__ __forceinline__ float hi16(uint_t v) { return b2f((ushort_t)(v >> 16)); }
static __device__ __forceinline__ bf16x8 ld_frag(const ushort_t* p) {
  u32x4 v = *reinterpret_cast<const u32x4*>(p);
  return __builtin_bit_cast(bf16x8, v);
}

// ---------------- preprocessing: two-level bucket sort ----------------
// bucket(c) = c >> 8 (256 nodes per bucket). Packed bucket record (u64):
// hi32 = r | (c_local << 24), lo32 = fp32 weight bits.

__global__ __launch_bounds__(256) void bucket_count(const int* __restrict__ ei,
                                                    int* __restrict__ bcnt, int E, int nbk) {
  __shared__ uint_t lc[MAXBK];
  int tid = threadIdx.x;
  for (int t = tid; t < nbk; t += 256) lc[t] = 0;
  __syncthreads();
  int e0 = blockIdx.x * EPB;
#pragma unroll
  for (int i = 0; i < EPB / 256; ++i) {
    int e = e0 + tid + i * 256;
    if (e < E) atomicAdd(&lc[(uint_t)ei[E + e] >> 8], 1u);
  }
  __syncthreads();
  for (int t = tid; t < nbk; t += 256)
    if (lc[t]) atomicAdd(&bcnt[t], (int)lc[t]);
}

__global__ void scan_buckets(const int* __restrict__ bcnt, int* __restrict__ bbase,
                             int nbk, int E) {
  __shared__ int s[512];
  int t = threadIdx.x;
  int v = (t < nbk) ? bcnt[t] : 0;
  s[t] = v;
  __syncthreads();
  for (int off = 1; off < 512; off <<= 1) {
    int u = (t >= off) ? s[t - off] : 0;
    __syncthreads();
    s[t] += u;
    __syncthreads();
  }
  if (t < nbk) bbase[t] = s[t] - v;
  if (t == 0) bbase[nbk] = E;
}

__global__ __launch_bounds__(256) void bucket_place(
    const int* __restrict__ ei, const float* __restrict__ ew, const int* __restrict__ bbase,
    int* __restrict__ gcur, u64* __restrict__ bkt, int E, int nbk) {
  __shared__ uint_t lc[MAXBK];
  __shared__ uint_t lb[MAXBK];
  int tid = threadIdx.x;
  for (int t = tid; t < nbk; t += 256) lc[t] = 0;
  __syncthreads();
  int e0 = blockIdx.x * EPB;
#pragma unroll
  for (int i = 0; i < EPB / 256; ++i) {
    int e = e0 + tid + i * 256;
    if (e < E) atomicAdd(&lc[(uint_t)ei[E + e] >> 8], 1u);
  }
  __syncthreads();
  for (int t = tid; t < nbk; t += 256) {
    uint_t c = lc[t];
    lb[t] = c ? (uint_t)(bbase[t] + atomicAdd(&gcur[t], (int)c)) : 0u;
    lc[t] = 0;
  }
  __syncthreads();
#pragma unroll
  for (int i = 0; i < EPB / 256; ++i) {
    int e = e0 + tid + i * 256;
    if (e < E) {
      uint_t r = (uint_t)ei[e];
      uint_t c = (uint_t)ei[E + e];
      uint_t b = c >> 8;
      float wv = ew[e];
      uint_t pos = lb[b] + atomicAdd(&lc[b], 1u);
      bkt[pos] = ((u64)(r | ((c & 255u) << 24)) << 32) | (u64)__float_as_uint(wv);
    }
  }
}

// per-bucket: LDS count + weighted degree, scan -> start[], dinv[]
__global__ __launch_bounds__(256) void bucket_stats(
    const u64* __restrict__ bkt, const int* __restrict__ bbase,
    int* __restrict__ start, float* __restrict__ dinv, int n, int E) {
  int b = blockIdx.x;
  __shared__ uint_t cnt[256];
  __shared__ float deg[256];
  __shared__ int ssc[256];
  int tid = threadIdx.x;
  cnt[tid] = 0;
  deg[tid] = 0.f;
  __syncthreads();
  int s = bbase[b], e_end = bbase[b + 1];
  for (int p = s + tid; p < e_end; p += 256) {
    u64 v = bkt[p];
    uint_t cl = (uint_t)(v >> 56);
    float wv = __uint_as_float((uint_t)(v & 0xffffffffULL));
    atomicAdd(&cnt[cl], 1u);
    atomicAdd(&deg[cl], wv);
  }
  __syncthreads();
  int v0 = (int)cnt[tid];
  ssc[tid] = v0;
  __syncthreads();
  for (int off = 1; off < 256; off <<= 1) {
    int u = (tid >= off) ? ssc[tid - off] : 0;
    __syncthreads();
    ssc[tid] += u;
    __syncthreads();
  }
  int node = (b << 8) + tid;
  if (node < n) {
    start[node] = s + ssc[tid] - v0;
    float d = deg[tid];
    dinv[node] = d > 0.f ? rsqrtf(fmaxf(d, 1e-12f)) : 0.f;
  }
  if (b == 0 && tid == 0) start[n] = E;
}

// per-bucket: emit meta {r, nrm}; scattered writes stay in the bucket's CSR window
__global__ __launch_bounds__(256) void bucket_emit(
    const u64* __restrict__ bkt, const int* __restrict__ bbase, const int* __restrict__ start,
    const float* __restrict__ dinv, u32x2* __restrict__ meta, int n) {
  int b = blockIdx.x;
  __shared__ uint_t lcur[256];
  int tid = threadIdx.x;
  lcur[tid] = 0;
  __syncthreads();
  int s = bbase[b], e_end = bbase[b + 1];
  for (int p = s + tid; p < e_end; p += 256) {
    u64 v = bkt[p];
    uint_t hi = (uint_t)(v >> 32);
    uint_t r = hi & 0xffffffu;
    uint_t cl = hi >> 24;
    float wv = __uint_as_float((uint_t)(v & 0xffffffffULL));
    uint_t node = ((uint_t)b << 8) + cl;
    float nrm = dinv[r] * wv * dinv[node];
    uint_t slot = (uint_t)start[node] + atomicAdd(&lcur[cl], 1u);
    u32x2 m;
    m.x = r;
    m.y = __float_as_uint(nrm);
    meta[slot] = m;
  }
}

// x (n x 26 fp32) -> padded bf16 (n x 32), zeros in cols 26..31
__global__ void convert_x(const float* __restrict__ in, uint_t* __restrict__ out, int n) {
  int idx = blockIdx.x * 256 + threadIdx.x;
  if (idx >= n * 16) return;
  int node = idx >> 4, lane = idx & 15;
  float f0 = 0.f, f1 = 0.f;
  if (lane < 13) {
    f0 = in[node * 26 + 2 * lane];
    f1 = in[node * 26 + 2 * lane + 1];
  }
  out[idx] = pack2(f0, f1);
}

// ---------------- W swizzle into MFMA B-fragment order ----------------
// out layout: [t (global kstep)][j 0..7][lane 0..63][i 0..7] bf16
// fragment element = B[k][col], k = 32*t_in_src + 8*(lane>>4) + i, col = 16*j + (lane&15)

__global__ void swizzleW_kcat(const float* __restrict__ W, ushort_t* __restrict__ out,
                              int ksps, int kwv, int nsrc) {
  int idx = blockIdx.x * 256 + threadIdx.x;
  int total = nsrc * ksps * 4096;
  if (idx >= total) return;
  int i = idx & 7, l = (idx >> 3) & 63, j = (idx >> 9) & 7, t = idx >> 12;
  int s = t / ksps, tt = t - s * ksps;
  int k = tt * 32 + 8 * (l >> 4) + i;
  int col = 16 * j + (l & 15);
  float v = (k < kwv) ? W[((size_t)s * kwv + k) * 128 + col] : 0.f;
  out[idx] = f2b(v);
}

__global__ void swizzleW_nslot(const float* __restrict__ W, ushort_t* __restrict__ out) {
  int idx = blockIdx.x * 256 + threadIdx.x;
  if (idx >= 4 * 4096) return;
  int i = idx & 7, l = (idx >> 3) & 63, j = (idx >> 9) & 7, t = idx >> 12;
  int k = t * 32 + 8 * (l >> 4) + i;
  int col = 16 * j + (l & 15);
  int s = col >> 5, c = col & 31;
  float v = (c < 26) ? W[((size_t)s * 128 + k) * 26 + c] : 0.f;
  out[idx] = f2b(v);
}

// ---------------- SpMM (pull, CSR by destination, bf16, interleaved meta) ----------------

// width 128: wave per node; 16 lanes per edge-slot, dwordx4 gathers;
// 8 independent edge chains in flight (two quads per iteration).
__global__ __launch_bounds__(256) void spmm128_bf(
    const u32x2* __restrict__ meta, const int* __restrict__ start,
    const uint_t* __restrict__ in, uint_t* __restrict__ out, int n) {
  int node = blockIdx.x * 4 + (threadIdx.x >> 6);
  int lane = threadIdx.x & 63;
  if (node >= n) return;
  int s = start[node], m = start[node + 1] - s;
  int eq = lane >> 4;   // which edge of the quad
  int f16 = lane & 15;  // 16B chunk within 256B row
  float a0 = 0.f, a1 = 0.f, a2 = 0.f, a3 = 0.f, a4 = 0.f, a5 = 0.f, a6 = 0.f, a7 = 0.f;
  for (int base = 0; base < m; base += 8) {
    int i0 = base + eq, i1 = base + 4 + eq;
    u32x2 mt0 = (i0 < m) ? meta[s + i0] : (u32x2){0u, 0u};
    u32x2 mt1 = (i1 < m) ? meta[s + i1] : (u32x2){0u, 0u};
    u32x4 v0 = *reinterpret_cast<const u32x4*>(in + (size_t)mt0.x * 64 + f16 * 4);
    u32x4 v1 = *reinterpret_cast<const u32x4*>(in + (size_t)mt1.x * 64 + f16 * 4);
    float w0 = __uint_as_float(mt0.y);
    float w1 = __uint_as_float(mt1.y);
    a0 += w0 * lo16(v0.x); a1 += w0 * hi16(v0.x);
    a2 += w0 * lo16(v0.y); a3 += w0 * hi16(v0.y);
    a4 += w0 * lo16(v0.z); a5 += w0 * hi16(v0.z);
    a6 += w0 * lo16(v0.w); a7 += w0 * hi16(v0.w);
    a0 += w1 * lo16(v1.x); a1 += w1 * hi16(v1.x);
    a2 += w1 * lo16(v1.y); a3 += w1 * hi16(v1.y);
    a4 += w1 * lo16(v1.z); a5 += w1 * hi16(v1.z);
    a6 += w1 * lo16(v1.w); a7 += w1 * hi16(v1.w);
  }
  a0 += __shfl_xor(a0, 16); a1 += __shfl_xor(a1, 16);
  a2 += __shfl_xor(a2, 16); a3 += __shfl_xor(a3, 16);
  a4 += __shfl_xor(a4, 16); a5 += __shfl_xor(a5, 16);
  a6 += __shfl_xor(a6, 16); a7 += __shfl_xor(a7, 16);
  a0 += __shfl_xor(a0, 32); a1 += __shfl_xor(a1, 32);
  a2 += __shfl_xor(a2, 32); a3 += __shfl_xor(a3, 32);
  a4 += __shfl_xor(a4, 32); a5 += __shfl_xor(a5, 32);
  a6 += __shfl_xor(a6, 32); a7 += __shfl_xor(a7, 32);
  if (eq == 0) {
    u32x4 o;
    o.x = pack2(a0, a1);
    o.y = pack2(a2, a3);
    o.z = pack2(a4, a5);
    o.w = pack2(a6, a7);
    *reinterpret_cast<u32x4*>(out + (size_t)node * 64 + f16 * 4) = o;
  }
}

// width 32-padded: 8 lanes per node (dwordx2 each), 8 edges per chunk
__global__ __launch_bounds__(256) void spmm26_bf(
    const u32x2* __restrict__ meta, const int* __restrict__ start,
    const uint_t* __restrict__ in, const uint_t* __restrict__ add,
    uint_t* __restrict__ out, int n) {
  int node = blockIdx.x * 32 + (threadIdx.x >> 3);
  int d2 = threadIdx.x & 7;  // dword-pair index (cols 4*d2..4*d2+3)
  if (node >= n) return;
  int s = start[node], m = start[node + 1] - s;
  float a0 = 0.f, a1 = 0.f, a2 = 0.f, a3 = 0.f;
  for (int base = 0; base < m; base += 8) {
#pragma unroll
    for (int j = 0; j < 8; ++j) {
      int eidx = base + j;
      u32x2 mt = (eidx < m) ? meta[s + eidx] : (u32x2){0u, 0u};
      int r = (int)mt.x;
      float wv = __uint_as_float(mt.y);
      u32x2 v = *reinterpret_cast<const u32x2*>(in + (size_t)r * 16 + 2 * d2);
      a0 += wv * lo16(v.x); a1 += wv * hi16(v.x);
      a2 += wv * lo16(v.y); a3 += wv * hi16(v.y);
    }
  }
  if (add) {
    u32x2 v = *reinterpret_cast<const u32x2*>(add + (size_t)node * 16 + 2 * d2);
    a0 += lo16(v.x); a1 += hi16(v.x);
    a2 += lo16(v.y); a3 += hi16(v.y);
  }
  u32x2 o;
  o.x = pack2(a0, a1);
  o.y = pack2(a2, a3);
  *reinterpret_cast<u32x2*>(out + (size_t)node * 16 + 2 * d2) = o;
}

// final Horner step: out_f32 (n x 26) += A*in
__global__ __launch_bounds__(256) void spmm26_addf(
    const u32x2* __restrict__ meta, const int* __restrict__ start,
    const uint_t* __restrict__ in, float* __restrict__ out, int n) {
  int node = blockIdx.x * 32 + (threadIdx.x >> 3);
  int d2 = threadIdx.x & 7;
  if (node >= n) return;
  int s = start[node], m = start[node + 1] - s;
  float a0 = 0.f, a1 = 0.f, a2 = 0.f, a3 = 0.f;
  for (int base = 0; base < m; base += 8) {
#pragma unroll
    for (int j = 0; j < 8; ++j) {
      int eidx = base + j;
      u32x2 mt = (eidx < m) ? meta[s + eidx] : (u32x2){0u, 0u};
      int r = (int)mt.x;
      float wv = __uint_as_float(mt.y);
      u32x2 v = *reinterpret_cast<const u32x2*>(in + (size_t)r * 16 + 2 * d2);
      a0 += wv * lo16(v.x); a1 += wv * hi16(v.x);
      a2 += wv * lo16(v.y); a3 += wv * hi16(v.y);
    }
  }
  int c0 = 4 * d2;
  if (c0 + 0 < 26) out[(size_t)node * 26 + c0 + 0] += a0;
  if (c0 + 1 < 26) out[(size_t)node * 26 + c0 + 1] += a1;
  if (c0 + 2 < 26) out[(size_t)node * 26 + c0 + 2] += a2;
  if (c0 + 3 < 26) out[(size_t)node * 26 + c0 + 3] += a3;
}

// ---------------- fused MFMA GEMM ----------------
// C(n x 128) = [A0|A1|A2|A3] (each n x KW bf16) @ Wswz (+bias)
// EPI 0: ELU, write bf16 n x 128 to outb
// EPI 1: layer-3 slots: slot0 -> outf (n x 26 fp32, +bias); slots 1..3 -> outb (3 x n x 32 bf16)
template <int KW, int NSRC, int EPI, int MR>
__global__ __launch_bounds__(256) void mfma_gemm(
    const ushort_t* __restrict__ A0, const ushort_t* __restrict__ A1,
    const ushort_t* __restrict__ A2, const ushort_t* __restrict__ A3,
    const ushort_t* __restrict__ Wswz, const float* __restrict__ bias,
    ushort_t* __restrict__ outb, float* __restrict__ outf, int n) {
  constexpr int KSPS = KW / 32;
  constexpr int KSTEPS = NSRC * KSPS;
  const int w = threadIdx.x >> 6;
  const int l = threadIdx.x & 63;
  const int row0 = blockIdx.x * (64 * MR) + w * (16 * MR);
  const int koff = 8 * (l >> 4);  // elements

  f32x4 acc[MR][8];
#pragma unroll
  for (int f = 0; f < MR; ++f)
#pragma unroll
    for (int j = 0; j < 8; ++j) acc[f][j] = (f32x4){0.f, 0.f, 0.f, 0.f};

  const ushort_t* const srcs[4] = {A0, A1, A2, A3};

#pragma unroll
  for (int t = 0; t < KSTEPS; ++t) {
    const int s = t / KSPS;
    const int tt = t - s * KSPS;
    bf16x8 af[MR];
#pragma unroll
    for (int f = 0; f < MR; ++f) {
      int arow = row0 + f * 16 + (l & 15);
      int arow_c = arow < n ? arow : (n - 1);
      af[f] = ld_frag(srcs[s] + (size_t)arow_c * KW + tt * 32 + koff);
    }
    const ushort_t* wp = Wswz + ((size_t)t * 8 * 64 + l) * 8;
#pragma unroll
    for (int j = 0; j < 8; ++j) {
      bf16x8 bfr = ld_frag(wp + (size_t)j * 64 * 8);
#pragma unroll
      for (int f = 0; f < MR; ++f)
        acc[f][j] = __builtin_amdgcn_mfma_f32_16x16x32_bf16(af[f], bfr, acc[f][j], 0, 0, 0);
    }
  }

  const int ccol = l & 15;
#pragma unroll
  for (int f = 0; f < MR; ++f) {
    const int crow0 = row0 + f * 16 + 4 * (l >> 4);
#pragma unroll
    for (int j = 0; j < 8; ++j) {
      if (EPI == 0) {
        int col = 16 * j + ccol;
        float bi = bias[col];
#pragma unroll
        for (int r = 0; r < 4; ++r) {
          int row = crow0 + r;
          if (row >= n) continue;
          float v = acc[f][j][r] + bi;
          v = v > 0.f ? v : (__expf(v) - 1.f);
          outb[(size_t)row * 128 + col] = f2b(v);
        }
      } else {
        int slot = j >> 1;
        int c = 16 * (j & 1) + ccol;
#pragma unroll
        for (int r = 0; r < 4; ++r) {
          int row = crow0 + r;
          if (row >= n) continue;
          float v = acc[f][j][r];
          if (slot == 0) {
            if (c < 26) outf[(size_t)row * 26 + c] = v + bias[c];
          } else {
            outb[((size_t)(slot - 1) * n + row) * 32 + c] = f2b(v);
          }
        }
      }
    }
  }
}

// ---------------- launcher ----------------

extern "C" void kernel_launch(void* const* d_in, const int* in_sizes, int n_in,
                              void* d_out, int out_size, void* d_ws, size_t ws_size,
                              hipStream_t stream) {
  const float* x  = (const float*)d_in[0];
  const int*   ei = (const int*)d_in[1];
  const float* ew = (const float*)d_in[2];
  const float* W1 = (const float*)d_in[3];
  const float* b1 = (const float*)d_in[4];
  const float* W2 = (const float*)d_in[5];
  const float* b2 = (const float*)d_in[6];
  const float* W3 = (const float*)d_in[7];
  const float* b3 = (const float*)d_in[8];
  float* out = (float*)d_out;

  const int n = in_sizes[0] / NCLS;  // 100000
  const int E = in_sizes[2];         // 1600000
  const int nbk = (n + 255) >> 8;    // 391 buckets

  char* w = (char*)d_ws;
  auto alloc = [&](size_t bytes) {
    char* p = w;
    w += (bytes + 255) / 256 * 256;
    return p;
  };
  // width-128 bf16 feature buffers (64 dwords per node)
  uint_t* H0 = (uint_t*)alloc((size_t)n * 64 * 4);
  uint_t* P1 = (uint_t*)alloc((size_t)n * 64 * 4);
  uint_t* P2 = (uint_t*)alloc((size_t)n * 64 * 4);
  uint_t* P3 = (uint_t*)alloc((size_t)n * 64 * 4);
  uint_t* H1 = (uint_t*)alloc((size_t)n * 64 * 4);
  // width-32-padded bf16 buffers (16 dwords per node)
  uint_t* x32 = (uint_t*)alloc((size_t)n * 16 * 4);
  uint_t* q1  = (uint_t*)alloc((size_t)n * 16 * 4);
  uint_t* q2  = (uint_t*)alloc((size_t)n * 16 * 4);
  uint_t* q3  = (uint_t*)alloc((size_t)n * 16 * 4);
  uint_t* zb  = (uint_t*)alloc((size_t)n * 48 * 4);  // z1,z2,z3 each n x 32 bf16
  // swizzled weights
  ushort_t* Wz1 = (ushort_t*)alloc(4 * 4096 * 2);
  ushort_t* Wz2 = (ushort_t*)alloc(16 * 4096 * 2);
  ushort_t* Wz3 = (ushort_t*)alloc(4 * 4096 * 2);
  // graph CSR
  u64*   bkt  = (u64*)zb;  // alias: bkt (12.8MB) dead before zb (19.2MB) is used
  u32x2* meta = (u32x2*)alloc((size_t)E * 8);
  int*   start = (int*)alloc((size_t)(n + 1) * 4);
  float* dinv  = (float*)alloc((size_t)n * 4);
  int*   bcnt  = (int*)alloc(MAXBK * 4);
  int*   gcur  = (int*)alloc(MAXBK * 4);
  int*   bbase = (int*)alloc((MAXBK + 1) * 4);

  const int ab = (E + EPB - 1) / EPB;  // bucketing blocks (196)

  hipMemsetAsync(bcnt, 0, MAXBK * 4, stream);
  hipMemsetAsync(gcur, 0, MAXBK * 4, stream);

  bucket_count<<<ab, 256, 0, stream>>>(ei, bcnt, E, nbk);
  scan_buckets<<<1, 512, 0, stream>>>(bcnt, bbase, nbk, E);
  bucket_place<<<ab, 256, 0, stream>>>(ei, ew, bbase, gcur, bkt, E, nbk);
  bucket_stats<<<nbk, 256, 0, stream>>>(bkt, bbase, start, dinv, n, E);
  bucket_emit<<<nbk, 256, 0, stream>>>(bkt, bbase, start, dinv, meta, n);

  convert_x<<<(n * 16 + 255) / 256, 256, 0, stream>>>(x, x32, n);
  swizzleW_kcat<<<(4 * 4096 + 255) / 256, 256, 0, stream>>>(W1, Wz1, 1, NCLS, 4);
  swizzleW_kcat<<<(16 * 4096 + 255) / 256, 256, 0, stream>>>(W2, Wz2, 4, HID, 4);
  swizzleW_nslot<<<(4 * 4096 + 255) / 256, 256, 0, stream>>>(W3, Wz3);

  const int g128 = (n + 3) / 4;
  const int g26  = (n + 31) / 32;
  const int gg   = (n + 127) / 128;  // mfma_gemm grid (MR=2: 128 rows/block)

  // ---- Layer 1: q_k = A^k x (width 32-padded), H0 = ELU([x|q1|q2|q3] @ W1cat + b1) ----
  spmm26_bf<<<g26, 256, 0, stream>>>(meta, start, x32, nullptr, q1, n);
  spmm26_bf<<<g26, 256, 0, stream>>>(meta, start, q1, nullptr, q2, n);
  spmm26_bf<<<g26, 256, 0, stream>>>(meta, start, q2, nullptr, q3, n);
  mfma_gemm<32, 4, 0, 2><<<gg, 256, 0, stream>>>(
      (const ushort_t*)x32, (const ushort_t*)q1, (const ushort_t*)q2, (const ushort_t*)q3,
      Wz1, b1, (ushort_t*)H0, nullptr, n);

  // ---- Layer 2: P_k = A^k H0, H1 = ELU([H0|P1|P2|P3] @ W2cat + b2) ----
  spmm128_bf<<<g128, 256, 0, stream>>>(meta, start, H0, P1, n);
  spmm128_bf<<<g128, 256, 0, stream>>>(meta, start, P1, P2, n);
  spmm128_bf<<<g128, 256, 0, stream>>>(meta, start, P2, P3, n);
  mfma_gemm<128, 4, 0, 2><<<gg, 256, 0, stream>>>(
      (const ushort_t*)H0, (const ushort_t*)P1, (const ushort_t*)P2, (const ushort_t*)P3,
      Wz2, b2, (ushort_t*)H1, nullptr, n);

  // ---- Layer 3: Z = H1 @ [W3_0|W3_1|W3_2|W3_3]; Horner out = z0+b3 + A(z1 + A(z2 + A z3)) ----
  // NOTE: zb aliases bkt, which is dead after bucket_emit — safe.
  mfma_gemm<128, 1, 1, 2><<<gg, 256, 0, stream>>>(
      (const ushort_t*)H1, (const ushort_t*)H1, (const ushort_t*)H1, (const ushort_t*)H1,
      Wz3, b3, (ushort_t*)zb, out, n);

  uint_t* z1 = zb;
  uint_t* z2 = zb + (size_t)n * 16;
  uint_t* z3 = zb + (size_t)n * 32;
  spmm26_bf<<<g26, 256, 0, stream>>>(meta, start, z3, z2, q1, n);  // q1 = z2 + A z3
  spmm26_bf<<<g26, 256, 0, stream>>>(meta, start, q1, z1, q2, n);  // q2 = z1 + A q1
  spmm26_addf<<<g26, 256, 0, stream>>>(meta, start, q2, out, n);   // out += A q2
}

// Round 7
// 548.395 us; speedup vs baseline: 6.8419x; 1.0074x over previous
//
#include <hip/hip_runtime.h>

#define NCLS 26
#define HID 128
#define EPB 8192   // edges per bucketing block
#define MAXBK 512  // max buckets (supports n <= 131072)
typedef unsigned short ushort_t;
typedef unsigned int uint_t;
typedef unsigned long long u64;

typedef __bf16 bf16x8 __attribute__((ext_vector_type(8)));
typedef float f32x4 __attribute__((ext_vector_type(4)));
typedef unsigned int u32x4 __attribute__((ext_vector_type(4)));
typedef unsigned int u32x2 __attribute__((ext_vector_type(2)));

// ---------------- bf16 helpers (ushort storage) ----------------
static __device__ __forceinline__ float b2f(ushort_t h) {
  return __uint_as_float(((uint_t)h) << 16);
}
static __device__ __forceinline__ ushort_t f2b(float f) {
  uint_t u = __float_as_uint(f);
  uint_t r = (u + 0x7fffu + ((u >> 16) & 1u)) >> 16;
  return (ushort_t)r;
}
static __device__ __forceinline__ uint_t pack2(float f0, float f1) {
  return (uint_t)f2b(f0) | ((uint_t)f2b(f1) << 16);
}
static __device__ __forceinline__ float lo16(uint_t v) { return b2f((ushort_t)(v & 0xffffu)); }
static __device__ __forceinline__ float hi16(uint_t v) { return b2f((ushort_t)(v >> 16)); }
static __device__ __forceinline__ bf16x8 ld_frag(const ushort_t* p) {
  u32x4 v = *reinterpret_cast<const u32x4*>(p);
  return __builtin_bit_cast(bf16x8, v);
}

// ---------------- preprocessing: two-level bucket sort ----------------
// bucket(c) = c >> 8 (256 nodes per bucket). Packed bucket record (u64):
// hi32 = r | (c_local << 24), lo32 = fp32 weight bits.

__global__ __launch_bounds__(256) void bucket_count(const int* __restrict__ ei,
                                                    int* __restrict__ bcnt, int E, int nbk) {
  __shared__ uint_t lc[MAXBK];
  int tid = threadIdx.x;
  for (int t = tid; t < nbk; t += 256) lc[t] = 0;
  __syncthreads();
  int e0 = blockIdx.x * EPB;
#pragma unroll
  for (int i = 0; i < EPB / 256; ++i) {
    int e = e0 + tid + i * 256;
    if (e < E) atomicAdd(&lc[(uint_t)ei[E + e] >> 8], 1u);
  }
  __syncthreads();
  for (int t = tid; t < nbk; t += 256)
    if (lc[t]) atomicAdd(&bcnt[t], (int)lc[t]);
}

__global__ void scan_buckets(const int* __restrict__ bcnt, int* __restrict__ bbase,
                             int nbk, int E) {
  __shared__ int s[512];
  int t = threadIdx.x;
  int v = (t < nbk) ? bcnt[t] : 0;
  s[t] = v;
  __syncthreads();
  for (int off = 1; off < 512; off <<= 1) {
    int u = (t >= off) ? s[t - off] : 0;
    __syncthreads();
    s[t] += u;
    __syncthreads();
  }
  if (t < nbk) bbase[t] = s[t] - v;
  if (t == 0) bbase[nbk] = E;
}

__global__ __launch_bounds__(256) void bucket_place(
    const int* __restrict__ ei, const float* __restrict__ ew, const int* __restrict__ bbase,
    int* __restrict__ gcur, u64* __restrict__ bkt, int E, int nbk) {
  __shared__ uint_t lc[MAXBK];
  __shared__ uint_t lb[MAXBK];
  int tid = threadIdx.x;
  for (int t = tid; t < nbk; t += 256) lc[t] = 0;
  __syncthreads();
  int e0 = blockIdx.x * EPB;
#pragma unroll
  for (int i = 0; i < EPB / 256; ++i) {
    int e = e0 + tid + i * 256;
    if (e < E) atomicAdd(&lc[(uint_t)ei[E + e] >> 8], 1u);
  }
  __syncthreads();
  for (int t = tid; t < nbk; t += 256) {
    uint_t c = lc[t];
    lb[t] = c ? (uint_t)(bbase[t] + atomicAdd(&gcur[t], (int)c)) : 0u;
    lc[t] = 0;
  }
  __syncthreads();
#pragma unroll
  for (int i = 0; i < EPB / 256; ++i) {
    int e = e0 + tid + i * 256;
    if (e < E) {
      uint_t r = (uint_t)ei[e];
      uint_t c = (uint_t)ei[E + e];
      uint_t b = c >> 8;
      float wv = ew[e];
      uint_t pos = lb[b] + atomicAdd(&lc[b], 1u);
      bkt[pos] = ((u64)(r | ((c & 255u) << 24)) << 32) | (u64)__float_as_uint(wv);
    }
  }
}

// per-bucket: LDS count + weighted degree, scan -> start[], dinv[]
__global__ __launch_bounds__(256) void bucket_stats(
    const u64* __restrict__ bkt, const int* __restrict__ bbase,
    int* __restrict__ start, float* __restrict__ dinv, int n, int E) {
  int b = blockIdx.x;
  __shared__ uint_t cnt[256];
  __shared__ float deg[256];
  __shared__ int ssc[256];
  int tid = threadIdx.x;
  cnt[tid] = 0;
  deg[tid] = 0.f;
  __syncthreads();
  int s = bbase[b], e_end = bbase[b + 1];
  for (int p = s + tid; p < e_end; p += 256) {
    u64 v = bkt[p];
    uint_t cl = (uint_t)(v >> 56);
    float wv = __uint_as_float((uint_t)(v & 0xffffffffULL));
    atomicAdd(&cnt[cl], 1u);
    atomicAdd(&deg[cl], wv);
  }
  __syncthreads();
  int v0 = (int)cnt[tid];
  ssc[tid] = v0;
  __syncthreads();
  for (int off = 1; off < 256; off <<= 1) {
    int u = (tid >= off) ? ssc[tid - off] : 0;
    __syncthreads();
    ssc[tid] += u;
    __syncthreads();
  }
  int node = (b << 8) + tid;
  if (node < n) {
    start[node] = s + ssc[tid] - v0;
    float d = deg[tid];
    dinv[node] = d > 0.f ? rsqrtf(fmaxf(d, 1e-12f)) : 0.f;
  }
  if (b == 0 && tid == 0) start[n] = E;
}

// per-bucket: emit meta {r, nrm}; scattered writes stay in the bucket's CSR window
__global__ __launch_bounds__(256) void bucket_emit(
    const u64* __restrict__ bkt, const int* __restrict__ bbase, const int* __restrict__ start,
    const float* __restrict__ dinv, u32x2* __restrict__ meta, int n) {
  int b = blockIdx.x;
  __shared__ uint_t lcur[256];
  int tid = threadIdx.x;
  lcur[tid] = 0;
  __syncthreads();
  int s = bbase[b], e_end = bbase[b + 1];
  for (int p = s + tid; p < e_end; p += 256) {
    u64 v = bkt[p];
    uint_t hi = (uint_t)(v >> 32);
    uint_t r = hi & 0xffffffu;
    uint_t cl = hi >> 24;
    float wv = __uint_as_float((uint_t)(v & 0xffffffffULL));
    uint_t node = ((uint_t)b << 8) + cl;
    float nrm = dinv[r] * wv * dinv[node];
    uint_t slot = (uint_t)start[node] + atomicAdd(&lcur[cl], 1u);
    u32x2 m;
    m.x = r;
    m.y = __float_as_uint(nrm);
    meta[slot] = m;
  }
}

// x (n x 26 fp32) -> padded bf16 (n x 32), zeros in cols 26..31
__global__ void convert_x(const float* __restrict__ in, uint_t* __restrict__ out, int n) {
  int idx = blockIdx.x * 256 + threadIdx.x;
  if (idx >= n * 16) return;
  int node = idx >> 4, lane = idx & 15;
  float f0 = 0.f, f1 = 0.f;
  if (lane < 13) {
    f0 = in[node * 26 + 2 * lane];
    f1 = in[node * 26 + 2 * lane + 1];
  }
  out[idx] = pack2(f0, f1);
}

// ---------------- W swizzle into MFMA B-fragment order ----------------
// out layout: [t (global kstep)][j 0..7][lane 0..63][i 0..7] bf16
// fragment element = B[k][col], k = 32*t_in_src + 8*(lane>>4) + i, col = 16*j + (lane&15)

__global__ void swizzleW_kcat(const float* __restrict__ W, ushort_t* __restrict__ out,
                              int ksps, int kwv, int nsrc) {
  int idx = blockIdx.x * 256 + threadIdx.x;
  int total = nsrc * ksps * 4096;
  if (idx >= total) return;
  int i = idx & 7, l = (idx >> 3) & 63, j = (idx >> 9) & 7, t = idx >> 12;
  int s = t / ksps, tt = t - s * ksps;
  int k = tt * 32 + 8 * (l >> 4) + i;
  int col = 16 * j + (l & 15);
  float v = (k < kwv) ? W[((size_t)s * kwv + k) * 128 + col] : 0.f;
  out[idx] = f2b(v);
}

__global__ void swizzleW_nslot(const float* __restrict__ W, ushort_t* __restrict__ out) {
  int idx = blockIdx.x * 256 + threadIdx.x;
  if (idx >= 4 * 4096) return;
  int i = idx & 7, l = (idx >> 3) & 63, j = (idx >> 9) & 7, t = idx >> 12;
  int k = t * 32 + 8 * (l >> 4) + i;
  int col = 16 * j + (l & 15);
  int s = col >> 5, c = col & 31;
  float v = (c < 26) ? W[((size_t)s * 128 + k) * 26 + c] : 0.f;
  out[idx] = f2b(v);
}

// ---------------- SpMM (pull, CSR by destination, bf16, interleaved meta) ----------------

// width 128: wave per node; 16 lanes per edge-slot, dwordx4 gathers;
// 16 independent edge chains in flight (four quads per iteration).
__global__ __launch_bounds__(256) void spmm128_bf(
    const u32x2* __restrict__ meta, const int* __restrict__ start,
    const uint_t* __restrict__ in, uint_t* __restrict__ out, int n) {
  int node = blockIdx.x * 4 + (threadIdx.x >> 6);
  int lane = threadIdx.x & 63;
  if (node >= n) return;
  int s = start[node], m = start[node + 1] - s;
  int eq = lane >> 4;   // which edge of the quad
  int f16 = lane & 15;  // 16B chunk within 256B row
  float a0 = 0.f, a1 = 0.f, a2 = 0.f, a3 = 0.f, a4 = 0.f, a5 = 0.f, a6 = 0.f, a7 = 0.f;
  for (int base = 0; base < m; base += 16) {
    int i0 = base + eq, i1 = i0 + 4, i2 = i0 + 8, i3 = i0 + 12;
    u32x2 mt0 = (i0 < m) ? meta[s + i0] : (u32x2){0u, 0u};
    u32x2 mt1 = (i1 < m) ? meta[s + i1] : (u32x2){0u, 0u};
    u32x2 mt2 = (i2 < m) ? meta[s + i2] : (u32x2){0u, 0u};
    u32x2 mt3 = (i3 < m) ? meta[s + i3] : (u32x2){0u, 0u};
    u32x4 v0 = *reinterpret_cast<const u32x4*>(in + (size_t)mt0.x * 64 + f16 * 4);
    u32x4 v1 = *reinterpret_cast<const u32x4*>(in + (size_t)mt1.x * 64 + f16 * 4);
    u32x4 v2 = *reinterpret_cast<const u32x4*>(in + (size_t)mt2.x * 64 + f16 * 4);
    u32x4 v3 = *reinterpret_cast<const u32x4*>(in + (size_t)mt3.x * 64 + f16 * 4);
    float w0 = __uint_as_float(mt0.y);
    float w1 = __uint_as_float(mt1.y);
    float w2 = __uint_as_float(mt2.y);
    float w3 = __uint_as_float(mt3.y);
    a0 += w0 * lo16(v0.x); a1 += w0 * hi16(v0.x);
    a2 += w0 * lo16(v0.y); a3 += w0 * hi16(v0.y);
    a4 += w0 * lo16(v0.z); a5 += w0 * hi16(v0.z);
    a6 += w0 * lo16(v0.w); a7 += w0 * hi16(v0.w);
    a0 += w1 * lo16(v1.x); a1 += w1 * hi16(v1.x);
    a2 += w1 * lo16(v1.y); a3 += w1 * hi16(v1.y);
    a4 += w1 * lo16(v1.z); a5 += w1 * hi16(v1.z);
    a6 += w1 * lo16(v1.w); a7 += w1 * hi16(v1.w);
    a0 += w2 * lo16(v2.x); a1 += w2 * hi16(v2.x);
    a2 += w2 * lo16(v2.y); a3 += w2 * hi16(v2.y);
    a4 += w2 * lo16(v2.z); a5 += w2 * hi16(v2.z);
    a6 += w2 * lo16(v2.w); a7 += w2 * hi16(v2.w);
    a0 += w3 * lo16(v3.x); a1 += w3 * hi16(v3.x);
    a2 += w3 * lo16(v3.y); a3 += w3 * hi16(v3.y);
    a4 += w3 * lo16(v3.z); a5 += w3 * hi16(v3.z);
    a6 += w3 * lo16(v3.w); a7 += w3 * hi16(v3.w);
  }
  a0 += __shfl_xor(a0, 16); a1 += __shfl_xor(a1, 16);
  a2 += __shfl_xor(a2, 16); a3 += __shfl_xor(a3, 16);
  a4 += __shfl_xor(a4, 16); a5 += __shfl_xor(a5, 16);
  a6 += __shfl_xor(a6, 16); a7 += __shfl_xor(a7, 16);
  a0 += __shfl_xor(a0, 32); a1 += __shfl_xor(a1, 32);
  a2 += __shfl_xor(a2, 32); a3 += __shfl_xor(a3, 32);
  a4 += __shfl_xor(a4, 32); a5 += __shfl_xor(a5, 32);
  a6 += __shfl_xor(a6, 32); a7 += __shfl_xor(a7, 32);
  if (eq == 0) {
    u32x4 o;
    o.x = pack2(a0, a1);
    o.y = pack2(a2, a3);
    o.z = pack2(a4, a5);
    o.w = pack2(a6, a7);
    *reinterpret_cast<u32x4*>(out + (size_t)node * 64 + f16 * 4) = o;
  }
}

// width 32-padded: 8 lanes per node (dwordx2 each), 8 edges per chunk
__global__ __launch_bounds__(256) void spmm26_bf(
    const u32x2* __restrict__ meta, const int* __restrict__ start,
    const uint_t* __restrict__ in, const uint_t* __restrict__ add,
    uint_t* __restrict__ out, int n) {
  int node = blockIdx.x * 32 + (threadIdx.x >> 3);
  int d2 = threadIdx.x & 7;  // dword-pair index (cols 4*d2..4*d2+3)
  if (node >= n) return;
  int s = start[node], m = start[node + 1] - s;
  float a0 = 0.f, a1 = 0.f, a2 = 0.f, a3 = 0.f;
  for (int base = 0; base < m; base += 8) {
#pragma unroll
    for (int j = 0; j < 8; ++j) {
      int eidx = base + j;
      u32x2 mt = (eidx < m) ? meta[s + eidx] : (u32x2){0u, 0u};
      int r = (int)mt.x;
      float wv = __uint_as_float(mt.y);
      u32x2 v = *reinterpret_cast<const u32x2*>(in + (size_t)r * 16 + 2 * d2);
      a0 += wv * lo16(v.x); a1 += wv * hi16(v.x);
      a2 += wv * lo16(v.y); a3 += wv * hi16(v.y);
    }
  }
  if (add) {
    u32x2 v = *reinterpret_cast<const u32x2*>(add + (size_t)node * 16 + 2 * d2);
    a0 += lo16(v.x); a1 += hi16(v.x);
    a2 += lo16(v.y); a3 += hi16(v.y);
  }
  u32x2 o;
  o.x = pack2(a0, a1);
  o.y = pack2(a2, a3);
  *reinterpret_cast<u32x2*>(out + (size_t)node * 16 + 2 * d2) = o;
}

// final Horner step: out_f32 (n x 26) += A*in
__global__ __launch_bounds__(256) void spmm26_addf(
    const u32x2* __restrict__ meta, const int* __restrict__ start,
    const uint_t* __restrict__ in, float* __restrict__ out, int n) {
  int node = blockIdx.x * 32 + (threadIdx.x >> 3);
  int d2 = threadIdx.x & 7;
  if (node >= n) return;
  int s = start[node], m = start[node + 1] - s;
  float a0 = 0.f, a1 = 0.f, a2 = 0.f, a3 = 0.f;
  for (int base = 0; base < m; base += 8) {
#pragma unroll
    for (int j = 0; j < 8; ++j) {
      int eidx = base + j;
      u32x2 mt = (eidx < m) ? meta[s + eidx] : (u32x2){0u, 0u};
      int r = (int)mt.x;
      float wv = __uint_as_float(mt.y);
      u32x2 v = *reinterpret_cast<const u32x2*>(in + (size_t)r * 16 + 2 * d2);
      a0 += wv * lo16(v.x); a1 += wv * hi16(v.x);
      a2 += wv * lo16(v.y); a3 += wv * hi16(v.y);
    }
  }
  int c0 = 4 * d2;
  if (c0 + 0 < 26) out[(size_t)node * 26 + c0 + 0] += a0;
  if (c0 + 1 < 26) out[(size_t)node * 26 + c0 + 1] += a1;
  if (c0 + 2 < 26) out[(size_t)node * 26 + c0 + 2] += a2;
  if (c0 + 3 < 26) out[(size_t)node * 26 + c0 + 3] += a3;
}

// ---------------- fused MFMA GEMM ----------------
// C(n x 128) = [A0|A1|A2|A3] (each n x KW bf16) @ Wswz (+bias)
// EPI 0: ELU, write bf16 n x 128 to outb
// EPI 1: layer-3 slots: slot0 -> outf (n x 26 fp32, +bias); slots 1..3 -> outb (3 x n x 32 bf16)
// MR=1: 64 rows per block (16 per wave) -> 1563 blocks for latency hiding via TLP.
template <int KW, int NSRC, int EPI, int MR>
__global__ __launch_bounds__(256) void mfma_gemm(
    const ushort_t* __restrict__ A0, const ushort_t* __restrict__ A1,
    const ushort_t* __restrict__ A2, const ushort_t* __restrict__ A3,
    const ushort_t* __restrict__ Wswz, const float* __restrict__ bias,
    ushort_t* __restrict__ outb, float* __restrict__ outf, int n) {
  constexpr int KSPS = KW / 32;
  constexpr int KSTEPS = NSRC * KSPS;
  const int w = threadIdx.x >> 6;
  const int l = threadIdx.x & 63;
  const int row0 = blockIdx.x * (64 * MR) + w * (16 * MR);
  const int koff = 8 * (l >> 4);  // elements

  f32x4 acc[MR][8];
#pragma unroll
  for (int f = 0; f < MR; ++f)
#pragma unroll
    for (int j = 0; j < 8; ++j) acc[f][j] = (f32x4){0.f, 0.f, 0.f, 0.f};

  const ushort_t* const srcs[4] = {A0, A1, A2, A3};

#pragma unroll
  for (int t = 0; t < KSTEPS; ++t) {
    const int s = t / KSPS;
    const int tt = t - s * KSPS;
    bf16x8 af[MR];
#pragma unroll
    for (int f = 0; f < MR; ++f) {
      int arow = row0 + f * 16 + (l & 15);
      int arow_c = arow < n ? arow : (n - 1);
      af[f] = ld_frag(srcs[s] + (size_t)arow_c * KW + tt * 32 + koff);
    }
    const ushort_t* wp = Wswz + ((size_t)t * 8 * 64 + l) * 8;
#pragma unroll
    for (int j = 0; j < 8; ++j) {
      bf16x8 bfr = ld_frag(wp + (size_t)j * 64 * 8);
#pragma unroll
      for (int f = 0; f < MR; ++f)
        acc[f][j] = __builtin_amdgcn_mfma_f32_16x16x32_bf16(af[f], bfr, acc[f][j], 0, 0, 0);
    }
  }

  const int ccol = l & 15;
#pragma unroll
  for (int f = 0; f < MR; ++f) {
    const int crow0 = row0 + f * 16 + 4 * (l >> 4);
#pragma unroll
    for (int j = 0; j < 8; ++j) {
      if (EPI == 0) {
        int col = 16 * j + ccol;
        float bi = bias[col];
#pragma unroll
        for (int r = 0; r < 4; ++r) {
          int row = crow0 + r;
          if (row >= n) continue;
          float v = acc[f][j][r] + bi;
          v = v > 0.f ? v : (__expf(v) - 1.f);
          outb[(size_t)row * 128 + col] = f2b(v);
        }
      } else {
        int slot = j >> 1;
        int c = 16 * (j & 1) + ccol;
#pragma unroll
        for (int r = 0; r < 4; ++r) {
          int row = crow0 + r;
          if (row >= n) continue;
          float v = acc[f][j][r];
          if (slot == 0) {
            if (c < 26) outf[(size_t)row * 26 + c] = v + bias[c];
          } else {
            outb[((size_t)(slot - 1) * n + row) * 32 + c] = f2b(v);
          }
        }
      }
    }
  }
}

// ---------------- launcher ----------------

extern "C" void kernel_launch(void* const* d_in, const int* in_sizes, int n_in,
                              void* d_out, int out_size, void* d_ws, size_t ws_size,
                              hipStream_t stream) {
  const float* x  = (const float*)d_in[0];
  const int*   ei = (const int*)d_in[1];
  const float* ew = (const float*)d_in[2];
  const float* W1 = (const float*)d_in[3];
  const float* b1 = (const float*)d_in[4];
  const float* W2 = (const float*)d_in[5];
  const float* b2 = (const float*)d_in[6];
  const float* W3 = (const float*)d_in[7];
  const float* b3 = (const float*)d_in[8];
  float* out = (float*)d_out;

  const int n = in_sizes[0] / NCLS;  // 100000
  const int E = in_sizes[2];         // 1600000
  const int nbk = (n + 255) >> 8;    // 391 buckets

  char* w = (char*)d_ws;
  auto alloc = [&](size_t bytes) {
    char* p = w;
    w += (bytes + 255) / 256 * 256;
    return p;
  };
  // width-128 bf16 feature buffers (64 dwords per node)
  uint_t* H0 = (uint_t*)alloc((size_t)n * 64 * 4);
  uint_t* P1 = (uint_t*)alloc((size_t)n * 64 * 4);
  uint_t* P2 = (uint_t*)alloc((size_t)n * 64 * 4);
  uint_t* P3 = (uint_t*)alloc((size_t)n * 64 * 4);
  uint_t* H1 = (uint_t*)alloc((size_t)n * 64 * 4);
  // width-32-padded bf16 buffers (16 dwords per node)
  uint_t* x32 = (uint_t*)alloc((size_t)n * 16 * 4);
  uint_t* q1  = (uint_t*)alloc((size_t)n * 16 * 4);
  uint_t* q2  = (uint_t*)alloc((size_t)n * 16 * 4);
  uint_t* q3  = (uint_t*)alloc((size_t)n * 16 * 4);
  uint_t* zb  = (uint_t*)alloc((size_t)n * 48 * 4);  // z1,z2,z3 each n x 32 bf16
  // swizzled weights
  ushort_t* Wz1 = (ushort_t*)alloc(4 * 4096 * 2);
  ushort_t* Wz2 = (ushort_t*)alloc(16 * 4096 * 2);
  ushort_t* Wz3 = (ushort_t*)alloc(4 * 4096 * 2);
  // graph CSR
  u64*   bkt  = (u64*)zb;  // alias: bkt (12.8MB) dead before zb (19.2MB) is used
  u32x2* meta = (u32x2*)alloc((size_t)E * 8);
  int*   start = (int*)alloc((size_t)(n + 1) * 4);
  float* dinv  = (float*)alloc((size_t)n * 4);
  int*   bcnt  = (int*)alloc(MAXBK * 4);
  int*   gcur  = (int*)alloc(MAXBK * 4);
  int*   bbase = (int*)alloc((MAXBK + 1) * 4);

  const int ab = (E + EPB - 1) / EPB;  // bucketing blocks (196)

  hipMemsetAsync(bcnt, 0, MAXBK * 4, stream);
  hipMemsetAsync(gcur, 0, MAXBK * 4, stream);

  bucket_count<<<ab, 256, 0, stream>>>(ei, bcnt, E, nbk);
  scan_buckets<<<1, 512, 0, stream>>>(bcnt, bbase, nbk, E);
  bucket_place<<<ab, 256, 0, stream>>>(ei, ew, bbase, gcur, bkt, E, nbk);
  bucket_stats<<<nbk, 256, 0, stream>>>(bkt, bbase, start, dinv, n, E);
  bucket_emit<<<nbk, 256, 0, stream>>>(bkt, bbase, start, dinv, meta, n);

  convert_x<<<(n * 16 + 255) / 256, 256, 0, stream>>>(x, x32, n);
  swizzleW_kcat<<<(4 * 4096 + 255) / 256, 256, 0, stream>>>(W1, Wz1, 1, NCLS, 4);
  swizzleW_kcat<<<(16 * 4096 + 255) / 256, 256, 0, stream>>>(W2, Wz2, 4, HID, 4);
  swizzleW_nslot<<<(4 * 4096 + 255) / 256, 256, 0, stream>>>(W3, Wz3);

  const int g128 = (n + 3) / 4;
  const int g26  = (n + 31) / 32;
  const int gg   = (n + 63) / 64;  // mfma_gemm grid (MR=1: 64 rows/block)

  // ---- Layer 1: q_k = A^k x (width 32-padded), H0 = ELU([x|q1|q2|q3] @ W1cat + b1) ----
  spmm26_bf<<<g26, 256, 0, stream>>>(meta, start, x32, nullptr, q1, n);
  spmm26_bf<<<g26, 256, 0, stream>>>(meta, start, q1, nullptr, q2, n);
  spmm26_bf<<<g26, 256, 0, stream>>>(meta, start, q2, nullptr, q3, n);
  mfma_gemm<32, 4, 0, 1><<<gg, 256, 0, stream>>>(
      (const ushort_t*)x32, (const ushort_t*)q1, (const ushort_t*)q2, (const ushort_t*)q3,
      Wz1, b1, (ushort_t*)H0, nullptr, n);

  // ---- Layer 2: P_k = A^k H0, H1 = ELU([H0|P1|P2|P3] @ W2cat + b2) ----
  spmm128_bf<<<g128, 256, 0, stream>>>(meta, start, H0, P1, n);
  spmm128_bf<<<g128, 256, 0, stream>>>(meta, start, P1, P2, n);
  spmm128_bf<<<g128, 256, 0, stream>>>(meta, start, P2, P3, n);
  mfma_gemm<128, 4, 0, 1><<<gg, 256, 0, stream>>>(
      (const ushort_t*)H0, (const ushort_t*)P1, (const ushort_t*)P2, (const ushort_t*)P3,
      Wz2, b2, (ushort_t*)H1, nullptr, n);

  // ---- Layer 3: Z = H1 @ [W3_0|W3_1|W3_2|W3_3]; Horner out = z0+b3 + A(z1 + A(z2 + A z3)) ----
  // NOTE: zb aliases bkt, which is dead after bucket_emit — safe.
  mfma_gemm<128, 1, 1, 1><<<gg, 256, 0, stream>>>(
      (const ushort_t*)H1, (const ushort_t*)H1, (const ushort_t*)H1, (const ushort_t*)H1,
      Wz3, b3, (ushort_t*)zb, out, n);

  uint_t* z1 = zb;
  uint_t* z2 = zb + (size_t)n * 16;
  uint_t* z3 = zb + (size_t)n * 32;
  spmm26_bf<<<g26, 256, 0, stream>>>(meta, start, z3, z2, q1, n);  // q1 = z2 + A z3
  spmm26_bf<<<g26, 256, 0, stream>>>(meta, start, q1, z1, q2, n);  // q2 = z1 + A q1
  spmm26_addf<<<g26, 256, 0, stream>>>(meta, start, q2, out, n);   // out += A q2
}

// Round 8
// 543.546 us; speedup vs baseline: 6.9030x; 1.0089x over previous
//
#include <hip/hip_runtime.h>

#define NCLS 26
#define HID 128
#define EPB 8192   // edges per bucketing block
#define MAXBK 512  // max buckets (supports n <= 131072)
typedef unsigned short ushort_t;
typedef unsigned int uint_t;
typedef unsigned long long u64;

typedef __bf16 bf16x8 __attribute__((ext_vector_type(8)));
typedef float f32x4 __attribute__((ext_vector_type(4)));
typedef unsigned int u32x4 __attribute__((ext_vector_type(4)));
typedef unsigned int u32x2 __attribute__((ext_vector_type(2)));

// ---------------- bf16 helpers (ushort storage) ----------------
static __device__ __forceinline__ float b2f(ushort_t h) {
  return __uint_as_float(((uint_t)h) << 16);
}
static __device__ __forceinline__ ushort_t f2b(float f) {
  uint_t u = __float_as_uint(f);
  uint_t r = (u + 0x7fffu + ((u >> 16) & 1u)) >> 16;
  return (ushort_t)r;
}
static __device__ __forceinline__ uint_t pack2(float f0, float f1) {
  return (uint_t)f2b(f0) | ((uint_t)f2b(f1) << 16);
}
static __device__ __forceinline__ float lo16(uint_t v) { return b2f((ushort_t)(v & 0xffffu)); }
static __device__ __forceinline__ float hi16(uint_t v) { return b2f((ushort_t)(v >> 16)); }
static __device__ __forceinline__ bf16x8 ld_frag(const ushort_t* p) {
  u32x4 v = *reinterpret_cast<const u32x4*>(p);
  return __builtin_bit_cast(bf16x8, v);
}

// ---------------- preprocessing: two-level bucket sort ----------------
// bucket(c) = c >> 8 (256 nodes per bucket). Packed bucket record (u64):
// hi32 = r | (c_local << 24), lo32 = fp32 weight bits.

__global__ __launch_bounds__(256) void bucket_count(const int* __restrict__ ei,
                                                    int* __restrict__ bcnt, int E, int nbk) {
  __shared__ uint_t lc[MAXBK];
  int tid = threadIdx.x;
  for (int t = tid; t < nbk; t += 256) lc[t] = 0;
  __syncthreads();
  int e0 = blockIdx.x * EPB;
#pragma unroll
  for (int i = 0; i < EPB / 256; ++i) {
    int e = e0 + tid + i * 256;
    if (e < E) atomicAdd(&lc[(uint_t)ei[E + e] >> 8], 1u);
  }
  __syncthreads();
  for (int t = tid; t < nbk; t += 256)
    if (lc[t]) atomicAdd(&bcnt[t], (int)lc[t]);
}

__global__ void scan_buckets(const int* __restrict__ bcnt, int* __restrict__ bbase,
                             int nbk, int E) {
  __shared__ int s[512];
  int t = threadIdx.x;
  int v = (t < nbk) ? bcnt[t] : 0;
  s[t] = v;
  __syncthreads();
  for (int off = 1; off < 512; off <<= 1) {
    int u = (t >= off) ? s[t - off] : 0;
    __syncthreads();
    s[t] += u;
    __syncthreads();
  }
  if (t < nbk) bbase[t] = s[t] - v;
  if (t == 0) bbase[nbk] = E;
}

__global__ __launch_bounds__(256) void bucket_place(
    const int* __restrict__ ei, const float* __restrict__ ew, const int* __restrict__ bbase,
    int* __restrict__ gcur, u64* __restrict__ bkt, int E, int nbk) {
  __shared__ uint_t lc[MAXBK];
  __shared__ uint_t lb[MAXBK];
  int tid = threadIdx.x;
  for (int t = tid; t < nbk; t += 256) lc[t] = 0;
  __syncthreads();
  int e0 = blockIdx.x * EPB;
#pragma unroll
  for (int i = 0; i < EPB / 256; ++i) {
    int e = e0 + tid + i * 256;
    if (e < E) atomicAdd(&lc[(uint_t)ei[E + e] >> 8], 1u);
  }
  __syncthreads();
  for (int t = tid; t < nbk; t += 256) {
    uint_t c = lc[t];
    lb[t] = c ? (uint_t)(bbase[t] + atomicAdd(&gcur[t], (int)c)) : 0u;
    lc[t] = 0;
  }
  __syncthreads();
#pragma unroll
  for (int i = 0; i < EPB / 256; ++i) {
    int e = e0 + tid + i * 256;
    if (e < E) {
      uint_t r = (uint_t)ei[e];
      uint_t c = (uint_t)ei[E + e];
      uint_t b = c >> 8;
      float wv = ew[e];
      uint_t pos = lb[b] + atomicAdd(&lc[b], 1u);
      bkt[pos] = ((u64)(r | ((c & 255u) << 24)) << 32) | (u64)__float_as_uint(wv);
    }
  }
}

// per-bucket: LDS count + weighted degree, scan -> start[], dinv[]
__global__ __launch_bounds__(256) void bucket_stats(
    const u64* __restrict__ bkt, const int* __restrict__ bbase,
    int* __restrict__ start, float* __restrict__ dinv, int n, int E) {
  int b = blockIdx.x;
  __shared__ uint_t cnt[256];
  __shared__ float deg[256];
  __shared__ int ssc[256];
  int tid = threadIdx.x;
  cnt[tid] = 0;
  deg[tid] = 0.f;
  __syncthreads();
  int s = bbase[b], e_end = bbase[b + 1];
  for (int p = s + tid; p < e_end; p += 256) {
    u64 v = bkt[p];
    uint_t cl = (uint_t)(v >> 56);
    float wv = __uint_as_float((uint_t)(v & 0xffffffffULL));
    atomicAdd(&cnt[cl], 1u);
    atomicAdd(&deg[cl], wv);
  }
  __syncthreads();
  int v0 = (int)cnt[tid];
  ssc[tid] = v0;
  __syncthreads();
  for (int off = 1; off < 256; off <<= 1) {
    int u = (tid >= off) ? ssc[tid - off] : 0;
    __syncthreads();
    ssc[tid] += u;
    __syncthreads();
  }
  int node = (b << 8) + tid;
  if (node < n) {
    start[node] = s + ssc[tid] - v0;
    float d = deg[tid];
    dinv[node] = d > 0.f ? rsqrtf(fmaxf(d, 1e-12f)) : 0.f;
  }
  if (b == 0 && tid == 0) start[n] = E;
}

// per-bucket: emit meta {r, nrm}; scattered writes stay in the bucket's CSR window
__global__ __launch_bounds__(256) void bucket_emit(
    const u64* __restrict__ bkt, const int* __restrict__ bbase, const int* __restrict__ start,
    const float* __restrict__ dinv, u32x2* __restrict__ meta, int n) {
  int b = blockIdx.x;
  __shared__ uint_t lcur[256];
  int tid = threadIdx.x;
  lcur[tid] = 0;
  __syncthreads();
  int s = bbase[b], e_end = bbase[b + 1];
  for (int p = s + tid; p < e_end; p += 256) {
    u64 v = bkt[p];
    uint_t hi = (uint_t)(v >> 32);
    uint_t r = hi & 0xffffffu;
    uint_t cl = hi >> 24;
    float wv = __uint_as_float((uint_t)(v & 0xffffffffULL));
    uint_t node = ((uint_t)b << 8) + cl;
    float nrm = dinv[r] * wv * dinv[node];
    uint_t slot = (uint_t)start[node] + atomicAdd(&lcur[cl], 1u);
    u32x2 m;
    m.x = r;
    m.y = __float_as_uint(nrm);
    meta[slot] = m;
  }
}

// x (n x 26 fp32) -> padded bf16 (n x 32), zeros in cols 26..31
__global__ void convert_x(const float* __restrict__ in, uint_t* __restrict__ out, int n) {
  int idx = blockIdx.x * 256 + threadIdx.x;
  if (idx >= n * 16) return;
  int node = idx >> 4, lane = idx & 15;
  float f0 = 0.f, f1 = 0.f;
  if (lane < 13) {
    f0 = in[node * 26 + 2 * lane];
    f1 = in[node * 26 + 2 * lane + 1];
  }
  out[idx] = pack2(f0, f1);
}

// ---------------- W swizzle into MFMA B-fragment order ----------------
// out layout: [t (global kstep)][j 0..7][lane 0..63][i 0..7] bf16
// fragment element = B[k][col], k = 32*t_in_src + 8*(lane>>4) + i, col = 16*j + (lane&15)

__global__ void swizzleW_kcat(const float* __restrict__ W, ushort_t* __restrict__ out,
                              int ksps, int kwv, int nsrc) {
  int idx = blockIdx.x * 256 + threadIdx.x;
  int total = nsrc * ksps * 4096;
  if (idx >= total) return;
  int i = idx & 7, l = (idx >> 3) & 63, j = (idx >> 9) & 7, t = idx >> 12;
  int s = t / ksps, tt = t - s * ksps;
  int k = tt * 32 + 8 * (l >> 4) + i;
  int col = 16 * j + (l & 15);
  float v = (k < kwv) ? W[((size_t)s * kwv + k) * 128 + col] : 0.f;
  out[idx] = f2b(v);
}

__global__ void swizzleW_nslot(const float* __restrict__ W, ushort_t* __restrict__ out) {
  int idx = blockIdx.x * 256 + threadIdx.x;
  if (idx >= 4 * 4096) return;
  int i = idx & 7, l = (idx >> 3) & 63, j = (idx >> 9) & 7, t = idx >> 12;
  int k = t * 32 + 8 * (l >> 4) + i;
  int col = 16 * j + (l & 15);
  int s = col >> 5, c = col & 31;
  float v = (c < 26) ? W[((size_t)s * 128 + k) * 26 + c] : 0.f;
  out[idx] = f2b(v);
}

// ---------------- SpMM (pull, CSR by destination, bf16, interleaved meta) ----------------

// width 128: wave per node; 16 lanes per edge-slot, dwordx4 gathers;
// 16 independent edge chains in flight (four quads per iteration).
__global__ __launch_bounds__(256) void spmm128_bf(
    const u32x2* __restrict__ meta, const int* __restrict__ start,
    const uint_t* __restrict__ in, uint_t* __restrict__ out, int n) {
  int node = blockIdx.x * 4 + (threadIdx.x >> 6);
  int lane = threadIdx.x & 63;
  if (node >= n) return;
  int s = start[node], m = start[node + 1] - s;
  int eq = lane >> 4;   // which edge of the quad
  int f16 = lane & 15;  // 16B chunk within 256B row
  float a0 = 0.f, a1 = 0.f, a2 = 0.f, a3 = 0.f, a4 = 0.f, a5 = 0.f, a6 = 0.f, a7 = 0.f;
  for (int base = 0; base < m; base += 16) {
    int i0 = base + eq, i1 = i0 + 4, i2 = i0 + 8, i3 = i0 + 12;
    u32x2 mt0 = (i0 < m) ? meta[s + i0] : (u32x2){0u, 0u};
    u32x2 mt1 = (i1 < m) ? meta[s + i1] : (u32x2){0u, 0u};
    u32x2 mt2 = (i2 < m) ? meta[s + i2] : (u32x2){0u, 0u};
    u32x2 mt3 = (i3 < m) ? meta[s + i3] : (u32x2){0u, 0u};
    u32x4 v0 = *reinterpret_cast<const u32x4*>(in + (size_t)mt0.x * 64 + f16 * 4);
    u32x4 v1 = *reinterpret_cast<const u32x4*>(in + (size_t)mt1.x * 64 + f16 * 4);
    u32x4 v2 = *reinterpret_cast<const u32x4*>(in + (size_t)mt2.x * 64 + f16 * 4);
    u32x4 v3 = *reinterpret_cast<const u32x4*>(in + (size_t)mt3.x * 64 + f16 * 4);
    float w0 = __uint_as_float(mt0.y);
    float w1 = __uint_as_float(mt1.y);
    float w2 = __uint_as_float(mt2.y);
    float w3 = __uint_as_float(mt3.y);
    a0 += w0 * lo16(v0.x); a1 += w0 * hi16(v0.x);
    a2 += w0 * lo16(v0.y); a3 += w0 * hi16(v0.y);
    a4 += w0 * lo16(v0.z); a5 += w0 * hi16(v0.z);
    a6 += w0 * lo16(v0.w); a7 += w0 * hi16(v0.w);
    a0 += w1 * lo16(v1.x); a1 += w1 * hi16(v1.x);
    a2 += w1 * lo16(v1.y); a3 += w1 * hi16(v1.y);
    a4 += w1 * lo16(v1.z); a5 += w1 * hi16(v1.z);
    a6 += w1 * lo16(v1.w); a7 += w1 * hi16(v1.w);
    a0 += w2 * lo16(v2.x); a1 += w2 * hi16(v2.x);
    a2 += w2 * lo16(v2.y); a3 += w2 * hi16(v2.y);
    a4 += w2 * lo16(v2.z); a5 += w2 * hi16(v2.z);
    a6 += w2 * lo16(v2.w); a7 += w2 * hi16(v2.w);
    a0 += w3 * lo16(v3.x); a1 += w3 * hi16(v3.x);
    a2 += w3 * lo16(v3.y); a3 += w3 * hi16(v3.y);
    a4 += w3 * lo16(v3.z); a5 += w3 * hi16(v3.z);
    a6 += w3 * lo16(v3.w); a7 += w3 * hi16(v3.w);
  }
  a0 += __shfl_xor(a0, 16); a1 += __shfl_xor(a1, 16);
  a2 += __shfl_xor(a2, 16); a3 += __shfl_xor(a3, 16);
  a4 += __shfl_xor(a4, 16); a5 += __shfl_xor(a5, 16);
  a6 += __shfl_xor(a6, 16); a7 += __shfl_xor(a7, 16);
  a0 += __shfl_xor(a0, 32); a1 += __shfl_xor(a1, 32);
  a2 += __shfl_xor(a2, 32); a3 += __shfl_xor(a3, 32);
  a4 += __shfl_xor(a4, 32); a5 += __shfl_xor(a5, 32);
  a6 += __shfl_xor(a6, 32); a7 += __shfl_xor(a7, 32);
  if (eq == 0) {
    u32x4 o;
    o.x = pack2(a0, a1);
    o.y = pack2(a2, a3);
    o.z = pack2(a4, a5);
    o.w = pack2(a6, a7);
    *reinterpret_cast<u32x4*>(out + (size_t)node * 64 + f16 * 4) = o;
  }
}

// width 32-padded: 8 lanes per node (dwordx2 each), 8 edges per chunk
__global__ __launch_bounds__(256) void spmm26_bf(
    const u32x2* __restrict__ meta, const int* __restrict__ start,
    const uint_t* __restrict__ in, const uint_t* __restrict__ add,
    uint_t* __restrict__ out, int n) {
  int node = blockIdx.x * 32 + (threadIdx.x >> 3);
  int d2 = threadIdx.x & 7;  // dword-pair index (cols 4*d2..4*d2+3)
  if (node >= n) return;
  int s = start[node], m = start[node + 1] - s;
  float a0 = 0.f, a1 = 0.f, a2 = 0.f, a3 = 0.f;
  for (int base = 0; base < m; base += 8) {
#pragma unroll
    for (int j = 0; j < 8; ++j) {
      int eidx = base + j;
      u32x2 mt = (eidx < m) ? meta[s + eidx] : (u32x2){0u, 0u};
      int r = (int)mt.x;
      float wv = __uint_as_float(mt.y);
      u32x2 v = *reinterpret_cast<const u32x2*>(in + (size_t)r * 16 + 2 * d2);
      a0 += wv * lo16(v.x); a1 += wv * hi16(v.x);
      a2 += wv * lo16(v.y); a3 += wv * hi16(v.y);
    }
  }
  if (add) {
    u32x2 v = *reinterpret_cast<const u32x2*>(add + (size_t)node * 16 + 2 * d2);
    a0 += lo16(v.x); a1 += hi16(v.x);
    a2 += lo16(v.y); a3 += hi16(v.y);
  }
  u32x2 o;
  o.x = pack2(a0, a1);
  o.y = pack2(a2, a3);
  *reinterpret_cast<u32x2*>(out + (size_t)node * 16 + 2 * d2) = o;
}

// final Horner step: out_f32 (n x 26) += A*in
__global__ __launch_bounds__(256) void spmm26_addf(
    const u32x2* __restrict__ meta, const int* __restrict__ start,
    const uint_t* __restrict__ in, float* __restrict__ out, int n) {
  int node = blockIdx.x * 32 + (threadIdx.x >> 3);
  int d2 = threadIdx.x & 7;
  if (node >= n) return;
  int s = start[node], m = start[node + 1] - s;
  float a0 = 0.f, a1 = 0.f, a2 = 0.f, a3 = 0.f;
  for (int base = 0; base < m; base += 8) {
#pragma unroll
    for (int j = 0; j < 8; ++j) {
      int eidx = base + j;
      u32x2 mt = (eidx < m) ? meta[s + eidx] : (u32x2){0u, 0u};
      int r = (int)mt.x;
      float wv = __uint_as_float(mt.y);
      u32x2 v = *reinterpret_cast<const u32x2*>(in + (size_t)r * 16 + 2 * d2);
      a0 += wv * lo16(v.x); a1 += wv * hi16(v.x);
      a2 += wv * lo16(v.y); a3 += wv * hi16(v.y);
    }
  }
  int c0 = 4 * d2;
  if (c0 + 0 < 26) out[(size_t)node * 26 + c0 + 0] += a0;
  if (c0 + 1 < 26) out[(size_t)node * 26 + c0 + 1] += a1;
  if (c0 + 2 < 26) out[(size_t)node * 26 + c0 + 2] += a2;
  if (c0 + 3 < 26) out[(size_t)node * 26 + c0 + 3] += a3;
}

// ---------------- fused MFMA GEMM, LDS-staged W ----------------
// C(n x 128) = [A0|A1|A2|A3] (each n x KW bf16) @ Wswz (+bias)
// W is staged cooperatively into LDS in GROUP-kstep chunks (8 KB per kstep);
// all 4 waves read B-fragments from LDS instead of each streaming W from L2.
// Single-buffer, write -> barrier -> compute; next group's global loads issue
// during the compute phase (latency hidden by TLP across resident blocks).
// EPI 0: ELU, write bf16 n x 128 to outb
// EPI 1: layer-3 slots: slot0 -> outf (n x 26 fp32, +bias); slots 1..3 -> outb (3 x n x 32 bf16)
template <int KW, int NSRC, int EPI, int MR, int GROUP>
__global__ __launch_bounds__(256) void mfma_gemm(
    const ushort_t* __restrict__ A0, const ushort_t* __restrict__ A1,
    const ushort_t* __restrict__ A2, const ushort_t* __restrict__ A3,
    const ushort_t* __restrict__ Wswz, const float* __restrict__ bias,
    ushort_t* __restrict__ outb, float* __restrict__ outf, int n) {
  constexpr int KSPS = KW / 32;
  constexpr int KSTEPS = NSRC * KSPS;
  constexpr int NGROUPS = KSTEPS / GROUP;
  __shared__ ushort_t sW[GROUP * 4096];
  const int tid = threadIdx.x;
  const int w = tid >> 6;
  const int l = tid & 63;
  const int row0 = blockIdx.x * (64 * MR) + w * (16 * MR);
  const int koff = 8 * (l >> 4);  // elements

  f32x4 acc[MR][8];
#pragma unroll
  for (int f = 0; f < MR; ++f)
#pragma unroll
    for (int j = 0; j < 8; ++j) acc[f][j] = (f32x4){0.f, 0.f, 0.f, 0.f};

  const ushort_t* const srcs[4] = {A0, A1, A2, A3};

  // staged W registers: GROUP ksteps x 32 B per thread
  u32x4 gw[2 * GROUP];
#pragma unroll
  for (int c = 0; c < GROUP; ++c) {
    const ushort_t* p = Wswz + (size_t)c * 4096 + tid * 8;
    gw[2 * c] = *reinterpret_cast<const u32x4*>(p);
    gw[2 * c + 1] = *reinterpret_cast<const u32x4*>(p + 2048);
  }

#pragma unroll
  for (int g = 0; g < NGROUPS; ++g) {
    __syncthreads();  // sW writable (all waves done reading previous group)
#pragma unroll
    for (int c = 0; c < GROUP; ++c) {
      *reinterpret_cast<u32x4*>(sW + c * 4096 + tid * 8) = gw[2 * c];
      *reinterpret_cast<u32x4*>(sW + c * 4096 + tid * 8 + 2048) = gw[2 * c + 1];
    }
    if (g + 1 < NGROUPS) {
#pragma unroll
      for (int c = 0; c < GROUP; ++c) {
        const ushort_t* p = Wswz + (size_t)(g + 1) * GROUP * 4096 + (size_t)c * 4096 + tid * 8;
        gw[2 * c] = *reinterpret_cast<const u32x4*>(p);
        gw[2 * c + 1] = *reinterpret_cast<const u32x4*>(p + 2048);
      }
    }
    __syncthreads();  // sW ready
#pragma unroll
    for (int tg = 0; tg < GROUP; ++tg) {
      const int t = g * GROUP + tg;
      const int s = t / KSPS;
      const int tt = t - s * KSPS;
      bf16x8 af[MR];
#pragma unroll
      for (int f = 0; f < MR; ++f) {
        int arow = row0 + f * 16 + (l & 15);
        int arow_c = arow < n ? arow : (n - 1);
        af[f] = ld_frag(srcs[s] + (size_t)arow_c * KW + tt * 32 + koff);
      }
      const ushort_t* wp = sW + tg * 4096 + l * 8;
#pragma unroll
      for (int j = 0; j < 8; ++j) {
        bf16x8 bfr = ld_frag(wp + j * 64 * 8);
#pragma unroll
        for (int f = 0; f < MR; ++f)
          acc[f][j] = __builtin_amdgcn_mfma_f32_16x16x32_bf16(af[f], bfr, acc[f][j], 0, 0, 0);
      }
    }
  }

  const int ccol = l & 15;
#pragma unroll
  for (int f = 0; f < MR; ++f) {
    const int crow0 = row0 + f * 16 + 4 * (l >> 4);
#pragma unroll
    for (int j = 0; j < 8; ++j) {
      if (EPI == 0) {
        int col = 16 * j + ccol;
        float bi = bias[col];
#pragma unroll
        for (int r = 0; r < 4; ++r) {
          int row = crow0 + r;
          if (row >= n) continue;
          float v = acc[f][j][r] + bi;
          v = v > 0.f ? v : (__expf(v) - 1.f);
          outb[(size_t)row * 128 + col] = f2b(v);
        }
      } else {
        int slot = j >> 1;
        int c = 16 * (j & 1) + ccol;
#pragma unroll
        for (int r = 0; r < 4; ++r) {
          int row = crow0 + r;
          if (row >= n) continue;
          float v = acc[f][j][r];
          if (slot == 0) {
            if (c < 26) outf[(size_t)row * 26 + c] = v + bias[c];
          } else {
            outb[((size_t)(slot - 1) * n + row) * 32 + c] = f2b(v);
          }
        }
      }
    }
  }
}

// ---------------- launcher ----------------

extern "C" void kernel_launch(void* const* d_in, const int* in_sizes, int n_in,
                              void* d_out, int out_size, void* d_ws, size_t ws_size,
                              hipStream_t stream) {
  const float* x  = (const float*)d_in[0];
  const int*   ei = (const int*)d_in[1];
  const float* ew = (const float*)d_in[2];
  const float* W1 = (const float*)d_in[3];
  const float* b1 = (const float*)d_in[4];
  const float* W2 = (const float*)d_in[5];
  const float* b2 = (const float*)d_in[6];
  const float* W3 = (const float*)d_in[7];
  const float* b3 = (const float*)d_in[8];
  float* out = (float*)d_out;

  const int n = in_sizes[0] / NCLS;  // 100000
  const int E = in_sizes[2];         // 1600000
  const int nbk = (n + 255) >> 8;    // 391 buckets

  char* w = (char*)d_ws;
  auto alloc = [&](size_t bytes) {
    char* p = w;
    w += (bytes + 255) / 256 * 256;
    return p;
  };
  // width-128 bf16 feature buffers (64 dwords per node)
  uint_t* H0 = (uint_t*)alloc((size_t)n * 64 * 4);
  uint_t* P1 = (uint_t*)alloc((size_t)n * 64 * 4);
  uint_t* P2 = (uint_t*)alloc((size_t)n * 64 * 4);
  uint_t* P3 = (uint_t*)alloc((size_t)n * 64 * 4);
  uint_t* H1 = (uint_t*)alloc((size_t)n * 64 * 4);
  // width-32-padded bf16 buffers (16 dwords per node)
  uint_t* x32 = (uint_t*)alloc((size_t)n * 16 * 4);
  uint_t* q1  = (uint_t*)alloc((size_t)n * 16 * 4);
  uint_t* q2  = (uint_t*)alloc((size_t)n * 16 * 4);
  uint_t* q3  = (uint_t*)alloc((size_t)n * 16 * 4);
  uint_t* zb  = (uint_t*)alloc((size_t)n * 48 * 4);  // z1,z2,z3 each n x 32 bf16
  // swizzled weights
  ushort_t* Wz1 = (ushort_t*)alloc(4 * 4096 * 2);
  ushort_t* Wz2 = (ushort_t*)alloc(16 * 4096 * 2);
  ushort_t* Wz3 = (ushort_t*)alloc(4 * 4096 * 2);
  // graph CSR
  u64*   bkt  = (u64*)zb;  // alias: bkt (12.8MB) dead before zb (19.2MB) is used
  u32x2* meta = (u32x2*)alloc((size_t)E * 8);
  int*   start = (int*)alloc((size_t)(n + 1) * 4);
  float* dinv  = (float*)alloc((size_t)n * 4);
  int*   bcnt  = (int*)alloc(MAXBK * 4);
  int*   gcur  = (int*)alloc(MAXBK * 4);
  int*   bbase = (int*)alloc((MAXBK + 1) * 4);

  const int ab = (E + EPB - 1) / EPB;  // bucketing blocks (196)

  hipMemsetAsync(bcnt, 0, MAXBK * 4, stream);
  hipMemsetAsync(gcur, 0, MAXBK * 4, stream);

  bucket_count<<<ab, 256, 0, stream>>>(ei, bcnt, E, nbk);
  scan_buckets<<<1, 512, 0, stream>>>(bcnt, bbase, nbk, E);
  bucket_place<<<ab, 256, 0, stream>>>(ei, ew, bbase, gcur, bkt, E, nbk);
  bucket_stats<<<nbk, 256, 0, stream>>>(bkt, bbase, start, dinv, n, E);
  bucket_emit<<<nbk, 256, 0, stream>>>(bkt, bbase, start, dinv, meta, n);

  convert_x<<<(n * 16 + 255) / 256, 256, 0, stream>>>(x, x32, n);
  swizzleW_kcat<<<(4 * 4096 + 255) / 256, 256, 0, stream>>>(W1, Wz1, 1, NCLS, 4);
  swizzleW_kcat<<<(16 * 4096 + 255) / 256, 256, 0, stream>>>(W2, Wz2, 4, HID, 4);
  swizzleW_nslot<<<(4 * 4096 + 255) / 256, 256, 0, stream>>>(W3, Wz3);

  const int g128 = (n + 3) / 4;
  const int g26  = (n + 31) / 32;
  const int gg1  = (n + 63) / 64;    // MR=1 grid
  const int gg2  = (n + 127) / 128;  // MR=2 grid

  // ---- Layer 1: q_k = A^k x (width 32-padded), H0 = ELU([x|q1|q2|q3] @ W1cat + b1) ----
  spmm26_bf<<<g26, 256, 0, stream>>>(meta, start, x32, nullptr, q1, n);
  spmm26_bf<<<g26, 256, 0, stream>>>(meta, start, q1, nullptr, q2, n);
  spmm26_bf<<<g26, 256, 0, stream>>>(meta, start, q2, nullptr, q3, n);
  mfma_gemm<32, 4, 0, 1, 4><<<gg1, 256, 0, stream>>>(
      (const ushort_t*)x32, (const ushort_t*)q1, (const ushort_t*)q2, (const ushort_t*)q3,
      Wz1, b1, (ushort_t*)H0, nullptr, n);

  // ---- Layer 2: P_k = A^k H0, H1 = ELU([H0|P1|P2|P3] @ W2cat + b2) ----
  spmm128_bf<<<g128, 256, 0, stream>>>(meta, start, H0, P1, n);
  spmm128_bf<<<g128, 256, 0, stream>>>(meta, start, P1, P2, n);
  spmm128_bf<<<g128, 256, 0, stream>>>(meta, start, P2, P3, n);
  mfma_gemm<128, 4, 0, 2, 2><<<gg2, 256, 0, stream>>>(
      (const ushort_t*)H0, (const ushort_t*)P1, (const ushort_t*)P2, (const ushort_t*)P3,
      Wz2, b2, (ushort_t*)H1, nullptr, n);

  // ---- Layer 3: Z = H1 @ [W3_0|W3_1|W3_2|W3_3]; Horner out = z0+b3 + A(z1 + A(z2 + A z3)) ----
  // NOTE: zb aliases bkt, which is dead after bucket_emit — safe.
  mfma_gemm<128, 1, 1, 1, 4><<<gg1, 256, 0, stream>>>(
      (const ushort_t*)H1, (const ushort_t*)H1, (const ushort_t*)H1, (const ushort_t*)H1,
      Wz3, b3, (ushort_t*)zb, out, n);

  uint_t* z1 = zb;
  uint_t* z2 = zb + (size_t)n * 16;
  uint_t* z3 = zb + (size_t)n * 32;
  spmm26_bf<<<g26, 256, 0, stream>>>(meta, start, z3, z2, q1, n);  // q1 = z2 + A z3
  spmm26_bf<<<g26, 256, 0, stream>>>(meta, start, q1, z1, q2, n);  // q2 = z1 + A q1
  spmm26_addf<<<g26, 256, 0, stream>>>(meta, start, q2, out, n);   // out += A q2
}

// Round 9
// 462.895 us; speedup vs baseline: 8.1057x; 1.1742x over previous
//
#include <hip/hip_runtime.h>

#define NCLS 26
#define HID 128
#define EPB 8192   // edges per bucketing block
#define MAXBK 512  // max buckets (supports n <= 131072)
#define BCAP 6016  // fixed bucket capacity (mean 4092 + ~30 sigma for uniform input)
typedef unsigned short ushort_t;
typedef unsigned int uint_t;
typedef unsigned long long u64;

typedef __bf16 bf16x8 __attribute__((ext_vector_type(8)));
typedef float f32x4 __attribute__((ext_vector_type(4)));
typedef unsigned int u32x4 __attribute__((ext_vector_type(4)));
typedef unsigned int u32x2 __attribute__((ext_vector_type(2)));

// ---------------- bf16 helpers (ushort storage) ----------------
static __device__ __forceinline__ float b2f(ushort_t h) {
  return __uint_as_float(((uint_t)h) << 16);
}
static __device__ __forceinline__ ushort_t f2b(float f) {
  uint_t u = __float_as_uint(f);
  uint_t r = (u + 0x7fffu + ((u >> 16) & 1u)) >> 16;
  return (ushort_t)r;
}
static __device__ __forceinline__ uint_t pack2(float f0, float f1) {
  return (uint_t)f2b(f0) | ((uint_t)f2b(f1) << 16);
}
static __device__ __forceinline__ float lo16(uint_t v) { return b2f((ushort_t)(v & 0xffffu)); }
static __device__ __forceinline__ float hi16(uint_t v) { return b2f((ushort_t)(v >> 16)); }
static __device__ __forceinline__ bf16x8 ld_frag(const ushort_t* p) {
  u32x4 v = *reinterpret_cast<const u32x4*>(p);
  return __builtin_bit_cast(bf16x8, v);
}

// ---------------- preprocessing: two-level bucket sort ----------------
// bucket(c) = c >> 8 (256 nodes per bucket). Packed bucket record (u64):
// hi32 = r | (c_local << 24), lo32 = fp32 weight bits.
// Buckets live at fixed offsets b*BCAP in bkt; gcur[b] = fill count.

__global__ __launch_bounds__(256) void bucket_place(
    const int* __restrict__ ei, const float* __restrict__ ew,
    int* __restrict__ gcur, u64* __restrict__ bkt, int E, int nbk) {
  __shared__ uint_t lc[MAXBK];
  __shared__ uint_t lb[MAXBK];
  int tid = threadIdx.x;
  for (int t = tid; t < nbk; t += 256) lc[t] = 0;
  __syncthreads();
  int e0 = blockIdx.x * EPB;
#pragma unroll
  for (int i = 0; i < EPB / 256; ++i) {
    int e = e0 + tid + i * 256;
    if (e < E) atomicAdd(&lc[(uint_t)ei[E + e] >> 8], 1u);
  }
  __syncthreads();
  for (int t = tid; t < nbk; t += 256) {
    uint_t c = lc[t];
    lb[t] = c ? (uint_t)t * BCAP + (uint_t)atomicAdd(&gcur[t], (int)c) : 0u;
    lc[t] = 0;
  }
  __syncthreads();
#pragma unroll
  for (int i = 0; i < EPB / 256; ++i) {
    int e = e0 + tid + i * 256;
    if (e < E) {
      uint_t r = (uint_t)ei[e];
      uint_t c = (uint_t)ei[E + e];
      uint_t b = c >> 8;
      uint_t pos = lb[b] + atomicAdd(&lc[b], 1u);
      bkt[pos] = ((u64)(r | ((c & 255u) << 24)) << 32) | (u64)__float_as_uint(ew[e]);
    }
  }
}

// exclusive scan of bucket fills -> meta CSR bucket offsets
__global__ void scan_buckets(const int* __restrict__ gcur, int* __restrict__ mbase,
                             int nbk, int E) {
  __shared__ int s[512];
  int t = threadIdx.x;
  int v = (t < nbk) ? gcur[t] : 0;
  s[t] = v;
  __syncthreads();
  for (int off = 1; off < 512; off <<= 1) {
    int u = (t >= off) ? s[t - off] : 0;
    __syncthreads();
    s[t] += u;
    __syncthreads();
  }
  if (t < nbk) mbase[t] = s[t] - v;
  if (t == 0) mbase[nbk] = E;
}

// per-bucket: LDS count + weighted degree, scan -> start[], dinv[]
__global__ __launch_bounds__(256) void bucket_stats(
    const u64* __restrict__ bkt, const int* __restrict__ gcur, const int* __restrict__ mbase,
    int* __restrict__ start, float* __restrict__ dinv, int n, int E) {
  int b = blockIdx.x;
  __shared__ uint_t cnt[256];
  __shared__ float deg[256];
  __shared__ int ssc[256];
  int tid = threadIdx.x;
  cnt[tid] = 0;
  deg[tid] = 0.f;
  __syncthreads();
  int fill = gcur[b];
  const u64* w = bkt + (size_t)b * BCAP;
  for (int p = tid; p < fill; p += 256) {
    u64 v = w[p];
    uint_t cl = (uint_t)(v >> 56);
    float wv = __uint_as_float((uint_t)(v & 0xffffffffULL));
    atomicAdd(&cnt[cl], 1u);
    atomicAdd(&deg[cl], wv);
  }
  __syncthreads();
  int v0 = (int)cnt[tid];
  ssc[tid] = v0;
  __syncthreads();
  for (int off = 1; off < 256; off <<= 1) {
    int u = (tid >= off) ? ssc[tid - off] : 0;
    __syncthreads();
    ssc[tid] += u;
    __syncthreads();
  }
  int node = (b << 8) + tid;
  if (node < n) {
    start[node] = mbase[b] + ssc[tid] - v0;
    float d = deg[tid];
    dinv[node] = d > 0.f ? rsqrtf(fmaxf(d, 1e-12f)) : 0.f;
  }
  if (b == 0 && tid == 0) start[n] = E;
}

// per-bucket: emit meta {r, nrm}; scattered writes stay in the bucket's CSR window
__global__ __launch_bounds__(256) void bucket_emit(
    const u64* __restrict__ bkt, const int* __restrict__ gcur, const int* __restrict__ start,
    const float* __restrict__ dinv, u32x2* __restrict__ meta, int n) {
  int b = blockIdx.x;
  __shared__ uint_t lcur[256];
  int tid = threadIdx.x;
  lcur[tid] = 0;
  __syncthreads();
  int fill = gcur[b];
  const u64* w = bkt + (size_t)b * BCAP;
  for (int p = tid; p < fill; p += 256) {
    u64 v = w[p];
    uint_t hi = (uint_t)(v >> 32);
    uint_t r = hi & 0xffffffu;
    uint_t cl = hi >> 24;
    float wv = __uint_as_float((uint_t)(v & 0xffffffffULL));
    uint_t node = ((uint_t)b << 8) + cl;
    float nrm = dinv[r] * wv * dinv[node];
    uint_t slot = (uint_t)start[node] + atomicAdd(&lcur[cl], 1u);
    u32x2 m;
    m.x = r;
    m.y = __float_as_uint(nrm);
    meta[slot] = m;
  }
}

// ---------------- fused small prep: convert_x + 3 W swizzles ----------------
// W swizzle out layout: [t (global kstep)][j 0..7][lane 0..63][i 0..7] bf16
// fragment element = B[k][col], k = 32*t_in_src + 8*(lane>>4) + i, col = 16*j + (lane&15)
__global__ __launch_bounds__(256) void prep_misc(
    const float* __restrict__ x, uint_t* __restrict__ x32,
    const float* __restrict__ W1, ushort_t* __restrict__ Wz1,
    const float* __restrict__ W2, ushort_t* __restrict__ Wz2,
    const float* __restrict__ W3, ushort_t* __restrict__ Wz3, int n, int gconv) {
  int blk = blockIdx.x;
  int tid = threadIdx.x;
  if (blk < gconv) {
    // x (n x 26 fp32) -> padded bf16 (n x 32)
    int idx = blk * 256 + tid;
    if (idx >= n * 16) return;
    int node = idx >> 4, lane = idx & 15;
    float f0 = 0.f, f1 = 0.f;
    if (lane < 13) {
      f0 = x[node * 26 + 2 * lane];
      f1 = x[node * 26 + 2 * lane + 1];
    }
    x32[idx] = pack2(f0, f1);
  } else if (blk < gconv + 64) {
    // W1 kcat: ksps=1, kwv=26, nsrc=4
    int idx = (blk - gconv) * 256 + tid;
    int i = idx & 7, l = (idx >> 3) & 63, j = (idx >> 9) & 7, t = idx >> 12;
    int k = 8 * (l >> 4) + i;
    int col = 16 * j + (l & 15);
    float v = (k < NCLS) ? W1[((size_t)t * NCLS + k) * 128 + col] : 0.f;
    Wz1[idx] = f2b(v);
  } else if (blk < gconv + 64 + 256) {
    // W2 kcat: ksps=4, kwv=128, nsrc=4
    int idx = (blk - gconv - 64) * 256 + tid;
    int i = idx & 7, l = (idx >> 3) & 63, j = (idx >> 9) & 7, t = idx >> 12;
    int s = t >> 2, tt = t & 3;
    int k = tt * 32 + 8 * (l >> 4) + i;
    int col = 16 * j + (l & 15);
    float v = W2[((size_t)s * HID + k) * 128 + col];
    Wz2[idx] = f2b(v);
  } else {
    // W3 nslot
    int idx = (blk - gconv - 64 - 256) * 256 + tid;
    int i = idx & 7, l = (idx >> 3) & 63, j = (idx >> 9) & 7, t = idx >> 12;
    int k = t * 32 + 8 * (l >> 4) + i;
    int col = 16 * j + (l & 15);
    int s = col >> 5, c = col & 31;
    float v = (c < 26) ? W3[((size_t)s * 128 + k) * 26 + c] : 0.f;
    Wz3[idx] = f2b(v);
  }
}

// ---------------- SpMM (pull, CSR by destination, bf16, interleaved meta) ----------------

// width 128: wave per node; 16 lanes per edge-slot (eq), dwordx4 gathers.
// Clamped-index meta (weight zeroed when past end), 32-bit addressing,
// software-pipelined meta prefetch (next pair loads during current FMAs).
__global__ __launch_bounds__(256) void spmm128_bf(
    const u32x2* __restrict__ meta, const int* __restrict__ start,
    const uint_t* __restrict__ in, uint_t* __restrict__ out, int n) {
  int node = blockIdx.x * 4 + (threadIdx.x >> 6);
  int lane = threadIdx.x & 63;
  if (node >= n) return;
  int s = start[node], m = start[node + 1] - s;
  int eq = lane >> 4;
  uint_t foff = (uint_t)(lane & 15) << 4;  // byte offset within 256B row
  const char* inb = (const char*)in;
  float a0 = 0.f, a1 = 0.f, a2 = 0.f, a3 = 0.f, a4 = 0.f, a5 = 0.f, a6 = 0.f, a7 = 0.f;
  if (m > 0) {
    int i0 = eq, i1 = 4 + eq;
    u32x2 mt0 = meta[s + (i0 < m ? i0 : m - 1)];
    u32x2 mt1 = meta[s + (i1 < m ? i1 : m - 1)];
    for (int base = 0; base < m; base += 8) {
      int p0 = base + 8 + eq, p1 = base + 12 + eq;
      u32x2 nx0 = meta[s + (p0 < m ? p0 : m - 1)];
      u32x2 nx1 = meta[s + (p1 < m ? p1 : m - 1)];
      float w0 = (base + eq < m) ? __uint_as_float(mt0.y) : 0.f;
      float w1 = (base + 4 + eq < m) ? __uint_as_float(mt1.y) : 0.f;
      u32x4 v0 = *reinterpret_cast<const u32x4*>(inb + (((uint_t)mt0.x << 8) + foff));
      u32x4 v1 = *reinterpret_cast<const u32x4*>(inb + (((uint_t)mt1.x << 8) + foff));
      a0 += w0 * lo16(v0.x); a1 += w0 * hi16(v0.x);
      a2 += w0 * lo16(v0.y); a3 += w0 * hi16(v0.y);
      a4 += w0 * lo16(v0.z); a5 += w0 * hi16(v0.z);
      a6 += w0 * lo16(v0.w); a7 += w0 * hi16(v0.w);
      a0 += w1 * lo16(v1.x); a1 += w1 * hi16(v1.x);
      a2 += w1 * lo16(v1.y); a3 += w1 * hi16(v1.y);
      a4 += w1 * lo16(v1.z); a5 += w1 * hi16(v1.z);
      a6 += w1 * lo16(v1.w); a7 += w1 * hi16(v1.w);
      mt0 = nx0;
      mt1 = nx1;
    }
  }
  a0 += __shfl_xor(a0, 16); a1 += __shfl_xor(a1, 16);
  a2 += __shfl_xor(a2, 16); a3 += __shfl_xor(a3, 16);
  a4 += __shfl_xor(a4, 16); a5 += __shfl_xor(a5, 16);
  a6 += __shfl_xor(a6, 16); a7 += __shfl_xor(a7, 16);
  a0 += __shfl_xor(a0, 32); a1 += __shfl_xor(a1, 32);
  a2 += __shfl_xor(a2, 32); a3 += __shfl_xor(a3, 32);
  a4 += __shfl_xor(a4, 32); a5 += __shfl_xor(a5, 32);
  a6 += __shfl_xor(a6, 32); a7 += __shfl_xor(a7, 32);
  if (eq == 0) {
    u32x4 o;
    o.x = pack2(a0, a1);
    o.y = pack2(a2, a3);
    o.z = pack2(a4, a5);
    o.w = pack2(a6, a7);
    *reinterpret_cast<u32x4*>(out + (size_t)node * 64 + (foff >> 2)) = o;
  }
}

// width 32-padded: 8 lanes per node (dwordx2 each); cooperative meta load
// (8 lanes load 8 different metas, shfl-broadcast) -> 8 gathers in flight.
__global__ __launch_bounds__(256) void spmm26_bf(
    const u32x2* __restrict__ meta, const int* __restrict__ start,
    const uint_t* __restrict__ in, const uint_t* __restrict__ add,
    uint_t* __restrict__ out, int n) {
  int node = blockIdx.x * 32 + (threadIdx.x >> 3);
  int ln = threadIdx.x & 7;
  if (node >= n) return;
  int s = start[node], m = start[node + 1] - s;
  uint_t foff = (uint_t)ln << 3;  // byte offset within 64B row
  const char* inb = (const char*)in;
  float a0 = 0.f, a1 = 0.f, a2 = 0.f, a3 = 0.f;
  if (m > 0) {
    for (int base = 0; base < m; base += 8) {
      int j = base + ln;
      u32x2 mt = meta[s + (j < m ? j : m - 1)];
      int rr = (int)mt.x;
      float ww = (j < m) ? __uint_as_float(mt.y) : 0.f;
#pragma unroll
      for (int k = 0; k < 8; ++k) {
        uint_t r = (uint_t)__shfl(rr, k, 8);
        float wv = __shfl(ww, k, 8);
        u32x2 v = *reinterpret_cast<const u32x2*>(inb + ((r << 6) + foff));
        a0 += wv * lo16(v.x); a1 += wv * hi16(v.x);
        a2 += wv * lo16(v.y); a3 += wv * hi16(v.y);
      }
    }
  }
  if (add) {
    u32x2 v = *reinterpret_cast<const u32x2*>(add + (size_t)node * 16 + 2 * ln);
    a0 += lo16(v.x); a1 += hi16(v.x);
    a2 += lo16(v.y); a3 += hi16(v.y);
  }
  u32x2 o;
  o.x = pack2(a0, a1);
  o.y = pack2(a2, a3);
  *reinterpret_cast<u32x2*>(out + (size_t)node * 16 + 2 * ln) = o;
}

// final Horner step: out_f32 (n x 26) += A*in
__global__ __launch_bounds__(256) void spmm26_addf(
    const u32x2* __restrict__ meta, const int* __restrict__ start,
    const uint_t* __restrict__ in, float* __restrict__ out, int n) {
  int node = blockIdx.x * 32 + (threadIdx.x >> 3);
  int ln = threadIdx.x & 7;
  if (node >= n) return;
  int s = start[node], m = start[node + 1] - s;
  uint_t foff = (uint_t)ln << 3;
  const char* inb = (const char*)in;
  float a0 = 0.f, a1 = 0.f, a2 = 0.f, a3 = 0.f;
  if (m > 0) {
    for (int base = 0; base < m; base += 8) {
      int j = base + ln;
      u32x2 mt = meta[s + (j < m ? j : m - 1)];
      int rr = (int)mt.x;
      float ww = (j < m) ? __uint_as_float(mt.y) : 0.f;
#pragma unroll
      for (int k = 0; k < 8; ++k) {
        uint_t r = (uint_t)__shfl(rr, k, 8);
        float wv = __shfl(ww, k, 8);
        u32x2 v = *reinterpret_cast<const u32x2*>(inb + ((r << 6) + foff));
        a0 += wv * lo16(v.x); a1 += wv * hi16(v.x);
        a2 += wv * lo16(v.y); a3 += wv * hi16(v.y);
      }
    }
  }
  int c0 = 4 * ln;
  if (c0 + 0 < 26) out[(size_t)node * 26 + c0 + 0] += a0;
  if (c0 + 1 < 26) out[(size_t)node * 26 + c0 + 1] += a1;
  if (c0 + 2 < 26) out[(size_t)node * 26 + c0 + 2] += a2;
  if (c0 + 3 < 26) out[(size_t)node * 26 + c0 + 3] += a3;
}

// ---------------- fused MFMA GEMM, LDS-staged W ----------------
// C(n x 128) = [A0|A1|A2|A3] (each n x KW bf16) @ Wswz (+bias)
// W staged cooperatively into LDS in GROUP-kstep chunks; all 4 waves share it.
// EPI 0: ELU, write bf16 n x 128 to outb
// EPI 1: layer-3 slots: slot0 -> outf (n x 26 fp32, +bias); slots 1..3 -> outb (3 x n x 32 bf16)
template <int KW, int NSRC, int EPI, int MR, int GROUP>
__global__ __launch_bounds__(256) void mfma_gemm(
    const ushort_t* __restrict__ A0, const ushort_t* __restrict__ A1,
    const ushort_t* __restrict__ A2, const ushort_t* __restrict__ A3,
    const ushort_t* __restrict__ Wswz, const float* __restrict__ bias,
    ushort_t* __restrict__ outb, float* __restrict__ outf, int n) {
  constexpr int KSPS = KW / 32;
  constexpr int KSTEPS = NSRC * KSPS;
  constexpr int NGROUPS = KSTEPS / GROUP;
  __shared__ ushort_t sW[GROUP * 4096];
  const int tid = threadIdx.x;
  const int w = tid >> 6;
  const int l = tid & 63;
  const int row0 = blockIdx.x * (64 * MR) + w * (16 * MR);
  const int koff = 8 * (l >> 4);  // elements

  f32x4 acc[MR][8];
#pragma unroll
  for (int f = 0; f < MR; ++f)
#pragma unroll
    for (int j = 0; j < 8; ++j) acc[f][j] = (f32x4){0.f, 0.f, 0.f, 0.f};

  const ushort_t* const srcs[4] = {A0, A1, A2, A3};

  // staged W registers: GROUP ksteps x 32 B per thread
  u32x4 gw[2 * GROUP];
#pragma unroll
  for (int c = 0; c < GROUP; ++c) {
    const ushort_t* p = Wswz + (size_t)c * 4096 + tid * 8;
    gw[2 * c] = *reinterpret_cast<const u32x4*>(p);
    gw[2 * c + 1] = *reinterpret_cast<const u32x4*>(p + 2048);
  }

#pragma unroll
  for (int g = 0; g < NGROUPS; ++g) {
    __syncthreads();  // sW writable (all waves done reading previous group)
#pragma unroll
    for (int c = 0; c < GROUP; ++c) {
      *reinterpret_cast<u32x4*>(sW + c * 4096 + tid * 8) = gw[2 * c];
      *reinterpret_cast<u32x4*>(sW + c * 4096 + tid * 8 + 2048) = gw[2 * c + 1];
    }
    if (g + 1 < NGROUPS) {
#pragma unroll
      for (int c = 0; c < GROUP; ++c) {
        const ushort_t* p = Wswz + (size_t)(g + 1) * GROUP * 4096 + (size_t)c * 4096 + tid * 8;
        gw[2 * c] = *reinterpret_cast<const u32x4*>(p);
        gw[2 * c + 1] = *reinterpret_cast<const u32x4*>(p + 2048);
      }
    }
    __syncthreads();  // sW ready
#pragma unroll
    for (int tg = 0; tg < GROUP; ++tg) {
      const int t = g * GROUP + tg;
      const int s = t / KSPS;
      const int tt = t - s * KSPS;
      bf16x8 af[MR];
#pragma unroll
      for (int f = 0; f < MR; ++f) {
        int arow = row0 + f * 16 + (l & 15);
        int arow_c = arow < n ? arow : (n - 1);
        af[f] = ld_frag(srcs[s] + (size_t)arow_c * KW + tt * 32 + koff);
      }
      const ushort_t* wp = sW + tg * 4096 + l * 8;
#pragma unroll
      for (int j = 0; j < 8; ++j) {
        bf16x8 bfr = ld_frag(wp + j * 64 * 8);
#pragma unroll
        for (int f = 0; f < MR; ++f)
          acc[f][j] = __builtin_amdgcn_mfma_f32_16x16x32_bf16(af[f], bfr, acc[f][j], 0, 0, 0);
      }
    }
  }

  const int ccol = l & 15;
#pragma unroll
  for (int f = 0; f < MR; ++f) {
    const int crow0 = row0 + f * 16 + 4 * (l >> 4);
#pragma unroll
    for (int j = 0; j < 8; ++j) {
      if (EPI == 0) {
        int col = 16 * j + ccol;
        float bi = bias[col];
#pragma unroll
        for (int r = 0; r < 4; ++r) {
          int row = crow0 + r;
          if (row >= n) continue;
          float v = acc[f][j][r] + bi;
          v = v > 0.f ? v : (__expf(v) - 1.f);
          outb[(size_t)row * 128 + col] = f2b(v);
        }
      } else {
        int slot = j >> 1;
        int c = 16 * (j & 1) + ccol;
#pragma unroll
        for (int r = 0; r < 4; ++r) {
          int row = crow0 + r;
          if (row >= n) continue;
          float v = acc[f][j][r];
          if (slot == 0) {
            if (c < 26) outf[(size_t)row * 26 + c] = v + bias[c];
          } else {
            outb[((size_t)(slot - 1) * n + row) * 32 + c] = f2b(v);
          }
        }
      }
    }
  }
}

// ---------------- launcher ----------------

extern "C" void kernel_launch(void* const* d_in, const int* in_sizes, int n_in,
                              void* d_out, int out_size, void* d_ws, size_t ws_size,
                              hipStream_t stream) {
  const float* x  = (const float*)d_in[0];
  const int*   ei = (const int*)d_in[1];
  const float* ew = (const float*)d_in[2];
  const float* W1 = (const float*)d_in[3];
  const float* b1 = (const float*)d_in[4];
  const float* W2 = (const float*)d_in[5];
  const float* b2 = (const float*)d_in[6];
  const float* W3 = (const float*)d_in[7];
  const float* b3 = (const float*)d_in[8];
  float* out = (float*)d_out;

  const int n = in_sizes[0] / NCLS;  // 100000
  const int E = in_sizes[2];         // 1600000
  const int nbk = (n + 255) >> 8;    // 391 buckets

  char* w = (char*)d_ws;
  auto alloc = [&](size_t bytes) {
    char* p = w;
    w += (bytes + 255) / 256 * 256;
    return p;
  };
  // width-128 bf16 feature buffers (64 dwords per node)
  uint_t* H0 = (uint_t*)alloc((size_t)n * 64 * 4);
  uint_t* P1 = (uint_t*)alloc((size_t)n * 64 * 4);
  uint_t* P2 = (uint_t*)alloc((size_t)n * 64 * 4);
  uint_t* P3 = (uint_t*)alloc((size_t)n * 64 * 4);
  uint_t* H1 = (uint_t*)alloc((size_t)n * 64 * 4);
  // width-32-padded bf16 buffers (16 dwords per node)
  uint_t* x32 = (uint_t*)alloc((size_t)n * 16 * 4);
  uint_t* q1  = (uint_t*)alloc((size_t)n * 16 * 4);
  uint_t* q2  = (uint_t*)alloc((size_t)n * 16 * 4);
  uint_t* q3  = (uint_t*)alloc((size_t)n * 16 * 4);
  uint_t* zb  = (uint_t*)alloc((size_t)n * 48 * 4);  // z1,z2,z3 each n x 32 bf16
  // swizzled weights
  ushort_t* Wz1 = (ushort_t*)alloc(4 * 4096 * 2);
  ushort_t* Wz2 = (ushort_t*)alloc(16 * 4096 * 2);
  ushort_t* Wz3 = (ushort_t*)alloc(4 * 4096 * 2);
  // graph CSR
  u64*   bkt  = (u64*)zb;  // alias: bkt (18.8MB @ BCAP=6016) dead before zb (19.2MB) is used
  u32x2* meta = (u32x2*)alloc((size_t)E * 8);
  int*   start = (int*)alloc((size_t)(n + 1) * 4);
  float* dinv  = (float*)alloc((size_t)n * 4);
  int*   gcur  = (int*)alloc(MAXBK * 4);
  int*   mbase = (int*)alloc((MAXBK + 1) * 4);

  const int ab = (E + EPB - 1) / EPB;  // bucketing blocks (196)
  const int gconv = (n * 16 + 255) / 256;

  // independent small prep (x conversion + W swizzles) in one launch
  prep_misc<<<gconv + 64 + 256 + 64, 256, 0, stream>>>(x, x32, W1, Wz1, W2, Wz2, W3, Wz3,
                                                       n, gconv);

  hipMemsetAsync(gcur, 0, MAXBK * 4, stream);
  bucket_place<<<ab, 256, 0, stream>>>(ei, ew, gcur, bkt, E, nbk);
  scan_buckets<<<1, 512, 0, stream>>>(gcur, mbase, nbk, E);
  bucket_stats<<<nbk, 256, 0, stream>>>(bkt, gcur, mbase, start, dinv, n, E);
  bucket_emit<<<nbk, 256, 0, stream>>>(bkt, gcur, start, dinv, meta, n);

  const int g128 = (n + 3) / 4;
  const int g26  = (n + 31) / 32;
  const int gg1  = (n + 63) / 64;    // MR=1 grid
  const int gg2  = (n + 127) / 128;  // MR=2 grid

  // ---- Layer 1: q_k = A^k x (width 32-padded), H0 = ELU([x|q1|q2|q3] @ W1cat + b1) ----
  spmm26_bf<<<g26, 256, 0, stream>>>(meta, start, x32, nullptr, q1, n);
  spmm26_bf<<<g26, 256, 0, stream>>>(meta, start, q1, nullptr, q2, n);
  spmm26_bf<<<g26, 256, 0, stream>>>(meta, start, q2, nullptr, q3, n);
  mfma_gemm<32, 4, 0, 1, 4><<<gg1, 256, 0, stream>>>(
      (const ushort_t*)x32, (const ushort_t*)q1, (const ushort_t*)q2, (const ushort_t*)q3,
      Wz1, b1, (ushort_t*)H0, nullptr, n);

  // ---- Layer 2: P_k = A^k H0, H1 = ELU([H0|P1|P2|P3] @ W2cat + b2) ----
  spmm128_bf<<<g128, 256, 0, stream>>>(meta, start, H0, P1, n);
  spmm128_bf<<<g128, 256, 0, stream>>>(meta, start, P1, P2, n);
  spmm128_bf<<<g128, 256, 0, stream>>>(meta, start, P2, P3, n);
  mfma_gemm<128, 4, 0, 2, 2><<<gg2, 256, 0, stream>>>(
      (const ushort_t*)H0, (const ushort_t*)P1, (const ushort_t*)P2, (const ushort_t*)P3,
      Wz2, b2, (ushort_t*)H1, nullptr, n);

  // ---- Layer 3: Z = H1 @ [W3_0|W3_1|W3_2|W3_3]; Horner out = z0+b3 + A(z1 + A(z2 + A z3)) ----
  // NOTE: zb aliases bkt, which is dead after bucket_emit — safe.
  mfma_gemm<128, 1, 1, 1, 4><<<gg1, 256, 0, stream>>>(
      (const ushort_t*)H1, (const ushort_t*)H1, (const ushort_t*)H1, (const ushort_t*)H1,
      Wz3, b3, (ushort_t*)zb, out, n);

  uint_t* z1 = zb;
  uint_t* z2 = zb + (size_t)n * 16;
  uint_t* z3 = zb + (size_t)n * 32;
  spmm26_bf<<<g26, 256, 0, stream>>>(meta, start, z3, z2, q1, n);  // q1 = z2 + A z3
  spmm26_bf<<<g26, 256, 0, stream>>>(meta, start, q1, z1, q2, n);  // q2 = z1 + A q1
  spmm26_addf<<<g26, 256, 0, stream>>>(meta, start, q2, out, n);   // out += A q2
}

// Round 10
// 458.091 us; speedup vs baseline: 8.1907x; 1.0105x over previous
//
#include <hip/hip_runtime.h>

#define NCLS 26
#define HID 128
#define EPB 8192   // edges per bucketing block
#define MAXBK 512  // max buckets (supports n <= 131072)
#define BCAP 6016  // fixed bucket capacity (mean 4092 + ~30 sigma for uniform input)
typedef unsigned short ushort_t;
typedef unsigned int uint_t;
typedef unsigned long long u64;

typedef __bf16 bf16x8 __attribute__((ext_vector_type(8)));
typedef float f32x4 __attribute__((ext_vector_type(4)));
typedef unsigned int u32x4 __attribute__((ext_vector_type(4)));
typedef unsigned int u32x2 __attribute__((ext_vector_type(2)));

// ---------------- bf16 helpers (ushort storage) ----------------
static __device__ __forceinline__ float b2f(ushort_t h) {
  return __uint_as_float(((uint_t)h) << 16);
}
static __device__ __forceinline__ ushort_t f2b(float f) {
  uint_t u = __float_as_uint(f);
  uint_t r = (u + 0x7fffu + ((u >> 16) & 1u)) >> 16;
  return (ushort_t)r;
}
static __device__ __forceinline__ uint_t pack2(float f0, float f1) {
  return (uint_t)f2b(f0) | ((uint_t)f2b(f1) << 16);
}
static __device__ __forceinline__ float lo16(uint_t v) { return b2f((ushort_t)(v & 0xffffu)); }
static __device__ __forceinline__ float hi16(uint_t v) { return b2f((ushort_t)(v >> 16)); }
static __device__ __forceinline__ bf16x8 ld_frag(const ushort_t* p) {
  u32x4 v = *reinterpret_cast<const u32x4*>(p);
  return __builtin_bit_cast(bf16x8, v);
}

// ---------------- preprocessing: two-level bucket sort ----------------
// bucket(c) = c >> 8 (256 nodes per bucket). Packed bucket record (u64):
// hi32 = r | (c_local << 24), lo32 = fp32 weight bits.
// Buckets live at fixed offsets b*BCAP in bkt; gcur[b] = fill count.

__global__ __launch_bounds__(256) void bucket_place(
    const int* __restrict__ ei, const float* __restrict__ ew,
    int* __restrict__ gcur, u64* __restrict__ bkt, int E, int nbk) {
  __shared__ uint_t lc[MAXBK];
  __shared__ uint_t lb[MAXBK];
  int tid = threadIdx.x;
  for (int t = tid; t < nbk; t += 256) lc[t] = 0;
  __syncthreads();
  int e0 = blockIdx.x * EPB;
#pragma unroll
  for (int i = 0; i < EPB / 256; ++i) {
    int e = e0 + tid + i * 256;
    if (e < E) atomicAdd(&lc[(uint_t)ei[E + e] >> 8], 1u);
  }
  __syncthreads();
  for (int t = tid; t < nbk; t += 256) {
    uint_t c = lc[t];
    lb[t] = c ? (uint_t)t * BCAP + (uint_t)atomicAdd(&gcur[t], (int)c) : 0u;
    lc[t] = 0;
  }
  __syncthreads();
#pragma unroll
  for (int i = 0; i < EPB / 256; ++i) {
    int e = e0 + tid + i * 256;
    if (e < E) {
      uint_t r = (uint_t)ei[e];
      uint_t c = (uint_t)ei[E + e];
      uint_t b = c >> 8;
      uint_t pos = lb[b] + atomicAdd(&lc[b], 1u);
      bkt[pos] = ((u64)(r | ((c & 255u) << 24)) << 32) | (u64)__float_as_uint(ew[e]);
    }
  }
}

// exclusive scan of bucket fills -> meta CSR bucket offsets
__global__ void scan_buckets(const int* __restrict__ gcur, int* __restrict__ mbase,
                             int nbk, int E) {
  __shared__ int s[512];
  int t = threadIdx.x;
  int v = (t < nbk) ? gcur[t] : 0;
  s[t] = v;
  __syncthreads();
  for (int off = 1; off < 512; off <<= 1) {
    int u = (t >= off) ? s[t - off] : 0;
    __syncthreads();
    s[t] += u;
    __syncthreads();
  }
  if (t < nbk) mbase[t] = s[t] - v;
  if (t == 0) mbase[nbk] = E;
}

// per-bucket: LDS count + weighted degree, scan -> start[], dinv[]
__global__ __launch_bounds__(256) void bucket_stats(
    const u64* __restrict__ bkt, const int* __restrict__ gcur, const int* __restrict__ mbase,
    int* __restrict__ start, float* __restrict__ dinv, int n, int E) {
  int b = blockIdx.x;
  __shared__ uint_t cnt[256];
  __shared__ float deg[256];
  __shared__ int ssc[256];
  int tid = threadIdx.x;
  cnt[tid] = 0;
  deg[tid] = 0.f;
  __syncthreads();
  int fill = gcur[b];
  const u64* w = bkt + (size_t)b * BCAP;
  for (int p = tid; p < fill; p += 256) {
    u64 v = w[p];
    uint_t cl = (uint_t)(v >> 56);
    float wv = __uint_as_float((uint_t)(v & 0xffffffffULL));
    atomicAdd(&cnt[cl], 1u);
    atomicAdd(&deg[cl], wv);
  }
  __syncthreads();
  int v0 = (int)cnt[tid];
  ssc[tid] = v0;
  __syncthreads();
  for (int off = 1; off < 256; off <<= 1) {
    int u = (tid >= off) ? ssc[tid - off] : 0;
    __syncthreads();
    ssc[tid] += u;
    __syncthreads();
  }
  int node = (b << 8) + tid;
  if (node < n) {
    start[node] = mbase[b] + ssc[tid] - v0;
    float d = deg[tid];
    dinv[node] = d > 0.f ? rsqrtf(fmaxf(d, 1e-12f)) : 0.f;
  }
  if (b == 0 && tid == 0) start[n] = E;
}

// per-bucket: emit meta {r, nrm}; scattered writes stay in the bucket's CSR window
__global__ __launch_bounds__(256) void bucket_emit(
    const u64* __restrict__ bkt, const int* __restrict__ gcur, const int* __restrict__ start,
    const float* __restrict__ dinv, u32x2* __restrict__ meta, int n) {
  int b = blockIdx.x;
  __shared__ uint_t lcur[256];
  int tid = threadIdx.x;
  lcur[tid] = 0;
  __syncthreads();
  int fill = gcur[b];
  const u64* w = bkt + (size_t)b * BCAP;
  for (int p = tid; p < fill; p += 256) {
    u64 v = w[p];
    uint_t hi = (uint_t)(v >> 32);
    uint_t r = hi & 0xffffffu;
    uint_t cl = hi >> 24;
    float wv = __uint_as_float((uint_t)(v & 0xffffffffULL));
    uint_t node = ((uint_t)b << 8) + cl;
    float nrm = dinv[r] * wv * dinv[node];
    uint_t slot = (uint_t)start[node] + atomicAdd(&lcur[cl], 1u);
    u32x2 m;
    m.x = r;
    m.y = __float_as_uint(nrm);
    meta[slot] = m;
  }
}

// ---------------- fused small prep: convert_x + 3 W swizzles ----------------
// W swizzle out layout: [t (global kstep)][j 0..7][lane 0..63][i 0..7] bf16
// fragment element = B[k][col], k = 32*t_in_src + 8*(lane>>4) + i, col = 16*j + (lane&15)
__global__ __launch_bounds__(256) void prep_misc(
    const float* __restrict__ x, uint_t* __restrict__ x32,
    const float* __restrict__ W1, ushort_t* __restrict__ Wz1,
    const float* __restrict__ W2, ushort_t* __restrict__ Wz2,
    const float* __restrict__ W3, ushort_t* __restrict__ Wz3, int n, int gconv) {
  int blk = blockIdx.x;
  int tid = threadIdx.x;
  if (blk < gconv) {
    // x (n x 26 fp32) -> padded bf16 (n x 32)
    int idx = blk * 256 + tid;
    if (idx >= n * 16) return;
    int node = idx >> 4, lane = idx & 15;
    float f0 = 0.f, f1 = 0.f;
    if (lane < 13) {
      f0 = x[node * 26 + 2 * lane];
      f1 = x[node * 26 + 2 * lane + 1];
    }
    x32[idx] = pack2(f0, f1);
  } else if (blk < gconv + 64) {
    // W1 kcat: ksps=1, kwv=26, nsrc=4
    int idx = (blk - gconv) * 256 + tid;
    int i = idx & 7, l = (idx >> 3) & 63, j = (idx >> 9) & 7, t = idx >> 12;
    int k = 8 * (l >> 4) + i;
    int col = 16 * j + (l & 15);
    float v = (k < NCLS) ? W1[((size_t)t * NCLS + k) * 128 + col] : 0.f;
    Wz1[idx] = f2b(v);
  } else if (blk < gconv + 64 + 256) {
    // W2 kcat: ksps=4, kwv=128, nsrc=4
    int idx = (blk - gconv - 64) * 256 + tid;
    int i = idx & 7, l = (idx >> 3) & 63, j = (idx >> 9) & 7, t = idx >> 12;
    int s = t >> 2, tt = t & 3;
    int k = tt * 32 + 8 * (l >> 4) + i;
    int col = 16 * j + (l & 15);
    float v = W2[((size_t)s * HID + k) * 128 + col];
    Wz2[idx] = f2b(v);
  } else {
    // W3 nslot
    int idx = (blk - gconv - 64 - 256) * 256 + tid;
    int i = idx & 7, l = (idx >> 3) & 63, j = (idx >> 9) & 7, t = idx >> 12;
    int k = t * 32 + 8 * (l >> 4) + i;
    int col = 16 * j + (l & 15);
    int s = col >> 5, c = col & 31;
    float v = (c < 26) ? W3[((size_t)s * 128 + k) * 26 + c] : 0.f;
    Wz3[idx] = f2b(v);
  }
}

// ---------------- SpMM (pull, CSR by destination, bf16, interleaved meta) ----------------

// width 128: wave per node; 16 lanes per edge-slot (eq), dwordx4 gathers.
// Clamped-index meta (weight zeroed when past end), 32-bit addressing,
// software-pipelined meta prefetch (next pair loads during current FMAs).
__global__ __launch_bounds__(256) void spmm128_bf(
    const u32x2* __restrict__ meta, const int* __restrict__ start,
    const uint_t* __restrict__ in, uint_t* __restrict__ out, int n) {
  int node = blockIdx.x * 4 + (threadIdx.x >> 6);
  int lane = threadIdx.x & 63;
  if (node >= n) return;
  int s = start[node], m = start[node + 1] - s;
  int eq = lane >> 4;
  uint_t foff = (uint_t)(lane & 15) << 4;  // byte offset within 256B row
  const char* inb = (const char*)in;
  float a0 = 0.f, a1 = 0.f, a2 = 0.f, a3 = 0.f, a4 = 0.f, a5 = 0.f, a6 = 0.f, a7 = 0.f;
  if (m > 0) {
    int i0 = eq, i1 = 4 + eq;
    u32x2 mt0 = meta[s + (i0 < m ? i0 : m - 1)];
    u32x2 mt1 = meta[s + (i1 < m ? i1 : m - 1)];
    for (int base = 0; base < m; base += 8) {
      int p0 = base + 8 + eq, p1 = base + 12 + eq;
      u32x2 nx0 = meta[s + (p0 < m ? p0 : m - 1)];
      u32x2 nx1 = meta[s + (p1 < m ? p1 : m - 1)];
      float w0 = (base + eq < m) ? __uint_as_float(mt0.y) : 0.f;
      float w1 = (base + 4 + eq < m) ? __uint_as_float(mt1.y) : 0.f;
      u32x4 v0 = *reinterpret_cast<const u32x4*>(inb + (((uint_t)mt0.x << 8) + foff));
      u32x4 v1 = *reinterpret_cast<const u32x4*>(inb + (((uint_t)mt1.x << 8) + foff));
      a0 += w0 * lo16(v0.x); a1 += w0 * hi16(v0.x);
      a2 += w0 * lo16(v0.y); a3 += w0 * hi16(v0.y);
      a4 += w0 * lo16(v0.z); a5 += w0 * hi16(v0.z);
      a6 += w0 * lo16(v0.w); a7 += w0 * hi16(v0.w);
      a0 += w1 * lo16(v1.x); a1 += w1 * hi16(v1.x);
      a2 += w1 * lo16(v1.y); a3 += w1 * hi16(v1.y);
      a4 += w1 * lo16(v1.z); a5 += w1 * hi16(v1.z);
      a6 += w1 * lo16(v1.w); a7 += w1 * hi16(v1.w);
      mt0 = nx0;
      mt1 = nx1;
    }
  }
  a0 += __shfl_xor(a0, 16); a1 += __shfl_xor(a1, 16);
  a2 += __shfl_xor(a2, 16); a3 += __shfl_xor(a3, 16);
  a4 += __shfl_xor(a4, 16); a5 += __shfl_xor(a5, 16);
  a6 += __shfl_xor(a6, 16); a7 += __shfl_xor(a7, 16);
  a0 += __shfl_xor(a0, 32); a1 += __shfl_xor(a1, 32);
  a2 += __shfl_xor(a2, 32); a3 += __shfl_xor(a3, 32);
  a4 += __shfl_xor(a4, 32); a5 += __shfl_xor(a5, 32);
  a6 += __shfl_xor(a6, 32); a7 += __shfl_xor(a7, 32);
  if (eq == 0) {
    u32x4 o;
    o.x = pack2(a0, a1);
    o.y = pack2(a2, a3);
    o.z = pack2(a4, a5);
    o.w = pack2(a6, a7);
    *reinterpret_cast<u32x4*>(out + (size_t)node * 64 + (foff >> 2)) = o;
  }
}

// width 32-padded: 8 lanes per node (dwordx2 each); cooperative meta load
// (8 lanes load 8 different metas, shfl-broadcast) -> 8 gathers in flight.
__global__ __launch_bounds__(256) void spmm26_bf(
    const u32x2* __restrict__ meta, const int* __restrict__ start,
    const uint_t* __restrict__ in, const uint_t* __restrict__ add,
    uint_t* __restrict__ out, int n) {
  int node = blockIdx.x * 32 + (threadIdx.x >> 3);
  int ln = threadIdx.x & 7;
  if (node >= n) return;
  int s = start[node], m = start[node + 1] - s;
  uint_t foff = (uint_t)ln << 3;  // byte offset within 64B row
  const char* inb = (const char*)in;
  float a0 = 0.f, a1 = 0.f, a2 = 0.f, a3 = 0.f;
  if (m > 0) {
    for (int base = 0; base < m; base += 8) {
      int j = base + ln;
      u32x2 mt = meta[s + (j < m ? j : m - 1)];
      int rr = (int)mt.x;
      float ww = (j < m) ? __uint_as_float(mt.y) : 0.f;
#pragma unroll
      for (int k = 0; k < 8; ++k) {
        uint_t r = (uint_t)__shfl(rr, k, 8);
        float wv = __shfl(ww, k, 8);
        u32x2 v = *reinterpret_cast<const u32x2*>(inb + ((r << 6) + foff));
        a0 += wv * lo16(v.x); a1 += wv * hi16(v.x);
        a2 += wv * lo16(v.y); a3 += wv * hi16(v.y);
      }
    }
  }
  if (add) {
    u32x2 v = *reinterpret_cast<const u32x2*>(add + (size_t)node * 16 + 2 * ln);
    a0 += lo16(v.x); a1 += hi16(v.x);
    a2 += lo16(v.y); a3 += hi16(v.y);
  }
  u32x2 o;
  o.x = pack2(a0, a1);
  o.y = pack2(a2, a3);
  *reinterpret_cast<u32x2*>(out + (size_t)node * 16 + 2 * ln) = o;
}

// final Horner step: out_f32 (n x 26) += A*in
__global__ __launch_bounds__(256) void spmm26_addf(
    const u32x2* __restrict__ meta, const int* __restrict__ start,
    const uint_t* __restrict__ in, float* __restrict__ out, int n) {
  int node = blockIdx.x * 32 + (threadIdx.x >> 3);
  int ln = threadIdx.x & 7;
  if (node >= n) return;
  int s = start[node], m = start[node + 1] - s;
  uint_t foff = (uint_t)ln << 3;
  const char* inb = (const char*)in;
  float a0 = 0.f, a1 = 0.f, a2 = 0.f, a3 = 0.f;
  if (m > 0) {
    for (int base = 0; base < m; base += 8) {
      int j = base + ln;
      u32x2 mt = meta[s + (j < m ? j : m - 1)];
      int rr = (int)mt.x;
      float ww = (j < m) ? __uint_as_float(mt.y) : 0.f;
#pragma unroll
      for (int k = 0; k < 8; ++k) {
        uint_t r = (uint_t)__shfl(rr, k, 8);
        float wv = __shfl(ww, k, 8);
        u32x2 v = *reinterpret_cast<const u32x2*>(inb + ((r << 6) + foff));
        a0 += wv * lo16(v.x); a1 += wv * hi16(v.x);
        a2 += wv * lo16(v.y); a3 += wv * hi16(v.y);
      }
    }
  }
  int c0 = 4 * ln;
  if (c0 + 0 < 26) out[(size_t)node * 26 + c0 + 0] += a0;
  if (c0 + 1 < 26) out[(size_t)node * 26 + c0 + 1] += a1;
  if (c0 + 2 < 26) out[(size_t)node * 26 + c0 + 2] += a2;
  if (c0 + 3 < 26) out[(size_t)node * 26 + c0 + 3] += a3;
}

// ---------------- fused MFMA GEMM, LDS-staged W, pipelined A prefetch ----------------
// C(n x 128) = [A0|A1|A2|A3] (each n x KW bf16) @ Wswz (+bias)
// W staged cooperatively into LDS in GROUP-kstep chunks (shared by all 4 waves).
// A-fragments double-buffered in registers: group g+1's loads issue before group
// g's MFMA phase, hiding A latency under compute. Wave owns 16 rows (grid n/64).
// EPI 0: ELU, write bf16 n x 128 to outb
// EPI 1: layer-3 slots: slot0 -> outf (n x 26 fp32, +bias); slots 1..3 -> outb (3 x n x 32 bf16)
template <int KW, int NSRC, int EPI, int GROUP>
__global__ __launch_bounds__(256) void mfma_gemm(
    const ushort_t* __restrict__ A0, const ushort_t* __restrict__ A1,
    const ushort_t* __restrict__ A2, const ushort_t* __restrict__ A3,
    const ushort_t* __restrict__ Wswz, const float* __restrict__ bias,
    ushort_t* __restrict__ outb, float* __restrict__ outf, int n) {
  constexpr int KSPS = KW / 32;
  constexpr int KSTEPS = NSRC * KSPS;
  constexpr int NGROUPS = KSTEPS / GROUP;
  __shared__ ushort_t sW[GROUP * 4096];
  const int tid = threadIdx.x;
  const int w = tid >> 6;
  const int l = tid & 63;
  const int row0 = blockIdx.x * 64 + w * 16;
  const int koff = 8 * (l >> 4);  // elements
  const int arow = row0 + (l & 15);
  const int arow_c = arow < n ? arow : (n - 1);

  f32x4 acc[8];
#pragma unroll
  for (int j = 0; j < 8; ++j) acc[j] = (f32x4){0.f, 0.f, 0.f, 0.f};

  const ushort_t* const srcs[4] = {A0, A1, A2, A3};

  // A-fragment address for global kstep t (s, tt compile-time under full unroll)
  auto aload = [&](int t) {
    const int s = t / KSPS;
    const int tt = t - s * KSPS;
    return ld_frag(srcs[s] + (size_t)arow_c * KW + tt * 32 + koff);
  };

  // prologue: A group 0 + W group 0 into registers
  bf16x8 afA[GROUP], afB[GROUP];
#pragma unroll
  for (int c = 0; c < GROUP; ++c) afA[c] = aload(c);
  u32x4 gw[2 * GROUP];
#pragma unroll
  for (int c = 0; c < GROUP; ++c) {
    const ushort_t* p = Wswz + (size_t)c * 4096 + tid * 8;
    gw[2 * c] = *reinterpret_cast<const u32x4*>(p);
    gw[2 * c + 1] = *reinterpret_cast<const u32x4*>(p + 2048);
  }

#pragma unroll
  for (int g = 0; g < NGROUPS; ++g) {
    __syncthreads();  // sW writable (all waves done reading previous group)
#pragma unroll
    for (int c = 0; c < GROUP; ++c) {
      *reinterpret_cast<u32x4*>(sW + c * 4096 + tid * 8) = gw[2 * c];
      *reinterpret_cast<u32x4*>(sW + c * 4096 + tid * 8 + 2048) = gw[2 * c + 1];
    }
    if (g + 1 < NGROUPS) {
      // prefetch next W group into registers and next A group into alternate buffer;
      // these loads complete during this group's MFMA phase
#pragma unroll
      for (int c = 0; c < GROUP; ++c) {
        const ushort_t* p = Wswz + (size_t)(g + 1) * GROUP * 4096 + (size_t)c * 4096 + tid * 8;
        gw[2 * c] = *reinterpret_cast<const u32x4*>(p);
        gw[2 * c + 1] = *reinterpret_cast<const u32x4*>(p + 2048);
      }
#pragma unroll
      for (int c = 0; c < GROUP; ++c) {
        if (g & 1)
          afA[c] = aload((g + 1) * GROUP + c);
        else
          afB[c] = aload((g + 1) * GROUP + c);
      }
    }
    __syncthreads();  // sW ready
#pragma unroll
    for (int tg = 0; tg < GROUP; ++tg) {
      bf16x8 af = (g & 1) ? afB[tg] : afA[tg];
      const ushort_t* wp = sW + tg * 4096 + l * 8;
#pragma unroll
      for (int j = 0; j < 8; ++j) {
        bf16x8 bfr = ld_frag(wp + j * 64 * 8);
        acc[j] = __builtin_amdgcn_mfma_f32_16x16x32_bf16(af, bfr, acc[j], 0, 0, 0);
      }
    }
  }

  const int ccol = l & 15;
  const int crow0 = row0 + 4 * (l >> 4);
#pragma unroll
  for (int j = 0; j < 8; ++j) {
    if (EPI == 0) {
      int col = 16 * j + ccol;
      float bi = bias[col];
#pragma unroll
      for (int r = 0; r < 4; ++r) {
        int row = crow0 + r;
        if (row >= n) continue;
        float v = acc[j][r] + bi;
        v = v > 0.f ? v : (__expf(v) - 1.f);
        outb[(size_t)row * 128 + col] = f2b(v);
      }
    } else {
      int slot = j >> 1;
      int c = 16 * (j & 1) + ccol;
#pragma unroll
      for (int r = 0; r < 4; ++r) {
        int row = crow0 + r;
        if (row >= n) continue;
        float v = acc[j][r];
        if (slot == 0) {
          if (c < 26) outf[(size_t)row * 26 + c] = v + bias[c];
        } else {
          outb[((size_t)(slot - 1) * n + row) * 32 + c] = f2b(v);
        }
      }
    }
  }
}

// ---------------- launcher ----------------

extern "C" void kernel_launch(void* const* d_in, const int* in_sizes, int n_in,
                              void* d_out, int out_size, void* d_ws, size_t ws_size,
                              hipStream_t stream) {
  const float* x  = (const float*)d_in[0];
  const int*   ei = (const int*)d_in[1];
  const float* ew = (const float*)d_in[2];
  const float* W1 = (const float*)d_in[3];
  const float* b1 = (const float*)d_in[4];
  const float* W2 = (const float*)d_in[5];
  const float* b2 = (const float*)d_in[6];
  const float* W3 = (const float*)d_in[7];
  const float* b3 = (const float*)d_in[8];
  float* out = (float*)d_out;

  const int n = in_sizes[0] / NCLS;  // 100000
  const int E = in_sizes[2];         // 1600000
  const int nbk = (n + 255) >> 8;    // 391 buckets

  char* w = (char*)d_ws;
  auto alloc = [&](size_t bytes) {
    char* p = w;
    w += (bytes + 255) / 256 * 256;
    return p;
  };
  // width-128 bf16 feature buffers (64 dwords per node)
  uint_t* H0 = (uint_t*)alloc((size_t)n * 64 * 4);
  uint_t* P1 = (uint_t*)alloc((size_t)n * 64 * 4);
  uint_t* P2 = (uint_t*)alloc((size_t)n * 64 * 4);
  uint_t* P3 = (uint_t*)alloc((size_t)n * 64 * 4);
  uint_t* H1 = (uint_t*)alloc((size_t)n * 64 * 4);
  // width-32-padded bf16 buffers (16 dwords per node)
  uint_t* x32 = (uint_t*)alloc((size_t)n * 16 * 4);
  uint_t* q1  = (uint_t*)alloc((size_t)n * 16 * 4);
  uint_t* q2  = (uint_t*)alloc((size_t)n * 16 * 4);
  uint_t* q3  = (uint_t*)alloc((size_t)n * 16 * 4);
  uint_t* zb  = (uint_t*)alloc((size_t)n * 48 * 4);  // z1,z2,z3 each n x 32 bf16
  // swizzled weights
  ushort_t* Wz1 = (ushort_t*)alloc(4 * 4096 * 2);
  ushort_t* Wz2 = (ushort_t*)alloc(16 * 4096 * 2);
  ushort_t* Wz3 = (ushort_t*)alloc(4 * 4096 * 2);
  // graph CSR
  u64*   bkt  = (u64*)zb;  // alias: bkt (18.8MB @ BCAP=6016) dead before zb (19.2MB) is used
  u32x2* meta = (u32x2*)alloc((size_t)E * 8);
  int*   start = (int*)alloc((size_t)(n + 1) * 4);
  float* dinv  = (float*)alloc((size_t)n * 4);
  int*   gcur  = (int*)alloc(MAXBK * 4);
  int*   mbase = (int*)alloc((MAXBK + 1) * 4);

  const int ab = (E + EPB - 1) / EPB;  // bucketing blocks (196)
  const int gconv = (n * 16 + 255) / 256;

  // independent small prep (x conversion + W swizzles) in one launch
  prep_misc<<<gconv + 64 + 256 + 64, 256, 0, stream>>>(x, x32, W1, Wz1, W2, Wz2, W3, Wz3,
                                                       n, gconv);

  hipMemsetAsync(gcur, 0, MAXBK * 4, stream);
  bucket_place<<<ab, 256, 0, stream>>>(ei, ew, gcur, bkt, E, nbk);
  scan_buckets<<<1, 512, 0, stream>>>(gcur, mbase, nbk, E);
  bucket_stats<<<nbk, 256, 0, stream>>>(bkt, gcur, mbase, start, dinv, n, E);
  bucket_emit<<<nbk, 256, 0, stream>>>(bkt, gcur, start, dinv, meta, n);

  const int g128 = (n + 3) / 4;
  const int g26  = (n + 31) / 32;
  const int gg   = (n + 63) / 64;  // mfma_gemm grid (64 rows/block)

  // ---- Layer 1: q_k = A^k x (width 32-padded), H0 = ELU([x|q1|q2|q3] @ W1cat + b1) ----
  spmm26_bf<<<g26, 256, 0, stream>>>(meta, start, x32, nullptr, q1, n);
  spmm26_bf<<<g26, 256, 0, stream>>>(meta, start, q1, nullptr, q2, n);
  spmm26_bf<<<g26, 256, 0, stream>>>(meta, start, q2, nullptr, q3, n);
  mfma_gemm<32, 4, 0, 4><<<gg, 256, 0, stream>>>(
      (const ushort_t*)x32, (const ushort_t*)q1, (const ushort_t*)q2, (const ushort_t*)q3,
      Wz1, b1, (ushort_t*)H0, nullptr, n);

  // ---- Layer 2: P_k = A^k H0, H1 = ELU([H0|P1|P2|P3] @ W2cat + b2) ----
  spmm128_bf<<<g128, 256, 0, stream>>>(meta, start, H0, P1, n);
  spmm128_bf<<<g128, 256, 0, stream>>>(meta, start, P1, P2, n);
  spmm128_bf<<<g128, 256, 0, stream>>>(meta, start, P2, P3, n);
  mfma_gemm<128, 4, 0, 4><<<gg, 256, 0, stream>>>(
      (const ushort_t*)H0, (const ushort_t*)P1, (const ushort_t*)P2, (const ushort_t*)P3,
      Wz2, b2, (ushort_t*)H1, nullptr, n);

  // ---- Layer 3: Z = H1 @ [W3_0|W3_1|W3_2|W3_3]; Horner out = z0+b3 + A(z1 + A(z2 + A z3)) ----
  // NOTE: zb aliases bkt, which is dead after bucket_emit — safe.
  mfma_gemm<128, 1, 1, 4><<<gg, 256, 0, stream>>>(
      (const ushort_t*)H1, (const ushort_t*)H1, (const ushort_t*)H1, (const ushort_t*)H1,
      Wz3, b3, (ushort_t*)zb, out, n);

  uint_t* z1 = zb;
  uint_t* z2 = zb + (size_t)n * 16;
  uint_t* z3 = zb + (size_t)n * 32;
  spmm26_bf<<<g26, 256, 0, stream>>>(meta, start, z3, z2, q1, n);  // q1 = z2 + A z3
  spmm26_bf<<<g26, 256, 0, stream>>>(meta, start, q1, z1, q2, n);  // q2 = z1 + A q1
  spmm26_addf<<<g26, 256, 0, stream>>>(meta, start, q2, out, n);   // out += A q2
}